// Round 11
// baseline (21585.378 us; speedup 1.0000x reference)
//
#include <hip/hip_runtime.h>

#define NN 50000
#define NE 600000
#define HD 128
#define NL 6

__global__ void k_code(float* __restrict__ out, float code) {
  if (threadIdx.x == 0 && blockIdx.x == 0) out[0] = code;
}

// ---------------- degree + inverse degree ----------------

__global__ __launch_bounds__(256) void k_deg(const int* __restrict__ ei, int* __restrict__ deg) {
  int e = blockIdx.x * 256 + threadIdx.x;
  if (e < NE) {
    int d = ei[NE + e];
    if (d >= 0 && d < NN) atomicAdd(&deg[d], 1);
  }
}

__global__ __launch_bounds__(256) void k_invd(const int* __restrict__ deg, float* __restrict__ invd) {
  int i = blockIdx.x * 256 + threadIdx.x;
  if (i < NN) invd[i] = 1.0f / fmaxf((float)deg[i], 1.0f);
}

// ---------------- embedding ----------------

__global__ __launch_bounds__(256) void k_emb1(const float* __restrict__ u, const float* __restrict__ pos,
                                              const float* __restrict__ W, const float* __restrict__ b,
                                              float* __restrict__ h, double* __restrict__ stats) {
  __shared__ float xs[32 * 129];
  int tid = threadIdx.x;
  int nl = tid & 31, jg = tid >> 5;
  int gn = blockIdx.x * 32 + nl;
  float f0 = 0.f, f1 = 0.f, f2 = 0.f, f3 = 0.f;
  if (gn < NN) { f0 = u[gn]; f1 = pos[gn*3+1]; f2 = pos[gn*3+2]; f3 = pos[gn*3+0]; }
  float x[16];
#pragma unroll
  for (int q = 0; q < 4; ++q) {
    int j = (jg << 4) + (q << 2);
    float4 w0 = *(const float4*)(W + 0*HD + j);
    float4 w1 = *(const float4*)(W + 1*HD + j);
    float4 w2 = *(const float4*)(W + 2*HD + j);
    float4 w3 = *(const float4*)(W + 3*HD + j);
    float4 bb = *(const float4*)(b + j);
    x[q*4+0] = f0*w0.x + f1*w1.x + f2*w2.x + f3*w3.x + bb.x;
    x[q*4+1] = f0*w0.y + f1*w1.y + f2*w2.y + f3*w3.y + bb.y;
    x[q*4+2] = f0*w0.z + f1*w1.z + f2*w2.z + f3*w3.z + bb.z;
    x[q*4+3] = f0*w0.w + f1*w1.w + f2*w2.w + f3*w3.w + bb.w;
  }
  if (gn < NN) {
#pragma unroll
    for (int q = 0; q < 4; ++q)
      *(float4*)(h + (size_t)gn*HD + (jg<<4) + (q<<2)) = make_float4(x[q*4+0], x[q*4+1], x[q*4+2], x[q*4+3]);
  }
#pragma unroll
  for (int i = 0; i < 16; ++i) xs[nl*129 + (jg<<4) + i] = (gn < NN) ? x[i] : 0.f;
  __syncthreads();
  if (tid < HD) {
    double s = 0.0, sq = 0.0;
    for (int e = 0; e < 32; ++e) { double v = (double)xs[e*129 + tid]; s += v; sq += v*v; }
    atomicAdd(&stats[tid], s);
    atomicAdd(&stats[HD + tid], sq);
  }
}

__global__ __launch_bounds__(256) void k_emb2(float* __restrict__ h, const float* __restrict__ W,
                                              const float* __restrict__ b, double* __restrict__ stats) {
  __shared__ float hs[32 * 129];
  int tid = threadIdx.x;
  int base = blockIdx.x * 32;
#pragma unroll
  for (int r = 0; r < 16; ++r) {
    int lin = r*256 + tid;
    int n = lin >> 7, j = lin & 127;
    int gn = base + n;
    hs[n*129 + j] = (gn < NN) ? h[(size_t)gn*HD + j] : 0.f;
  }
  __syncthreads();
  int nl = tid & 31, jg = tid >> 5;
  int gn = base + nl;
  float acc[16];
#pragma unroll
  for (int q = 0; q < 4; ++q) {
    float4 bb = *(const float4*)(b + (jg<<4) + (q<<2));
    acc[q*4+0] = bb.x; acc[q*4+1] = bb.y; acc[q*4+2] = bb.z; acc[q*4+3] = bb.w;
  }
  for (int k = 0; k < HD; ++k) {
    float a = hs[nl*129 + k];
    const float4* wp = (const float4*)(W + (size_t)k*HD + (jg<<4));
#pragma unroll
    for (int q = 0; q < 4; ++q) {
      float4 wv = wp[q];
      acc[q*4+0] = fmaf(a, wv.x, acc[q*4+0]);
      acc[q*4+1] = fmaf(a, wv.y, acc[q*4+1]);
      acc[q*4+2] = fmaf(a, wv.z, acc[q*4+2]);
      acc[q*4+3] = fmaf(a, wv.w, acc[q*4+3]);
    }
  }
  if (gn < NN) {
#pragma unroll
    for (int q = 0; q < 4; ++q)
      *(float4*)(h + (size_t)gn*HD + (jg<<4) + (q<<2)) = make_float4(acc[q*4+0], acc[q*4+1], acc[q*4+2], acc[q*4+3]);
  }
  __syncthreads();
#pragma unroll
  for (int i = 0; i < 16; ++i) hs[nl*129 + (jg<<4) + i] = (gn < NN) ? acc[i] : 0.f;
  __syncthreads();
  if (tid < HD) {
    double s = 0.0, sq = 0.0;
    for (int e = 0; e < 32; ++e) { double v = (double)hs[e*129 + tid]; s += v; sq += v*v; }
    atomicAdd(&stats[tid], s);
    atomicAdd(&stats[HD + tid], sq);
  }
}

__global__ void k_redA(const double* __restrict__ stats, float* __restrict__ musig) {
  int c = threadIdx.x;   // 128
  double mu  = stats[c] / (double)NN;
  double var = stats[128 + c] / (double)NN - mu * mu;
  musig[c]      = (float)mu;
  musig[HD + c] = (float)(1.0 / sqrt(var + 1e-5));
}

__global__ __launch_bounds__(256) void k_bn(float* __restrict__ h, const float* __restrict__ musig,
                                            const float* __restrict__ g, const float* __restrict__ be,
                                            int relu) {
  int idx = blockIdx.x * 256 + threadIdx.x;
  if (idx >= NN * HD) return;
  int j = idx & 127;
  float x = h[idx];
  x = g[j] * (x - musig[j]) * musig[HD + j] + be[j];
  if (relu) x = fmaxf(x, 0.f);
  h[idx] = x;
}

// ---------------- direct edge message MLP + atomic aggregation ----------------

__global__ __launch_bounds__(256) void k_msg_direct(const float* __restrict__ h,
                                                    const int* __restrict__ ei, const float* __restrict__ u,
                                                    const float* __restrict__ pos, const float* __restrict__ invd,
                                                    const float* __restrict__ W1, const float* __restrict__ b1,
                                                    const float* __restrict__ W2, const float* __restrict__ b2,
                                                    float* __restrict__ agg) {
  __shared__ float hd[32 * 129];
  __shared__ float hsr[32 * 129];
  __shared__ float m1s[32 * 129];
  __shared__ int lsrc[32];
  __shared__ int ldst[32];
  __shared__ float lf[32][4];
  int tid = threadIdx.x;
  int base = blockIdx.x * 32;
  if (tid < 32) {
    int e = base + tid;
    int s = ei[e], d = ei[NE + e];
    s = s < 0 ? 0 : (s >= NN ? NN - 1 : s);
    d = d < 0 ? 0 : (d >= NN ? NN - 1 : d);
    lsrc[tid] = s; ldst[tid] = d;
    lf[tid][0] = u[d] - u[s];
    lf[tid][1] = pos[d*3+1] - pos[s*3+1];
    lf[tid][2] = pos[d*3+2] - pos[s*3+2];
    lf[tid][3] = pos[d*3+0];
  }
  __syncthreads();
#pragma unroll
  for (int r = 0; r < 16; ++r) {
    int lin = r*256 + tid;
    int n = lin >> 7, j = lin & 127;
    hd[n*129 + j]  = h[(size_t)ldst[n]*HD + j];
    hsr[n*129 + j] = h[(size_t)lsrc[n]*HD + j];
  }
  __syncthreads();
  int el = tid & 31, jg = tid >> 5;
  float f0 = lf[el][0], f1 = lf[el][1], f2 = lf[el][2], f3 = lf[el][3];
  const float* We = W1 + 256*HD + (jg<<4);
  float acc[16];
#pragma unroll
  for (int q = 0; q < 4; ++q) {
    float4 w0 = *(const float4*)(We + 0*HD + (q<<2));
    float4 w1 = *(const float4*)(We + 1*HD + (q<<2));
    float4 w2 = *(const float4*)(We + 2*HD + (q<<2));
    float4 w3 = *(const float4*)(We + 3*HD + (q<<2));
    float4 bb = *(const float4*)(b1 + (jg<<4) + (q<<2));
    acc[q*4+0] = f0*w0.x + f1*w1.x + f2*w2.x + f3*w3.x + bb.x;
    acc[q*4+1] = f0*w0.y + f1*w1.y + f2*w2.y + f3*w3.y + bb.y;
    acc[q*4+2] = f0*w0.z + f1*w1.z + f2*w2.z + f3*w3.z + bb.z;
    acc[q*4+3] = f0*w0.w + f1*w1.w + f2*w2.w + f3*w3.w + bb.w;
  }
  for (int k = 0; k < HD; ++k) {
    float a  = hd[el*129 + k];
    float bs = hsr[el*129 + k];
    const float4* wa = (const float4*)(W1 + (size_t)k*HD + (jg<<4));
    const float4* wb = (const float4*)(W1 + (size_t)(128 + k)*HD + (jg<<4));
#pragma unroll
    for (int q = 0; q < 4; ++q) {
      float4 w1v = wa[q];
      float4 w2v = wb[q];
      acc[q*4+0] = fmaf(a, w1v.x, fmaf(bs, w2v.x, acc[q*4+0]));
      acc[q*4+1] = fmaf(a, w1v.y, fmaf(bs, w2v.y, acc[q*4+1]));
      acc[q*4+2] = fmaf(a, w1v.z, fmaf(bs, w2v.z, acc[q*4+2]));
      acc[q*4+3] = fmaf(a, w1v.w, fmaf(bs, w2v.w, acc[q*4+3]));
    }
  }
#pragma unroll
  for (int i = 0; i < 16; ++i) m1s[el*129 + (jg<<4) + i] = fmaxf(acc[i], 0.f);
  __syncthreads();
  float acc2[16];
#pragma unroll
  for (int q = 0; q < 4; ++q) {
    float4 bb = *(const float4*)(b2 + (jg<<4) + (q<<2));
    acc2[q*4+0] = bb.x; acc2[q*4+1] = bb.y; acc2[q*4+2] = bb.z; acc2[q*4+3] = bb.w;
  }
  for (int k = 0; k < HD; ++k) {
    float a = m1s[el*129 + k];
    const float4* wp = (const float4*)(W2 + (size_t)k*HD + (jg<<4));
#pragma unroll
    for (int q = 0; q < 4; ++q) {
      float4 wv = wp[q];
      acc2[q*4+0] = fmaf(a, wv.x, acc2[q*4+0]);
      acc2[q*4+1] = fmaf(a, wv.y, acc2[q*4+1]);
      acc2[q*4+2] = fmaf(a, wv.z, acc2[q*4+2]);
      acc2[q*4+3] = fmaf(a, wv.w, acc2[q*4+3]);
    }
  }
#pragma unroll
  for (int i = 0; i < 16; ++i) hd[el*129 + (jg<<4) + i] = fmaxf(acc2[i], 0.f);
  __syncthreads();
  if (tid < HD) {
    int j = tid;
    for (int e = 0; e < 32; ++e) {
      int de = ldst[e];
      atomicAdd(&agg[(size_t)de*HD + j], hd[e*129 + j] * invd[de]);
    }
  }
}

// ---------------- node update MLP ----------------

__global__ __launch_bounds__(256) void k_upd(float* __restrict__ h, const float* __restrict__ agg,
                                             const float* __restrict__ pos,
                                             const float* __restrict__ W1, const float* __restrict__ b1,
                                             const float* __restrict__ W2, const float* __restrict__ b2,
                                             double* __restrict__ stats) {
  __shared__ float hs[32 * 129];
  __shared__ float as_[32 * 129];
  int tid = threadIdx.x;
  int base = blockIdx.x * 32;
#pragma unroll
  for (int r = 0; r < 16; ++r) {
    int lin = r*256 + tid;
    int n = lin >> 7, j = lin & 127;
    int gn = base + n;
    hs[n*129 + j]  = (gn < NN) ? h[(size_t)gn*HD + j]   : 0.f;
    as_[n*129 + j] = (gn < NN) ? agg[(size_t)gn*HD + j] : 0.f;
  }
  __syncthreads();
  int nl = tid & 31, jg = tid >> 5;
  int gn = base + nl;
  float var = (gn < NN) ? pos[gn*3+0] : 0.f;
  float acc[16];
#pragma unroll
  for (int q = 0; q < 4; ++q) {
    int j = (jg<<4) + (q<<2);
    float4 bb = *(const float4*)(b1 + j);
    float4 wv = *(const float4*)(W1 + 256*HD + j);
    acc[q*4+0] = fmaf(var, wv.x, bb.x);
    acc[q*4+1] = fmaf(var, wv.y, bb.y);
    acc[q*4+2] = fmaf(var, wv.z, bb.z);
    acc[q*4+3] = fmaf(var, wv.w, bb.w);
  }
  for (int k = 0; k < HD; ++k) {
    float a = hs[nl*129 + k];
    float g = as_[nl*129 + k];
    const float4* w1p = (const float4*)(W1 + (size_t)k*HD + (jg<<4));
    const float4* w2p = (const float4*)(W1 + (size_t)(128 + k)*HD + (jg<<4));
#pragma unroll
    for (int q = 0; q < 4; ++q) {
      float4 wa = w1p[q];
      float4 wb = w2p[q];
      acc[q*4+0] = fmaf(a, wa.x, fmaf(g, wb.x, acc[q*4+0]));
      acc[q*4+1] = fmaf(a, wa.y, fmaf(g, wb.y, acc[q*4+1]));
      acc[q*4+2] = fmaf(a, wa.z, fmaf(g, wb.z, acc[q*4+2]));
      acc[q*4+3] = fmaf(a, wa.w, fmaf(g, wb.w, acc[q*4+3]));
    }
  }
  float up1[16];
#pragma unroll
  for (int i = 0; i < 16; ++i) up1[i] = fmaxf(acc[i], 0.f);
  __syncthreads();
#pragma unroll
  for (int i = 0; i < 16; ++i) as_[nl*129 + (jg<<4) + i] = up1[i];
  __syncthreads();
  float acc2[16];
#pragma unroll
  for (int q = 0; q < 4; ++q) {
    float4 bb = *(const float4*)(b2 + (jg<<4) + (q<<2));
    acc2[q*4+0] = bb.x; acc2[q*4+1] = bb.y; acc2[q*4+2] = bb.z; acc2[q*4+3] = bb.w;
  }
  for (int k = 0; k < HD; ++k) {
    float a = as_[nl*129 + k];
    const float4* wp = (const float4*)(W2 + (size_t)k*HD + (jg<<4));
#pragma unroll
    for (int q = 0; q < 4; ++q) {
      float4 wv = wp[q];
      acc2[q*4+0] = fmaf(a, wv.x, acc2[q*4+0]);
      acc2[q*4+1] = fmaf(a, wv.y, acc2[q*4+1]);
      acc2[q*4+2] = fmaf(a, wv.z, acc2[q*4+2]);
      acc2[q*4+3] = fmaf(a, wv.w, acc2[q*4+3]);
    }
  }
  float x[16];
#pragma unroll
  for (int i = 0; i < 16; ++i)
    x[i] = hs[nl*129 + (jg<<4) + i] + fmaxf(acc2[i], 0.f);
  if (gn < NN) {
#pragma unroll
    for (int q = 0; q < 4; ++q)
      *(float4*)(h + (size_t)gn*HD + (jg<<4) + (q<<2)) = make_float4(x[q*4+0], x[q*4+1], x[q*4+2], x[q*4+3]);
  }
  __syncthreads();
#pragma unroll
  for (int i = 0; i < 16; ++i) hs[nl*129 + (jg<<4) + i] = (gn < NN) ? x[i] : 0.f;
  __syncthreads();
  if (tid < HD) {
    double s = 0.0, sq = 0.0;
    for (int e = 0; e < 32; ++e) { double v = (double)hs[e*129 + tid]; s += v; sq += v*v; }
    atomicAdd(&stats[tid], s);
    atomicAdd(&stats[HD + tid], sq);
  }
}

// ---------------- CNN head (FIXED: full 72-slot o2 coverage) ----------------

__global__ __launch_bounds__(256) void k_conv(const float* __restrict__ h,
                                              const float* __restrict__ c1W, const float* __restrict__ c1b,
                                              const float* __restrict__ c2W, const float* __restrict__ c2b,
                                              const float* __restrict__ c3W, const float* __restrict__ c3b,
                                              float* __restrict__ out) {
  __shared__ float xs[4][128];
  __shared__ float o1[4][152];
  __shared__ float o2[4][72];
  int tid = threadIdx.x;
  int w = tid >> 6, lane = tid & 63;
  int n = blockIdx.x * 4 + w;          // NN % 4 == 0
  xs[w][lane]      = h[(size_t)n*HD + lane];
  xs[w][64 + lane] = h[(size_t)n*HD + 64 + lane];
  __syncthreads();
  for (int o = lane; o < 152; o += 64) {
    int oc = o / 38, t = o % 38;
    float s = c1b[oc];
#pragma unroll
    for (int k = 0; k < 16; ++k) s = fmaf(xs[w][t*3 + k], c1W[oc*16 + k], s);
    o1[w][oc*38 + t] = fmaxf(s, 0.f);
  }
  __syncthreads();
  // BUG FIX (rounds 0-8): was `if (lane < 72)` with lane = tid&63 < 64 — slots
  // o2[7][1..8] were never written, so conv3 summed stale LDS (the 8.5e-4).
  for (int o = lane; o < 72; o += 64) {
    int oc = o / 9, t = o % 9;
    float s = c2b[oc];
    for (int ic = 0; ic < 4; ++ic) {
#pragma unroll
      for (int k = 0; k < 12; ++k) s = fmaf(o1[w][ic*38 + t*3 + k], c2W[oc*48 + ic*12 + k], s);
    }
    o2[w][oc*9 + t] = fmaxf(s, 0.f);
  }
  __syncthreads();
  int ic = lane >> 3, k = lane & 7;
  float t3 = o2[w][ic*9 + k] * c3W[ic*8 + k];
  for (int off = 32; off; off >>= 1) t3 += __shfl_down(t3, off);
  if (lane == 0) out[n] = 0.001f * (t3 + c3b[0]);   // dt = cumsum(DT*0.1), TW=1
}

// ---------------- launcher ----------------

extern "C" void kernel_launch(void* const* d_in, const int* in_sizes, int n_in,
                              void* d_out, int out_size, void* d_ws, size_t ws_size,
                              hipStream_t stream) {
  (void)out_size;
  float* out = (float*)d_out;

  static const int expect[27] = {
    50000, 150000, 1200000,
    512, 128, 128, 128,
    16384, 128, 128, 128,
    199680, 768, 98304, 768, 197376, 768, 98304, 768,
    768, 768,
    64, 4, 384, 8, 64, 1
  };
  if (n_in != 27) { k_code<<<1, 64, 0, stream>>>(out, 5000099.f); return; }
  for (int i = 0; i < 27; ++i)
    if (in_sizes[i] != expect[i]) { k_code<<<1, 64, 0, stream>>>(out, 5000100.f + (float)i); return; }

  const float* u    = (const float*)d_in[0];
  const float* pos  = (const float*)d_in[1];
  const int*   ei   = (const int*)d_in[2];
  const float* eW1  = (const float*)d_in[3];
  const float* eb1  = (const float*)d_in[4];
  const float* eg1  = (const float*)d_in[5];
  const float* ebe1 = (const float*)d_in[6];
  const float* eW2  = (const float*)d_in[7];
  const float* eb2  = (const float*)d_in[8];
  const float* eg2  = (const float*)d_in[9];
  const float* ebe2 = (const float*)d_in[10];
  const float* m1W  = (const float*)d_in[11];
  const float* m1b  = (const float*)d_in[12];
  const float* m2W  = (const float*)d_in[13];
  const float* m2b  = (const float*)d_in[14];
  const float* u1W  = (const float*)d_in[15];
  const float* u1b  = (const float*)d_in[16];
  const float* u2W  = (const float*)d_in[17];
  const float* u2b  = (const float*)d_in[18];
  const float* bng  = (const float*)d_in[19];
  const float* bnb  = (const float*)d_in[20];
  const float* c1W  = (const float*)d_in[21];
  const float* c1b  = (const float*)d_in[22];
  const float* c2W  = (const float*)d_in[23];
  const float* c2b  = (const float*)d_in[24];
  const float* c3W  = (const float*)d_in[25];
  const float* c3b  = (const float*)d_in[26];

  // ---- workspace ----
  char* wsp = (char*)d_ws;
  size_t off = 0;
  auto alloc = [&](size_t bytes) -> void* {
    void* p = wsp + off;
    off = (off + bytes + 255) & ~(size_t)255;
    return p;
  };
  double* stats = (double*)alloc(256 * 8);
  float*  musig = (float*)alloc(256 * 4);
  int*    deg   = (int*)alloc((size_t)NN * 4);
  float*  invd  = (float*)alloc((size_t)NN * 4);
  float*  h     = (float*)alloc((size_t)NN * HD * 4);
  float*  agg   = (float*)alloc((size_t)NN * HD * 4);
  size_t needed = off;
  if (ws_size < needed) {
    k_code<<<1, 64, 0, stream>>>(out, (float)(9000000u + (unsigned)(ws_size >> 20)));
    return;
  }

  const int nbN  = (NN + 255) / 256;
  const int nbE  = (NE + 255) / 256;
  const int nt32 = (NN + 31) / 32;
  const int nbBN = NN * HD / 256;

  // ---- degree / inverse degree ----
  hipMemsetAsync(deg, 0, (size_t)NN * 4, stream);
  k_deg<<<nbE, 256, 0, stream>>>(ei, deg);
  k_invd<<<nbN, 256, 0, stream>>>(deg, invd);

  // ---- embedding ----
  hipMemsetAsync(stats, 0, 256 * 8, stream);
  k_emb1<<<nt32, 256, 0, stream>>>(u, pos, eW1, eb1, h, stats);
  k_redA<<<1, 128, 0, stream>>>(stats, musig);
  k_bn<<<nbBN, 256, 0, stream>>>(h, musig, eg1, ebe1, 1);
  hipMemsetAsync(stats, 0, 256 * 8, stream);
  k_emb2<<<nt32, 256, 0, stream>>>(h, eW2, eb2, stats);
  k_redA<<<1, 128, 0, stream>>>(stats, musig);
  k_bn<<<nbBN, 256, 0, stream>>>(h, musig, eg2, ebe2, 0);

  // ---- message-passing layers ----
  for (int i = 0; i < NL; ++i) {
    hipMemsetAsync(agg, 0, (size_t)NN * HD * 4, stream);
    k_msg_direct<<<NE / 32, 256, 0, stream>>>(h, ei, u, pos, invd,
                                              m1W + (size_t)i * 260 * HD, m1b + (size_t)i * HD,
                                              m2W + (size_t)i * HD * HD, m2b + (size_t)i * HD, agg);
    hipMemsetAsync(stats, 0, 256 * 8, stream);
    k_upd<<<nt32, 256, 0, stream>>>(h, agg, pos,
                                    u1W + (size_t)i * 257 * HD, u1b + (size_t)i * HD,
                                    u2W + (size_t)i * HD * HD, u2b + (size_t)i * HD, stats);
    k_redA<<<1, 128, 0, stream>>>(stats, musig);
    k_bn<<<nbBN, 256, 0, stream>>>(h, musig, bng + (size_t)i * HD, bnb + (size_t)i * HD, 0);
  }

  // ---- CNN head ----
  k_conv<<<NN / 4, 256, 0, stream>>>(h, c1W, c1b, c2W, c2b, c3W, c3b, out);
}

// Round 12
// 10600.600 us; speedup vs baseline: 2.0362x; 2.0362x over previous
//
#include <hip/hip_runtime.h>

#define NN 50000
#define NE 600000
#define HD 128
#define NL 6

__global__ void k_code(float* __restrict__ out, float code) {
  if (threadIdx.x == 0 && blockIdx.x == 0) out[0] = code;
}

// ---------------- degree histogram, scan, counting sort (by dst) ----------------

__global__ __launch_bounds__(256) void k_deg(const int* __restrict__ ei, int* __restrict__ deg) {
  int e = blockIdx.x * 256 + threadIdx.x;
  if (e < NE) {
    int d = ei[NE + e];
    if (d >= 0 && d < NN) atomicAdd(&deg[d], 1);
  }
}

__global__ __launch_bounds__(256) void k_scan1(const int* __restrict__ deg, int* __restrict__ cursor,
                                               int* __restrict__ blk, float* __restrict__ invd) {
  __shared__ int sd[256];
  int t = threadIdx.x;
  int i = blockIdx.x * 256 + t;
  int v = (i < NN) ? deg[i] : 0;
  sd[t] = v;
  __syncthreads();
  for (int off = 1; off < 256; off <<= 1) {
    int x = (t >= off) ? sd[t - off] : 0;
    __syncthreads();
    if (t >= off) sd[t] += x;
    __syncthreads();
  }
  int incl = sd[t];
  if (i < NN) {
    cursor[i] = incl - v;                       // local exclusive
    invd[i] = 1.0f / fmaxf((float)v, 1.0f);
  }
  if (t == 255) blk[blockIdx.x] = incl;
}

__global__ __launch_bounds__(256) void k_scan2(int* __restrict__ blk, int nb) {
  __shared__ int sd[256];
  int t = threadIdx.x;
  int v = (t < nb) ? blk[t] : 0;
  sd[t] = v;
  __syncthreads();
  for (int off = 1; off < 256; off <<= 1) {
    int x = (t >= off) ? sd[t - off] : 0;
    __syncthreads();
    if (t >= off) sd[t] += x;
    __syncthreads();
  }
  if (t < nb) blk[t] = sd[t] - v;               // exclusive block offsets
}

__global__ __launch_bounds__(256) void k_scan3(int* __restrict__ cursor, const int* __restrict__ blk) {
  int i = blockIdx.x * 256 + threadIdx.x;
  if (i < NN) cursor[i] += blk[blockIdx.x];
}

__global__ __launch_bounds__(256) void k_scatter(const int* __restrict__ ei, const float* __restrict__ u,
                                                 const float* __restrict__ pos, int* __restrict__ cursor,
                                                 int* __restrict__ ssrc, int* __restrict__ sdst,
                                                 float* __restrict__ sfeat) {
  int e = blockIdx.x * 256 + threadIdx.x;
  if (e >= NE) return;
  int s = ei[e], d = ei[NE + e];
  s = s < 0 ? 0 : (s >= NN ? NN - 1 : s);
  d = d < 0 ? 0 : (d >= NN ? NN - 1 : d);
  int p = atomicAdd(&cursor[d], 1);
  ssrc[p] = s;
  sdst[p] = d;
  float du  = u[d] - u[s];
  float dpx = pos[d*3+1] - pos[s*3+1];   // LX = 1
  float dpy = pos[d*3+2] - pos[s*3+2];   // LY = 1
  float vi  = pos[d*3+0];                // TMAX = 1
  ((float4*)sfeat)[p] = make_float4(du, dpx, dpy, vi);
}

// ---------------- embedding ----------------

__global__ __launch_bounds__(256) void k_emb1(const float* __restrict__ u, const float* __restrict__ pos,
                                              const float* __restrict__ W, const float* __restrict__ b,
                                              float* __restrict__ h, double* __restrict__ stats) {
  __shared__ float xs[32 * 129];
  int tid = threadIdx.x;
  int nl = tid & 31, jg = tid >> 5;
  int gn = blockIdx.x * 32 + nl;
  float f0 = 0.f, f1 = 0.f, f2 = 0.f, f3 = 0.f;
  if (gn < NN) { f0 = u[gn]; f1 = pos[gn*3+1]; f2 = pos[gn*3+2]; f3 = pos[gn*3+0]; }
  float x[16];
#pragma unroll
  for (int q = 0; q < 4; ++q) {
    int j = (jg << 4) + (q << 2);
    float4 w0 = *(const float4*)(W + 0*HD + j);
    float4 w1 = *(const float4*)(W + 1*HD + j);
    float4 w2 = *(const float4*)(W + 2*HD + j);
    float4 w3 = *(const float4*)(W + 3*HD + j);
    float4 bb = *(const float4*)(b + j);
    x[q*4+0] = f0*w0.x + f1*w1.x + f2*w2.x + f3*w3.x + bb.x;
    x[q*4+1] = f0*w0.y + f1*w1.y + f2*w2.y + f3*w3.y + bb.y;
    x[q*4+2] = f0*w0.z + f1*w1.z + f2*w2.z + f3*w3.z + bb.z;
    x[q*4+3] = f0*w0.w + f1*w1.w + f2*w2.w + f3*w3.w + bb.w;
  }
  if (gn < NN) {
#pragma unroll
    for (int q = 0; q < 4; ++q)
      *(float4*)(h + (size_t)gn*HD + (jg<<4) + (q<<2)) = make_float4(x[q*4+0], x[q*4+1], x[q*4+2], x[q*4+3]);
  }
#pragma unroll
  for (int i = 0; i < 16; ++i) xs[nl*129 + (jg<<4) + i] = (gn < NN) ? x[i] : 0.f;
  __syncthreads();
  if (tid < HD) {
    double s = 0.0, sq = 0.0;
    for (int e = 0; e < 32; ++e) { double v = (double)xs[e*129 + tid]; s += v; sq += v*v; }
    atomicAdd(&stats[tid], s);
    atomicAdd(&stats[HD + tid], sq);
  }
}

__global__ __launch_bounds__(256) void k_emb2(float* __restrict__ h, const float* __restrict__ W,
                                              const float* __restrict__ b, double* __restrict__ stats) {
  __shared__ float hs[32 * 129];
  int tid = threadIdx.x;
  int base = blockIdx.x * 32;
#pragma unroll
  for (int r = 0; r < 16; ++r) {
    int lin = r*256 + tid;
    int n = lin >> 7, j = lin & 127;
    int gn = base + n;
    hs[n*129 + j] = (gn < NN) ? h[(size_t)gn*HD + j] : 0.f;
  }
  __syncthreads();
  int nl = tid & 31, jg = tid >> 5;
  int gn = base + nl;
  float acc[16];
#pragma unroll
  for (int q = 0; q < 4; ++q) {
    float4 bb = *(const float4*)(b + (jg<<4) + (q<<2));
    acc[q*4+0] = bb.x; acc[q*4+1] = bb.y; acc[q*4+2] = bb.z; acc[q*4+3] = bb.w;
  }
  for (int k = 0; k < HD; ++k) {
    float a = hs[nl*129 + k];
    const float4* wp = (const float4*)(W + (size_t)k*HD + (jg<<4));
#pragma unroll
    for (int q = 0; q < 4; ++q) {
      float4 wv = wp[q];
      acc[q*4+0] = fmaf(a, wv.x, acc[q*4+0]);
      acc[q*4+1] = fmaf(a, wv.y, acc[q*4+1]);
      acc[q*4+2] = fmaf(a, wv.z, acc[q*4+2]);
      acc[q*4+3] = fmaf(a, wv.w, acc[q*4+3]);
    }
  }
  if (gn < NN) {
#pragma unroll
    for (int q = 0; q < 4; ++q)
      *(float4*)(h + (size_t)gn*HD + (jg<<4) + (q<<2)) = make_float4(acc[q*4+0], acc[q*4+1], acc[q*4+2], acc[q*4+3]);
  }
  __syncthreads();
#pragma unroll
  for (int i = 0; i < 16; ++i) hs[nl*129 + (jg<<4) + i] = (gn < NN) ? acc[i] : 0.f;
  __syncthreads();
  if (tid < HD) {
    double s = 0.0, sq = 0.0;
    for (int e = 0; e < 32; ++e) { double v = (double)hs[e*129 + tid]; s += v; sq += v*v; }
    atomicAdd(&stats[tid], s);
    atomicAdd(&stats[HD + tid], sq);
  }
}

__global__ void k_redA(const double* __restrict__ stats, float* __restrict__ musig) {
  int c = threadIdx.x;   // 128
  double mu  = stats[c] / (double)NN;
  double var = stats[128 + c] / (double)NN - mu * mu;
  musig[c]      = (float)mu;
  musig[HD + c] = (float)(1.0 / sqrt(var + 1e-5));
}

__global__ __launch_bounds__(256) void k_bn(float* __restrict__ h, const float* __restrict__ musig,
                                            const float* __restrict__ g, const float* __restrict__ be,
                                            int relu) {
  int idx = blockIdx.x * 256 + threadIdx.x;
  if (idx >= NN * HD) return;
  int j = idx & 127;
  float x = h[idx];
  x = g[j] * (x - musig[j]) * musig[HD + j] + be[j];
  if (relu) x = fmaxf(x, 0.f);
  h[idx] = x;
}

// ---------------- hoisted node GEMMs: A = h@W1[0:128], B = h@W1[128:256] ----------------

__global__ __launch_bounds__(256) void k_ab(const float* __restrict__ h, const float* __restrict__ W,
                                            float* __restrict__ A, float* __restrict__ B) {
  __shared__ float hs[32 * 129];
  int tid = threadIdx.x;
  int base = blockIdx.x * 32;
#pragma unroll
  for (int r = 0; r < 16; ++r) {
    int lin = r*256 + tid;
    int n = lin >> 7, j = lin & 127;
    int gn = base + n;
    hs[n*129 + j] = (gn < NN) ? h[(size_t)gn*HD + j] : 0.f;
  }
  __syncthreads();
  int nl = tid & 31, jg = tid >> 5;
  int gn = base + nl;
  float accA[16], accB[16];
#pragma unroll
  for (int i = 0; i < 16; ++i) { accA[i] = 0.f; accB[i] = 0.f; }
  const float* Wa = W;                 // rows 0..127   (h[dst] part)
  const float* Wb = W + 128 * HD;      // rows 128..255 (h[src] part)
  for (int k = 0; k < HD; ++k) {
    float a = hs[nl*129 + k];
    const float4* wa = (const float4*)(Wa + (size_t)k*HD + (jg<<4));
    const float4* wb = (const float4*)(Wb + (size_t)k*HD + (jg<<4));
#pragma unroll
    for (int q = 0; q < 4; ++q) {
      float4 w1 = wa[q];
      accA[q*4+0] = fmaf(a, w1.x, accA[q*4+0]);
      accA[q*4+1] = fmaf(a, w1.y, accA[q*4+1]);
      accA[q*4+2] = fmaf(a, w1.z, accA[q*4+2]);
      accA[q*4+3] = fmaf(a, w1.w, accA[q*4+3]);
    }
#pragma unroll
    for (int q = 0; q < 4; ++q) {
      float4 w2 = wb[q];
      accB[q*4+0] = fmaf(a, w2.x, accB[q*4+0]);
      accB[q*4+1] = fmaf(a, w2.y, accB[q*4+1]);
      accB[q*4+2] = fmaf(a, w2.z, accB[q*4+2]);
      accB[q*4+3] = fmaf(a, w2.w, accB[q*4+3]);
    }
  }
  if (gn < NN) {
#pragma unroll
    for (int q = 0; q < 4; ++q) {
      *(float4*)(A + (size_t)gn*HD + (jg<<4) + (q<<2)) = make_float4(accA[q*4+0], accA[q*4+1], accA[q*4+2], accA[q*4+3]);
      *(float4*)(B + (size_t)gn*HD + (jg<<4) + (q<<2)) = make_float4(accB[q*4+0], accB[q*4+1], accB[q*4+2], accB[q*4+3]);
    }
  }
}

// ---------------- edge message MLP (sorted) + segmented aggregation ----------------
// 32 dst-sorted edges per block. m1 = relu(A[dst]+B[src]+feats@W1[256:260]+b1);
// m2 = relu(m1@W2+b2); segmented column-sum by dst, scaled by invd, atomic flush.

__global__ __launch_bounds__(256) void k_msg(const float* __restrict__ A, const float* __restrict__ B,
                                             const int* __restrict__ ssrc, const int* __restrict__ sdst,
                                             const float* __restrict__ sfeat, const float* __restrict__ invd,
                                             const float* __restrict__ W1, const float* __restrict__ b1,
                                             const float* __restrict__ W2, const float* __restrict__ b2,
                                             float* __restrict__ agg) {
  __shared__ float m1s[32 * 129];
  __shared__ float m2s[32 * 129];
  __shared__ int lsrc[32];
  __shared__ int ldst[32];
  __shared__ float lfeat[32][4];
  int tid = threadIdx.x;
  int base = blockIdx.x * 32;     // NE % 32 == 0
  if (tid < 32) { lsrc[tid] = ssrc[base + tid]; ldst[tid] = sdst[base + tid]; }
  if (tid < 128) ((float*)lfeat)[tid] = sfeat[(size_t)base*4 + tid];
  __syncthreads();
  int el = tid & 31, jg = tid >> 5;
  int s = lsrc[el], d = ldst[el];
  float f0 = lfeat[el][0], f1 = lfeat[el][1], f2 = lfeat[el][2], f3 = lfeat[el][3];
  const float* Arow = A + (size_t)d*HD + (jg<<4);
  const float* Brow = B + (size_t)s*HD + (jg<<4);
  const float* We = W1 + 256*HD + (jg<<4);
  float m1[16];
#pragma unroll
  for (int q = 0; q < 4; ++q) {
    float4 av = *(const float4*)(Arow + (q<<2));
    float4 bv = *(const float4*)(Brow + (q<<2));
    float4 w0 = *(const float4*)(We + 0*HD + (q<<2));
    float4 w1 = *(const float4*)(We + 1*HD + (q<<2));
    float4 w2 = *(const float4*)(We + 2*HD + (q<<2));
    float4 w3 = *(const float4*)(We + 3*HD + (q<<2));
    float4 bb = *(const float4*)(b1 + (jg<<4) + (q<<2));
    m1[q*4+0] = fmaxf(av.x + bv.x + f0*w0.x + f1*w1.x + f2*w2.x + f3*w3.x + bb.x, 0.f);
    m1[q*4+1] = fmaxf(av.y + bv.y + f0*w0.y + f1*w1.y + f2*w2.y + f3*w3.y + bb.y, 0.f);
    m1[q*4+2] = fmaxf(av.z + bv.z + f0*w0.z + f1*w1.z + f2*w2.z + f3*w3.z + bb.z, 0.f);
    m1[q*4+3] = fmaxf(av.w + bv.w + f0*w0.w + f1*w1.w + f2*w2.w + f3*w3.w + bb.w, 0.f);
  }
#pragma unroll
  for (int i = 0; i < 16; ++i) m1s[el*129 + (jg<<4) + i] = m1[i];
  __syncthreads();
  float acc[16];
#pragma unroll
  for (int q = 0; q < 4; ++q) {
    float4 bb = *(const float4*)(b2 + (jg<<4) + (q<<2));
    acc[q*4+0] = bb.x; acc[q*4+1] = bb.y; acc[q*4+2] = bb.z; acc[q*4+3] = bb.w;
  }
  for (int k = 0; k < HD; ++k) {
    float a = m1s[el*129 + k];
    const float4* wp = (const float4*)(W2 + (size_t)k*HD + (jg<<4));
#pragma unroll
    for (int q = 0; q < 4; ++q) {
      float4 wv = wp[q];
      acc[q*4+0] = fmaf(a, wv.x, acc[q*4+0]);
      acc[q*4+1] = fmaf(a, wv.y, acc[q*4+1]);
      acc[q*4+2] = fmaf(a, wv.z, acc[q*4+2]);
      acc[q*4+3] = fmaf(a, wv.w, acc[q*4+3]);
    }
  }
#pragma unroll
  for (int i = 0; i < 16; ++i) m2s[el*129 + (jg<<4) + i] = fmaxf(acc[i], 0.f);
  __syncthreads();
  if (tid < HD) {
    int j = tid;
    float a2 = 0.f;
    int cur = ldst[0];
    for (int e = 0; e < 32; ++e) {
      int de = ldst[e];                       // wave-uniform across j-threads
      if (de != cur) {
        atomicAdd(&agg[(size_t)cur*HD + j], a2 * invd[cur]);
        a2 = 0.f;
        cur = de;
      }
      a2 += m2s[e*129 + j];
    }
    atomicAdd(&agg[(size_t)cur*HD + j], a2 * invd[cur]);
  }
}

// ---------------- fallback: direct edge MLP + naive atomics (unsorted) ----------------

__global__ __launch_bounds__(256) void k_msg_direct(const float* __restrict__ h,
                                                    const int* __restrict__ ei, const float* __restrict__ u,
                                                    const float* __restrict__ pos, const float* __restrict__ invd,
                                                    const float* __restrict__ W1, const float* __restrict__ b1,
                                                    const float* __restrict__ W2, const float* __restrict__ b2,
                                                    float* __restrict__ agg) {
  __shared__ float hd[32 * 129];
  __shared__ float hsr[32 * 129];
  __shared__ float m1s[32 * 129];
  __shared__ int lsrc[32];
  __shared__ int ldst[32];
  __shared__ float lf[32][4];
  int tid = threadIdx.x;
  int base = blockIdx.x * 32;
  if (tid < 32) {
    int e = base + tid;
    int s = ei[e], d = ei[NE + e];
    s = s < 0 ? 0 : (s >= NN ? NN - 1 : s);
    d = d < 0 ? 0 : (d >= NN ? NN - 1 : d);
    lsrc[tid] = s; ldst[tid] = d;
    lf[tid][0] = u[d] - u[s];
    lf[tid][1] = pos[d*3+1] - pos[s*3+1];
    lf[tid][2] = pos[d*3+2] - pos[s*3+2];
    lf[tid][3] = pos[d*3+0];
  }
  __syncthreads();
#pragma unroll
  for (int r = 0; r < 16; ++r) {
    int lin = r*256 + tid;
    int n = lin >> 7, j = lin & 127;
    hd[n*129 + j]  = h[(size_t)ldst[n]*HD + j];
    hsr[n*129 + j] = h[(size_t)lsrc[n]*HD + j];
  }
  __syncthreads();
  int el = tid & 31, jg = tid >> 5;
  float f0 = lf[el][0], f1 = lf[el][1], f2 = lf[el][2], f3 = lf[el][3];
  const float* We = W1 + 256*HD + (jg<<4);
  float acc[16];
#pragma unroll
  for (int q = 0; q < 4; ++q) {
    float4 w0 = *(const float4*)(We + 0*HD + (q<<2));
    float4 w1 = *(const float4*)(We + 1*HD + (q<<2));
    float4 w2 = *(const float4*)(We + 2*HD + (q<<2));
    float4 w3 = *(const float4*)(We + 3*HD + (q<<2));
    float4 bb = *(const float4*)(b1 + (jg<<4) + (q<<2));
    acc[q*4+0] = f0*w0.x + f1*w1.x + f2*w2.x + f3*w3.x + bb.x;
    acc[q*4+1] = f0*w0.y + f1*w1.y + f2*w2.y + f3*w3.y + bb.y;
    acc[q*4+2] = f0*w0.z + f1*w1.z + f2*w2.z + f3*w3.z + bb.z;
    acc[q*4+3] = f0*w0.w + f1*w1.w + f2*w2.w + f3*w3.w + bb.w;
  }
  for (int k = 0; k < HD; ++k) {
    float a  = hd[el*129 + k];
    float bs = hsr[el*129 + k];
    const float4* wa = (const float4*)(W1 + (size_t)k*HD + (jg<<4));
    const float4* wb = (const float4*)(W1 + (size_t)(128 + k)*HD + (jg<<4));
#pragma unroll
    for (int q = 0; q < 4; ++q) {
      float4 w1v = wa[q];
      float4 w2v = wb[q];
      acc[q*4+0] = fmaf(a, w1v.x, fmaf(bs, w2v.x, acc[q*4+0]));
      acc[q*4+1] = fmaf(a, w1v.y, fmaf(bs, w2v.y, acc[q*4+1]));
      acc[q*4+2] = fmaf(a, w1v.z, fmaf(bs, w2v.z, acc[q*4+2]));
      acc[q*4+3] = fmaf(a, w1v.w, fmaf(bs, w2v.w, acc[q*4+3]));
    }
  }
#pragma unroll
  for (int i = 0; i < 16; ++i) m1s[el*129 + (jg<<4) + i] = fmaxf(acc[i], 0.f);
  __syncthreads();
  float acc2[16];
#pragma unroll
  for (int q = 0; q < 4; ++q) {
    float4 bb = *(const float4*)(b2 + (jg<<4) + (q<<2));
    acc2[q*4+0] = bb.x; acc2[q*4+1] = bb.y; acc2[q*4+2] = bb.z; acc2[q*4+3] = bb.w;
  }
  for (int k = 0; k < HD; ++k) {
    float a = m1s[el*129 + k];
    const float4* wp = (const float4*)(W2 + (size_t)k*HD + (jg<<4));
#pragma unroll
    for (int q = 0; q < 4; ++q) {
      float4 wv = wp[q];
      acc2[q*4+0] = fmaf(a, wv.x, acc2[q*4+0]);
      acc2[q*4+1] = fmaf(a, wv.y, acc2[q*4+1]);
      acc2[q*4+2] = fmaf(a, wv.z, acc2[q*4+2]);
      acc2[q*4+3] = fmaf(a, wv.w, acc2[q*4+3]);
    }
  }
#pragma unroll
  for (int i = 0; i < 16; ++i) hd[el*129 + (jg<<4) + i] = fmaxf(acc2[i], 0.f);
  __syncthreads();
  if (tid < HD) {
    int j = tid;
    for (int e = 0; e < 32; ++e) {
      int de = ldst[e];
      atomicAdd(&agg[(size_t)de*HD + j], hd[e*129 + j] * invd[de]);
    }
  }
}

// ---------------- node update MLP ----------------

__global__ __launch_bounds__(256) void k_upd(float* __restrict__ h, const float* __restrict__ agg,
                                             const float* __restrict__ pos,
                                             const float* __restrict__ W1, const float* __restrict__ b1,
                                             const float* __restrict__ W2, const float* __restrict__ b2,
                                             double* __restrict__ stats) {
  __shared__ float hs[32 * 129];
  __shared__ float as_[32 * 129];
  int tid = threadIdx.x;
  int base = blockIdx.x * 32;
#pragma unroll
  for (int r = 0; r < 16; ++r) {
    int lin = r*256 + tid;
    int n = lin >> 7, j = lin & 127;
    int gn = base + n;
    hs[n*129 + j]  = (gn < NN) ? h[(size_t)gn*HD + j]   : 0.f;
    as_[n*129 + j] = (gn < NN) ? agg[(size_t)gn*HD + j] : 0.f;
  }
  __syncthreads();
  int nl = tid & 31, jg = tid >> 5;
  int gn = base + nl;
  float var = (gn < NN) ? pos[gn*3+0] : 0.f;
  float acc[16];
#pragma unroll
  for (int q = 0; q < 4; ++q) {
    int j = (jg<<4) + (q<<2);
    float4 bb = *(const float4*)(b1 + j);
    float4 wv = *(const float4*)(W1 + 256*HD + j);
    acc[q*4+0] = fmaf(var, wv.x, bb.x);
    acc[q*4+1] = fmaf(var, wv.y, bb.y);
    acc[q*4+2] = fmaf(var, wv.z, bb.z);
    acc[q*4+3] = fmaf(var, wv.w, bb.w);
  }
  for (int k = 0; k < HD; ++k) {
    float a = hs[nl*129 + k];
    float g = as_[nl*129 + k];
    const float4* w1p = (const float4*)(W1 + (size_t)k*HD + (jg<<4));
    const float4* w2p = (const float4*)(W1 + (size_t)(128 + k)*HD + (jg<<4));
#pragma unroll
    for (int q = 0; q < 4; ++q) {
      float4 wa = w1p[q];
      float4 wb = w2p[q];
      acc[q*4+0] = fmaf(a, wa.x, fmaf(g, wb.x, acc[q*4+0]));
      acc[q*4+1] = fmaf(a, wa.y, fmaf(g, wb.y, acc[q*4+1]));
      acc[q*4+2] = fmaf(a, wa.z, fmaf(g, wb.z, acc[q*4+2]));
      acc[q*4+3] = fmaf(a, wa.w, fmaf(g, wb.w, acc[q*4+3]));
    }
  }
  float up1[16];
#pragma unroll
  for (int i = 0; i < 16; ++i) up1[i] = fmaxf(acc[i], 0.f);
  __syncthreads();
#pragma unroll
  for (int i = 0; i < 16; ++i) as_[nl*129 + (jg<<4) + i] = up1[i];
  __syncthreads();
  float acc2[16];
#pragma unroll
  for (int q = 0; q < 4; ++q) {
    float4 bb = *(const float4*)(b2 + (jg<<4) + (q<<2));
    acc2[q*4+0] = bb.x; acc2[q*4+1] = bb.y; acc2[q*4+2] = bb.z; acc2[q*4+3] = bb.w;
  }
  for (int k = 0; k < HD; ++k) {
    float a = as_[nl*129 + k];
    const float4* wp = (const float4*)(W2 + (size_t)k*HD + (jg<<4));
#pragma unroll
    for (int q = 0; q < 4; ++q) {
      float4 wv = wp[q];
      acc2[q*4+0] = fmaf(a, wv.x, acc2[q*4+0]);
      acc2[q*4+1] = fmaf(a, wv.y, acc2[q*4+1]);
      acc2[q*4+2] = fmaf(a, wv.z, acc2[q*4+2]);
      acc2[q*4+3] = fmaf(a, wv.w, acc2[q*4+3]);
    }
  }
  float x[16];
#pragma unroll
  for (int i = 0; i < 16; ++i)
    x[i] = hs[nl*129 + (jg<<4) + i] + fmaxf(acc2[i], 0.f);
  if (gn < NN) {
#pragma unroll
    for (int q = 0; q < 4; ++q)
      *(float4*)(h + (size_t)gn*HD + (jg<<4) + (q<<2)) = make_float4(x[q*4+0], x[q*4+1], x[q*4+2], x[q*4+3]);
  }
  __syncthreads();
#pragma unroll
  for (int i = 0; i < 16; ++i) hs[nl*129 + (jg<<4) + i] = (gn < NN) ? x[i] : 0.f;
  __syncthreads();
  if (tid < HD) {
    double s = 0.0, sq = 0.0;
    for (int e = 0; e < 32; ++e) { double v = (double)hs[e*129 + tid]; s += v; sq += v*v; }
    atomicAdd(&stats[tid], s);
    atomicAdd(&stats[HD + tid], sq);
  }
}

// ---------------- CNN head (full 72-slot o2 coverage) ----------------

__global__ __launch_bounds__(256) void k_conv(const float* __restrict__ h,
                                              const float* __restrict__ c1W, const float* __restrict__ c1b,
                                              const float* __restrict__ c2W, const float* __restrict__ c2b,
                                              const float* __restrict__ c3W, const float* __restrict__ c3b,
                                              float* __restrict__ out) {
  __shared__ float xs[4][128];
  __shared__ float o1[4][152];
  __shared__ float o2[4][72];
  int tid = threadIdx.x;
  int w = tid >> 6, lane = tid & 63;
  int n = blockIdx.x * 4 + w;          // NN % 4 == 0
  xs[w][lane]      = h[(size_t)n*HD + lane];
  xs[w][64 + lane] = h[(size_t)n*HD + 64 + lane];
  __syncthreads();
  for (int o = lane; o < 152; o += 64) {
    int oc = o / 38, t = o % 38;
    float s = c1b[oc];
#pragma unroll
    for (int k = 0; k < 16; ++k) s = fmaf(xs[w][t*3 + k], c1W[oc*16 + k], s);
    o1[w][oc*38 + t] = fmaxf(s, 0.f);
  }
  __syncthreads();
  for (int o = lane; o < 72; o += 64) {       // full coverage (R8 bug fix)
    int oc = o / 9, t = o % 9;
    float s = c2b[oc];
    for (int ic = 0; ic < 4; ++ic) {
#pragma unroll
      for (int k = 0; k < 12; ++k) s = fmaf(o1[w][ic*38 + t*3 + k], c2W[oc*48 + ic*12 + k], s);
    }
    o2[w][oc*9 + t] = fmaxf(s, 0.f);
  }
  __syncthreads();
  int ic = lane >> 3, k = lane & 7;
  float t3 = o2[w][ic*9 + k] * c3W[ic*8 + k];
  for (int off = 32; off; off >>= 1) t3 += __shfl_down(t3, off);
  if (lane == 0) out[n] = 0.001f * (t3 + c3b[0]);   // dt = cumsum(DT*0.1), TW=1
}

// ---------------- launcher ----------------

extern "C" void kernel_launch(void* const* d_in, const int* in_sizes, int n_in,
                              void* d_out, int out_size, void* d_ws, size_t ws_size,
                              hipStream_t stream) {
  (void)out_size;
  float* out = (float*)d_out;

  static const int expect[27] = {
    50000, 150000, 1200000,
    512, 128, 128, 128,
    16384, 128, 128, 128,
    199680, 768, 98304, 768, 197376, 768, 98304, 768,
    768, 768,
    64, 4, 384, 8, 64, 1
  };
  if (n_in != 27) { k_code<<<1, 64, 0, stream>>>(out, 5000099.f); return; }
  for (int i = 0; i < 27; ++i)
    if (in_sizes[i] != expect[i]) { k_code<<<1, 64, 0, stream>>>(out, 5000100.f + (float)i); return; }

  const float* u    = (const float*)d_in[0];
  const float* pos  = (const float*)d_in[1];
  const int*   ei   = (const int*)d_in[2];
  const float* eW1  = (const float*)d_in[3];
  const float* eb1  = (const float*)d_in[4];
  const float* eg1  = (const float*)d_in[5];
  const float* ebe1 = (const float*)d_in[6];
  const float* eW2  = (const float*)d_in[7];
  const float* eb2  = (const float*)d_in[8];
  const float* eg2  = (const float*)d_in[9];
  const float* ebe2 = (const float*)d_in[10];
  const float* m1W  = (const float*)d_in[11];
  const float* m1b  = (const float*)d_in[12];
  const float* m2W  = (const float*)d_in[13];
  const float* m2b  = (const float*)d_in[14];
  const float* u1W  = (const float*)d_in[15];
  const float* u1b  = (const float*)d_in[16];
  const float* u2W  = (const float*)d_in[17];
  const float* u2b  = (const float*)d_in[18];
  const float* bng  = (const float*)d_in[19];
  const float* bnb  = (const float*)d_in[20];
  const float* c1W  = (const float*)d_in[21];
  const float* c1b  = (const float*)d_in[22];
  const float* c2W  = (const float*)d_in[23];
  const float* c2b  = (const float*)d_in[24];
  const float* c3W  = (const float*)d_in[25];
  const float* c3b  = (const float*)d_in[26];

  // ---- workspace ----
  char* wsp = (char*)d_ws;
  size_t off = 0;
  auto alloc = [&](size_t bytes) -> void* {
    void* p = wsp + off;
    off = (off + bytes + 255) & ~(size_t)255;
    return p;
  };
  double* stats  = (double*)alloc(256 * 8);
  float*  musig  = (float*)alloc(256 * 4);
  int*    deg    = (int*)alloc((size_t)NN * 4);
  int*    cursor = (int*)alloc((size_t)NN * 4);
  int*    blk    = (int*)alloc(256 * 4);
  float*  invd   = (float*)alloc((size_t)NN * 4);
  float*  h      = (float*)alloc((size_t)NN * HD * 4);
  float*  agg    = (float*)alloc((size_t)NN * HD * 4);
  size_t needed_direct = off;
  float*  A      = (float*)alloc((size_t)NN * HD * 4);
  float*  B      = (float*)alloc((size_t)NN * HD * 4);
  float*  sfeat  = (float*)alloc((size_t)NE * 4 * 4);
  int*    ssrc   = (int*)alloc((size_t)NE * 4);
  int*    sdst   = (int*)alloc((size_t)NE * 4);
  size_t needed_fast = off;

  if (ws_size < needed_direct) {
    k_code<<<1, 64, 0, stream>>>(out, (float)(9000000u + (unsigned)(ws_size >> 20)));
    return;
  }
  const bool fast = (ws_size >= needed_fast);

  const int nbN  = (NN + 255) / 256;   // 196
  const int nbE  = (NE + 255) / 256;   // 2344
  const int nt32 = (NN + 31) / 32;     // 1563
  const int nbBN = NN * HD / 256;      // 25000

  // ---- degree / inverse degree (+ sort if fast) ----
  hipMemsetAsync(deg, 0, (size_t)NN * 4, stream);
  k_deg<<<nbE, 256, 0, stream>>>(ei, deg);
  k_scan1<<<nbN, 256, 0, stream>>>(deg, cursor, blk, invd);
  if (fast) {
    k_scan2<<<1, 256, 0, stream>>>(blk, nbN);
    k_scan3<<<nbN, 256, 0, stream>>>(cursor, blk);
    k_scatter<<<nbE, 256, 0, stream>>>(ei, u, pos, cursor, ssrc, sdst, sfeat);
  }

  // ---- embedding ----
  hipMemsetAsync(stats, 0, 256 * 8, stream);
  k_emb1<<<nt32, 256, 0, stream>>>(u, pos, eW1, eb1, h, stats);
  k_redA<<<1, 128, 0, stream>>>(stats, musig);
  k_bn<<<nbBN, 256, 0, stream>>>(h, musig, eg1, ebe1, 1);
  hipMemsetAsync(stats, 0, 256 * 8, stream);
  k_emb2<<<nt32, 256, 0, stream>>>(h, eW2, eb2, stats);
  k_redA<<<1, 128, 0, stream>>>(stats, musig);
  k_bn<<<nbBN, 256, 0, stream>>>(h, musig, eg2, ebe2, 0);

  // ---- message-passing layers ----
  for (int i = 0; i < NL; ++i) {
    hipMemsetAsync(agg, 0, (size_t)NN * HD * 4, stream);
    if (fast) {
      k_ab<<<nt32, 256, 0, stream>>>(h, m1W + (size_t)i * 260 * HD, A, B);
      k_msg<<<NE / 32, 256, 0, stream>>>(A, B, ssrc, sdst, sfeat, invd,
                                         m1W + (size_t)i * 260 * HD, m1b + (size_t)i * HD,
                                         m2W + (size_t)i * HD * HD, m2b + (size_t)i * HD, agg);
    } else {
      k_msg_direct<<<NE / 32, 256, 0, stream>>>(h, ei, u, pos, invd,
                                                m1W + (size_t)i * 260 * HD, m1b + (size_t)i * HD,
                                                m2W + (size_t)i * HD * HD, m2b + (size_t)i * HD, agg);
    }
    hipMemsetAsync(stats, 0, 256 * 8, stream);
    k_upd<<<nt32, 256, 0, stream>>>(h, agg, pos,
                                    u1W + (size_t)i * 257 * HD, u1b + (size_t)i * HD,
                                    u2W + (size_t)i * HD * HD, u2b + (size_t)i * HD, stats);
    k_redA<<<1, 128, 0, stream>>>(stats, musig);
    k_bn<<<nbBN, 256, 0, stream>>>(h, musig, bng + (size_t)i * HD, bnb + (size_t)i * HD, 0);
  }

  // ---- CNN head ----
  k_conv<<<NN / 4, 256, 0, stream>>>(h, c1W, c1b, c2W, c2b, c3W, c3b, out);
}

// Round 15
// 5202.393 us; speedup vs baseline: 4.1491x; 2.0376x over previous
//
#include <hip/hip_runtime.h>

#define NN 50000
#define NE 600000
#define HD 128
#define NL 6

typedef __attribute__((ext_vector_type(8))) short bf16x8;
typedef __attribute__((ext_vector_type(4))) float f32x4;

__device__ inline unsigned short f2bf(float x) {
  unsigned u = __float_as_uint(x);
  u += 0x7FFF + ((u >> 16) & 1);           // round-to-nearest-even on raw bits
  return (unsigned short)(u >> 16);
}

__global__ void k_code(float* __restrict__ out, float code) {
  if (threadIdx.x == 0 && blockIdx.x == 0) out[0] = code;
}

// ---------------- W2 -> bf16 transposed [layer][n][k] ----------------

__global__ __launch_bounds__(256) void k_w2t(const float* __restrict__ W, unsigned short* __restrict__ T) {
  int idx = blockIdx.x * 256 + threadIdx.x;
  if (idx >= NL * HD * HD) return;
  int l = idx >> 14, r = idx & 16383;
  int n = r >> 7, k = r & 127;
  T[idx] = f2bf(W[(l << 14) + (k << 7) + n]);
}

// ---------------- degree histogram, scan, counting sort (by dst) ----------------

__global__ __launch_bounds__(256) void k_deg(const int* __restrict__ ei, int* __restrict__ deg) {
  int e = blockIdx.x * 256 + threadIdx.x;
  if (e < NE) {
    int d = ei[NE + e];
    if (d >= 0 && d < NN) atomicAdd(&deg[d], 1);
  }
}

__global__ __launch_bounds__(256) void k_scan1(const int* __restrict__ deg, int* __restrict__ cursor,
                                               int* __restrict__ blk, float* __restrict__ invd) {
  __shared__ int sd[256];
  int t = threadIdx.x;
  int i = blockIdx.x * 256 + t;
  int v = (i < NN) ? deg[i] : 0;
  sd[t] = v;
  __syncthreads();
  for (int off = 1; off < 256; off <<= 1) {
    int x = (t >= off) ? sd[t - off] : 0;
    __syncthreads();
    if (t >= off) sd[t] += x;
    __syncthreads();
  }
  int incl = sd[t];
  if (i < NN) {
    cursor[i] = incl - v;
    invd[i] = 1.0f / fmaxf((float)v, 1.0f);
  }
  if (t == 255) blk[blockIdx.x] = incl;
}

__global__ __launch_bounds__(256) void k_scan2(int* __restrict__ blk, int nb) {
  __shared__ int sd[256];
  int t = threadIdx.x;
  int v = (t < nb) ? blk[t] : 0;
  sd[t] = v;
  __syncthreads();
  for (int off = 1; off < 256; off <<= 1) {
    int x = (t >= off) ? sd[t - off] : 0;
    __syncthreads();
    if (t >= off) sd[t] += x;
    __syncthreads();
  }
  if (t < nb) blk[t] = sd[t] - v;
}

__global__ __launch_bounds__(256) void k_scan3(int* __restrict__ cursor, const int* __restrict__ blk) {
  int i = blockIdx.x * 256 + threadIdx.x;
  if (i < NN) cursor[i] += blk[blockIdx.x];
}

__global__ __launch_bounds__(256) void k_scatter(const int* __restrict__ ei, const float* __restrict__ u,
                                                 const float* __restrict__ pos, int* __restrict__ cursor,
                                                 int* __restrict__ ssrc, int* __restrict__ sdst,
                                                 float* __restrict__ sfeat) {
  int e = blockIdx.x * 256 + threadIdx.x;
  if (e >= NE) return;
  int s = ei[e], d = ei[NE + e];
  s = s < 0 ? 0 : (s >= NN ? NN - 1 : s);
  d = d < 0 ? 0 : (d >= NN ? NN - 1 : d);
  int p = atomicAdd(&cursor[d], 1);
  ssrc[p] = s;
  sdst[p] = d;
  float du  = u[d] - u[s];
  float dpx = pos[d*3+1] - pos[s*3+1];
  float dpy = pos[d*3+2] - pos[s*3+2];
  float vi  = pos[d*3+0];
  ((float4*)sfeat)[p] = make_float4(du, dpx, dpy, vi);
}

// ---------------- embedding ----------------

__global__ __launch_bounds__(256) void k_emb1(const float* __restrict__ u, const float* __restrict__ pos,
                                              const float* __restrict__ W, const float* __restrict__ b,
                                              float* __restrict__ h, double* __restrict__ stats) {
  __shared__ float xs[32 * 129];
  int tid = threadIdx.x;
  int nl = tid & 31, jg = tid >> 5;
  int gn = blockIdx.x * 32 + nl;
  float f0 = 0.f, f1 = 0.f, f2 = 0.f, f3 = 0.f;
  if (gn < NN) { f0 = u[gn]; f1 = pos[gn*3+1]; f2 = pos[gn*3+2]; f3 = pos[gn*3+0]; }
  float x[16];
#pragma unroll
  for (int q = 0; q < 4; ++q) {
    int j = (jg << 4) + (q << 2);
    float4 w0 = *(const float4*)(W + 0*HD + j);
    float4 w1 = *(const float4*)(W + 1*HD + j);
    float4 w2 = *(const float4*)(W + 2*HD + j);
    float4 w3 = *(const float4*)(W + 3*HD + j);
    float4 bb = *(const float4*)(b + j);
    x[q*4+0] = f0*w0.x + f1*w1.x + f2*w2.x + f3*w3.x + bb.x;
    x[q*4+1] = f0*w0.y + f1*w1.y + f2*w2.y + f3*w3.y + bb.y;
    x[q*4+2] = f0*w0.z + f1*w1.z + f2*w2.z + f3*w3.z + bb.z;
    x[q*4+3] = f0*w0.w + f1*w1.w + f2*w2.w + f3*w3.w + bb.w;
  }
  if (gn < NN) {
#pragma unroll
    for (int q = 0; q < 4; ++q)
      *(float4*)(h + (size_t)gn*HD + (jg<<4) + (q<<2)) = make_float4(x[q*4+0], x[q*4+1], x[q*4+2], x[q*4+3]);
  }
#pragma unroll
  for (int i = 0; i < 16; ++i) xs[nl*129 + (jg<<4) + i] = (gn < NN) ? x[i] : 0.f;
  __syncthreads();
  if (tid < HD) {
    double s = 0.0, sq = 0.0;
    for (int e = 0; e < 32; ++e) { double v = (double)xs[e*129 + tid]; s += v; sq += v*v; }
    atomicAdd(&stats[tid], s);
    atomicAdd(&stats[HD + tid], sq);
  }
}

__global__ __launch_bounds__(256) void k_emb2(float* __restrict__ h, const float* __restrict__ W,
                                              const float* __restrict__ b, double* __restrict__ stats) {
  __shared__ float hs[32 * 129];
  int tid = threadIdx.x;
  int base = blockIdx.x * 32;
#pragma unroll
  for (int r = 0; r < 16; ++r) {
    int lin = r*256 + tid;
    int n = lin >> 7, j = lin & 127;
    int gn = base + n;
    hs[n*129 + j] = (gn < NN) ? h[(size_t)gn*HD + j] : 0.f;
  }
  __syncthreads();
  int nl = tid & 31, jg = tid >> 5;
  int gn = base + nl;
  float acc[16];
#pragma unroll
  for (int q = 0; q < 4; ++q) {
    float4 bb = *(const float4*)(b + (jg<<4) + (q<<2));
    acc[q*4+0] = bb.x; acc[q*4+1] = bb.y; acc[q*4+2] = bb.z; acc[q*4+3] = bb.w;
  }
  for (int k = 0; k < HD; ++k) {
    float a = hs[nl*129 + k];
    const float4* wp = (const float4*)(W + (size_t)k*HD + (jg<<4));
#pragma unroll
    for (int q = 0; q < 4; ++q) {
      float4 wv = wp[q];
      acc[q*4+0] = fmaf(a, wv.x, acc[q*4+0]);
      acc[q*4+1] = fmaf(a, wv.y, acc[q*4+1]);
      acc[q*4+2] = fmaf(a, wv.z, acc[q*4+2]);
      acc[q*4+3] = fmaf(a, wv.w, acc[q*4+3]);
    }
  }
  if (gn < NN) {
#pragma unroll
    for (int q = 0; q < 4; ++q)
      *(float4*)(h + (size_t)gn*HD + (jg<<4) + (q<<2)) = make_float4(acc[q*4+0], acc[q*4+1], acc[q*4+2], acc[q*4+3]);
  }
  __syncthreads();
#pragma unroll
  for (int i = 0; i < 16; ++i) hs[nl*129 + (jg<<4) + i] = (gn < NN) ? acc[i] : 0.f;
  __syncthreads();
  if (tid < HD) {
    double s = 0.0, sq = 0.0;
    for (int e = 0; e < 32; ++e) { double v = (double)hs[e*129 + tid]; s += v; sq += v*v; }
    atomicAdd(&stats[tid], s);
    atomicAdd(&stats[HD + tid], sq);
  }
}

__global__ void k_redA(const double* __restrict__ stats, float* __restrict__ musig) {
  int c = threadIdx.x;   // 128
  double mu  = stats[c] / (double)NN;
  double var = stats[128 + c] / (double)NN - mu * mu;
  musig[c]      = (float)mu;
  musig[HD + c] = (float)(1.0 / sqrt(var + 1e-5));
}

__global__ __launch_bounds__(256) void k_bn(float* __restrict__ h, const float* __restrict__ musig,
                                            const float* __restrict__ g, const float* __restrict__ be,
                                            int relu) {
  int idx = blockIdx.x * 256 + threadIdx.x;
  if (idx >= NN * HD) return;
  int j = idx & 127;
  float x = h[idx];
  x = g[j] * (x - musig[j]) * musig[HD + j] + be[j];
  if (relu) x = fmaxf(x, 0.f);
  h[idx] = x;
}

// ---------------- hoisted node GEMMs: A = h@W1[0:128], B = h@W1[128:256] ----------------

__global__ __launch_bounds__(256) void k_ab(const float* __restrict__ h, const float* __restrict__ W,
                                            float* __restrict__ A, float* __restrict__ B) {
  __shared__ float hs[32 * 129];
  int tid = threadIdx.x;
  int base = blockIdx.x * 32;
#pragma unroll
  for (int r = 0; r < 16; ++r) {
    int lin = r*256 + tid;
    int n = lin >> 7, j = lin & 127;
    int gn = base + n;
    hs[n*129 + j] = (gn < NN) ? h[(size_t)gn*HD + j] : 0.f;
  }
  __syncthreads();
  int nl = tid & 31, jg = tid >> 5;
  int gn = base + nl;
  float accA[16], accB[16];
#pragma unroll
  for (int i = 0; i < 16; ++i) { accA[i] = 0.f; accB[i] = 0.f; }
  const float* Wa = W;
  const float* Wb = W + 128 * HD;
  for (int k = 0; k < HD; ++k) {
    float a = hs[nl*129 + k];
    const float4* wa = (const float4*)(Wa + (size_t)k*HD + (jg<<4));
    const float4* wb = (const float4*)(Wb + (size_t)k*HD + (jg<<4));
#pragma unroll
    for (int q = 0; q < 4; ++q) {
      float4 w1 = wa[q];
      accA[q*4+0] = fmaf(a, w1.x, accA[q*4+0]);
      accA[q*4+1] = fmaf(a, w1.y, accA[q*4+1]);
      accA[q*4+2] = fmaf(a, w1.z, accA[q*4+2]);
      accA[q*4+3] = fmaf(a, w1.w, accA[q*4+3]);
    }
#pragma unroll
    for (int q = 0; q < 4; ++q) {
      float4 w2 = wb[q];
      accB[q*4+0] = fmaf(a, w2.x, accB[q*4+0]);
      accB[q*4+1] = fmaf(a, w2.y, accB[q*4+1]);
      accB[q*4+2] = fmaf(a, w2.z, accB[q*4+2]);
      accB[q*4+3] = fmaf(a, w2.w, accB[q*4+3]);
    }
  }
  if (gn < NN) {
#pragma unroll
    for (int q = 0; q < 4; ++q) {
      *(float4*)(A + (size_t)gn*HD + (jg<<4) + (q<<2)) = make_float4(accA[q*4+0], accA[q*4+1], accA[q*4+2], accA[q*4+3]);
      *(float4*)(B + (size_t)gn*HD + (jg<<4) + (q<<2)) = make_float4(accB[q*4+0], accB[q*4+1], accB[q*4+2], accB[q*4+3]);
    }
  }
}

// ---------------- edge message MLP: fp32 part-1 + bf16-MFMA m2 GEMM + segmented flush ----------------
// m1 = relu(A[dst]+B[src]+feats@W1[256:260]+b1)  -> bf16 LDS rows (stride 136, 16B-aligned)
// m2 = relu(m1 @ W2 + b2) via v_mfma_f32_16x16x32_bf16: M=32 edges, N=128, K=128.
// A-frag: A[m=lane&15][k=quad*8+j]; B-frag: B[k=quad*8+j][n=lane&15] (w2t is [n][k] so reads are 16B);
// C/D: col=lane&15, row=quad*4+reg.

__global__ __launch_bounds__(256) void k_msg_mfma(const float* __restrict__ A, const float* __restrict__ B,
                                                  const int* __restrict__ ssrc, const int* __restrict__ sdst,
                                                  const float* __restrict__ sfeat, const float* __restrict__ invd,
                                                  const float* __restrict__ W1, const float* __restrict__ b1,
                                                  const unsigned short* __restrict__ w2t, const float* __restrict__ b2,
                                                  float* __restrict__ agg) {
  __shared__ unsigned short m1bf[32 * 136];   // [edge][k] bf16, row stride 272 B
  __shared__ float m2s[32 * 129];
  __shared__ int lsrc[32];
  __shared__ int ldst[32];
  __shared__ float lfeat[32][4];
  int tid = threadIdx.x;
  int base = blockIdx.x * 32;     // NE % 32 == 0
  if (tid < 32) { lsrc[tid] = ssrc[base + tid]; ldst[tid] = sdst[base + tid]; }
  if (tid < 128) ((float*)lfeat)[tid] = sfeat[(size_t)base*4 + tid];
  __syncthreads();
  {
    int el = tid & 31, jg = tid >> 5;
    int s = lsrc[el], d = ldst[el];
    float f0 = lfeat[el][0], f1 = lfeat[el][1], f2 = lfeat[el][2], f3 = lfeat[el][3];
    const float* Arow = A + (size_t)d*HD + (jg<<4);
    const float* Brow = B + (size_t)s*HD + (jg<<4);
    const float* We = W1 + 256*HD + (jg<<4);
    float m1[16];
#pragma unroll
    for (int q = 0; q < 4; ++q) {
      float4 av = *(const float4*)(Arow + (q<<2));
      float4 bv = *(const float4*)(Brow + (q<<2));
      float4 w0 = *(const float4*)(We + 0*HD + (q<<2));
      float4 w1 = *(const float4*)(We + 1*HD + (q<<2));
      float4 w2 = *(const float4*)(We + 2*HD + (q<<2));
      float4 w3 = *(const float4*)(We + 3*HD + (q<<2));
      float4 bb = *(const float4*)(b1 + (jg<<4) + (q<<2));
      m1[q*4+0] = fmaxf(av.x + bv.x + f0*w0.x + f1*w1.x + f2*w2.x + f3*w3.x + bb.x, 0.f);
      m1[q*4+1] = fmaxf(av.y + bv.y + f0*w0.y + f1*w1.y + f2*w2.y + f3*w3.y + bb.y, 0.f);
      m1[q*4+2] = fmaxf(av.z + bv.z + f0*w0.z + f1*w1.z + f2*w2.z + f3*w3.z + bb.z, 0.f);
      m1[q*4+3] = fmaxf(av.w + bv.w + f0*w0.w + f1*w1.w + f2*w2.w + f3*w3.w + bb.w, 0.f);
    }
    unsigned* p = (unsigned*)(m1bf + el*136 + (jg<<4));
#pragma unroll
    for (int i = 0; i < 8; ++i)
      p[i] = (unsigned)f2bf(m1[2*i]) | ((unsigned)f2bf(m1[2*i+1]) << 16);
  }
  __syncthreads();
  // ---- MFMA: 4 waves, wave w handles mt=(w&1), nt in [(w>>1)*4, +4) ----
  {
    int wv = tid >> 6, lane = tid & 63;
    int quad = lane >> 4, mrow = lane & 15;
    int mt = wv & 1, ntg = wv >> 1;
    f32x4 acc0 = {0.f,0.f,0.f,0.f}, acc1 = acc0, acc2 = acc0, acc3 = acc0;
#pragma unroll
    for (int ks = 0; ks < 4; ++ks) {
      bf16x8 a = *(const bf16x8*)(m1bf + (mt*16 + mrow)*136 + ks*32 + quad*8);
      bf16x8 bf0 = *(const bf16x8*)(w2t + ((ntg*4+0)*16 + mrow)*128 + ks*32 + quad*8);
      bf16x8 bf1 = *(const bf16x8*)(w2t + ((ntg*4+1)*16 + mrow)*128 + ks*32 + quad*8);
      bf16x8 bf2 = *(const bf16x8*)(w2t + ((ntg*4+2)*16 + mrow)*128 + ks*32 + quad*8);
      bf16x8 bf3 = *(const bf16x8*)(w2t + ((ntg*4+3)*16 + mrow)*128 + ks*32 + quad*8);
      acc0 = __builtin_amdgcn_mfma_f32_16x16x32_bf16(a, bf0, acc0, 0, 0, 0);
      acc1 = __builtin_amdgcn_mfma_f32_16x16x32_bf16(a, bf1, acc1, 0, 0, 0);
      acc2 = __builtin_amdgcn_mfma_f32_16x16x32_bf16(a, bf2, acc2, 0, 0, 0);
      acc3 = __builtin_amdgcn_mfma_f32_16x16x32_bf16(a, bf3, acc3, 0, 0, 0);
    }
    f32x4 av[4] = {acc0, acc1, acc2, acc3};
#pragma unroll
    for (int t = 0; t < 4; ++t) {
      int c = (ntg*4 + t)*16 + mrow;
      float bb = b2[c];
#pragma unroll
      for (int r = 0; r < 4; ++r) {
        int erow = mt*16 + quad*4 + r;
        m2s[erow*129 + c] = fmaxf(av[t][r] + bb, 0.f);
      }
    }
  }
  __syncthreads();
  if (tid < HD) {
    int j = tid;
    float a2 = 0.f;
    int cur = ldst[0];
    for (int e = 0; e < 32; ++e) {
      int de = ldst[e];
      if (de != cur) {
        atomicAdd(&agg[(size_t)cur*HD + j], a2 * invd[cur]);
        a2 = 0.f;
        cur = de;
      }
      a2 += m2s[e*129 + j];
    }
    atomicAdd(&agg[(size_t)cur*HD + j], a2 * invd[cur]);
  }
}

// ---------------- fallback: direct edge MLP + naive atomics (unsorted) ----------------

__global__ __launch_bounds__(256) void k_msg_direct(const float* __restrict__ h,
                                                    const int* __restrict__ ei, const float* __restrict__ u,
                                                    const float* __restrict__ pos, const float* __restrict__ invd,
                                                    const float* __restrict__ W1, const float* __restrict__ b1,
                                                    const float* __restrict__ W2, const float* __restrict__ b2,
                                                    float* __restrict__ agg) {
  __shared__ float hd[32 * 129];
  __shared__ float hsr[32 * 129];
  __shared__ float m1s[32 * 129];
  __shared__ int lsrc[32];
  __shared__ int ldst[32];
  __shared__ float lf[32][4];
  int tid = threadIdx.x;
  int base = blockIdx.x * 32;
  if (tid < 32) {
    int e = base + tid;
    int s = ei[e], d = ei[NE + e];
    s = s < 0 ? 0 : (s >= NN ? NN - 1 : s);
    d = d < 0 ? 0 : (d >= NN ? NN - 1 : d);
    lsrc[tid] = s; ldst[tid] = d;
    lf[tid][0] = u[d] - u[s];
    lf[tid][1] = pos[d*3+1] - pos[s*3+1];
    lf[tid][2] = pos[d*3+2] - pos[s*3+2];
    lf[tid][3] = pos[d*3+0];
  }
  __syncthreads();
#pragma unroll
  for (int r = 0; r < 16; ++r) {
    int lin = r*256 + tid;
    int n = lin >> 7, j = lin & 127;
    hd[n*129 + j]  = h[(size_t)ldst[n]*HD + j];
    hsr[n*129 + j] = h[(size_t)lsrc[n]*HD + j];
  }
  __syncthreads();
  int el = tid & 31, jg = tid >> 5;
  float f0 = lf[el][0], f1 = lf[el][1], f2 = lf[el][2], f3 = lf[el][3];
  const float* We = W1 + 256*HD + (jg<<4);
  float acc[16];
#pragma unroll
  for (int q = 0; q < 4; ++q) {
    float4 w0 = *(const float4*)(We + 0*HD + (q<<2));
    float4 w1 = *(const float4*)(We + 1*HD + (q<<2));
    float4 w2 = *(const float4*)(We + 2*HD + (q<<2));
    float4 w3 = *(const float4*)(We + 3*HD + (q<<2));
    float4 bb = *(const float4*)(b1 + (jg<<4) + (q<<2));
    acc[q*4+0] = f0*w0.x + f1*w1.x + f2*w2.x + f3*w3.x + bb.x;
    acc[q*4+1] = f0*w0.y + f1*w1.y + f2*w2.y + f3*w3.y + bb.y;
    acc[q*4+2] = f0*w0.z + f1*w1.z + f2*w2.z + f3*w3.z + bb.z;
    acc[q*4+3] = f0*w0.w + f1*w1.w + f2*w2.w + f3*w3.w + bb.w;
  }
  for (int k = 0; k < HD; ++k) {
    float a  = hd[el*129 + k];
    float bs = hsr[el*129 + k];
    const float4* wa = (const float4*)(W1 + (size_t)k*HD + (jg<<4));
    const float4* wb = (const float4*)(W1 + (size_t)(128 + k)*HD + (jg<<4));
#pragma unroll
    for (int q = 0; q < 4; ++q) {
      float4 w1v = wa[q];
      float4 w2v = wb[q];
      acc[q*4+0] = fmaf(a, w1v.x, fmaf(bs, w2v.x, acc[q*4+0]));
      acc[q*4+1] = fmaf(a, w1v.y, fmaf(bs, w2v.y, acc[q*4+1]));
      acc[q*4+2] = fmaf(a, w1v.z, fmaf(bs, w2v.z, acc[q*4+2]));
      acc[q*4+3] = fmaf(a, w1v.w, fmaf(bs, w2v.w, acc[q*4+3]));
    }
  }
#pragma unroll
  for (int i = 0; i < 16; ++i) m1s[el*129 + (jg<<4) + i] = fmaxf(acc[i], 0.f);
  __syncthreads();
  float acc2[16];
#pragma unroll
  for (int q = 0; q < 4; ++q) {
    float4 bb = *(const float4*)(b2 + (jg<<4) + (q<<2));
    acc2[q*4+0] = bb.x; acc2[q*4+1] = bb.y; acc2[q*4+2] = bb.z; acc2[q*4+3] = bb.w;
  }
  for (int k = 0; k < HD; ++k) {
    float a = m1s[el*129 + k];
    const float4* wp = (const float4*)(W2 + (size_t)k*HD + (jg<<4));
#pragma unroll
    for (int q = 0; q < 4; ++q) {
      float4 wv = wp[q];
      acc2[q*4+0] = fmaf(a, wv.x, acc2[q*4+0]);
      acc2[q*4+1] = fmaf(a, wv.y, acc2[q*4+1]);
      acc2[q*4+2] = fmaf(a, wv.z, acc2[q*4+2]);
      acc2[q*4+3] = fmaf(a, wv.w, acc2[q*4+3]);
    }
  }
#pragma unroll
  for (int i = 0; i < 16; ++i) hd[el*129 + (jg<<4) + i] = fmaxf(acc2[i], 0.f);
  __syncthreads();
  if (tid < HD) {
    int j = tid;
    for (int e = 0; e < 32; ++e) {
      int de = ldst[e];
      atomicAdd(&agg[(size_t)de*HD + j], hd[e*129 + j] * invd[de]);
    }
  }
}

// ---------------- node update MLP ----------------

__global__ __launch_bounds__(256) void k_upd(float* __restrict__ h, const float* __restrict__ agg,
                                             const float* __restrict__ pos,
                                             const float* __restrict__ W1, const float* __restrict__ b1,
                                             const float* __restrict__ W2, const float* __restrict__ b2,
                                             double* __restrict__ stats) {
  __shared__ float hs[32 * 129];
  __shared__ float as_[32 * 129];
  int tid = threadIdx.x;
  int base = blockIdx.x * 32;
#pragma unroll
  for (int r = 0; r < 16; ++r) {
    int lin = r*256 + tid;
    int n = lin >> 7, j = lin & 127;
    int gn = base + n;
    hs[n*129 + j]  = (gn < NN) ? h[(size_t)gn*HD + j]   : 0.f;
    as_[n*129 + j] = (gn < NN) ? agg[(size_t)gn*HD + j] : 0.f;
  }
  __syncthreads();
  int nl = tid & 31, jg = tid >> 5;
  int gn = base + nl;
  float var = (gn < NN) ? pos[gn*3+0] : 0.f;
  float acc[16];
#pragma unroll
  for (int q = 0; q < 4; ++q) {
    int j = (jg<<4) + (q<<2);
    float4 bb = *(const float4*)(b1 + j);
    float4 wv = *(const float4*)(W1 + 256*HD + j);
    acc[q*4+0] = fmaf(var, wv.x, bb.x);
    acc[q*4+1] = fmaf(var, wv.y, bb.y);
    acc[q*4+2] = fmaf(var, wv.z, bb.z);
    acc[q*4+3] = fmaf(var, wv.w, bb.w);
  }
  for (int k = 0; k < HD; ++k) {
    float a = hs[nl*129 + k];
    float g = as_[nl*129 + k];
    const float4* w1p = (const float4*)(W1 + (size_t)k*HD + (jg<<4));
    const float4* w2p = (const float4*)(W1 + (size_t)(128 + k)*HD + (jg<<4));
#pragma unroll
    for (int q = 0; q < 4; ++q) {
      float4 wa = w1p[q];
      float4 wb = w2p[q];
      acc[q*4+0] = fmaf(a, wa.x, fmaf(g, wb.x, acc[q*4+0]));
      acc[q*4+1] = fmaf(a, wa.y, fmaf(g, wb.y, acc[q*4+1]));
      acc[q*4+2] = fmaf(a, wa.z, fmaf(g, wb.z, acc[q*4+2]));
      acc[q*4+3] = fmaf(a, wa.w, fmaf(g, wb.w, acc[q*4+3]));
    }
  }
  float up1[16];
#pragma unroll
  for (int i = 0; i < 16; ++i) up1[i] = fmaxf(acc[i], 0.f);
  __syncthreads();
#pragma unroll
  for (int i = 0; i < 16; ++i) as_[nl*129 + (jg<<4) + i] = up1[i];
  __syncthreads();
  float acc2[16];
#pragma unroll
  for (int q = 0; q < 4; ++q) {
    float4 bb = *(const float4*)(b2 + (jg<<4) + (q<<2));
    acc2[q*4+0] = bb.x; acc2[q*4+1] = bb.y; acc2[q*4+2] = bb.z; acc2[q*4+3] = bb.w;
  }
  for (int k = 0; k < HD; ++k) {
    float a = as_[nl*129 + k];
    const float4* wp = (const float4*)(W2 + (size_t)k*HD + (jg<<4));
#pragma unroll
    for (int q = 0; q < 4; ++q) {
      float4 wv = wp[q];
      acc2[q*4+0] = fmaf(a, wv.x, acc2[q*4+0]);
      acc2[q*4+1] = fmaf(a, wv.y, acc2[q*4+1]);
      acc2[q*4+2] = fmaf(a, wv.z, acc2[q*4+2]);
      acc2[q*4+3] = fmaf(a, wv.w, acc2[q*4+3]);
    }
  }
  float x[16];
#pragma unroll
  for (int i = 0; i < 16; ++i)
    x[i] = hs[nl*129 + (jg<<4) + i] + fmaxf(acc2[i], 0.f);
  if (gn < NN) {
#pragma unroll
    for (int q = 0; q < 4; ++q)
      *(float4*)(h + (size_t)gn*HD + (jg<<4) + (q<<2)) = make_float4(x[q*4+0], x[q*4+1], x[q*4+2], x[q*4+3]);
  }
  __syncthreads();
#pragma unroll
  for (int i = 0; i < 16; ++i) hs[nl*129 + (jg<<4) + i] = (gn < NN) ? x[i] : 0.f;
  __syncthreads();
  if (tid < HD) {
    double s = 0.0, sq = 0.0;
    for (int e = 0; e < 32; ++e) { double v = (double)hs[e*129 + tid]; s += v; sq += v*v; }
    atomicAdd(&stats[tid], s);
    atomicAdd(&stats[HD + tid], sq);
  }
}

// ---------------- CNN head (full 72-slot o2 coverage) ----------------

__global__ __launch_bounds__(256) void k_conv(const float* __restrict__ h,
                                              const float* __restrict__ c1W, const float* __restrict__ c1b,
                                              const float* __restrict__ c2W, const float* __restrict__ c2b,
                                              const float* __restrict__ c3W, const float* __restrict__ c3b,
                                              float* __restrict__ out) {
  __shared__ float xs[4][128];
  __shared__ float o1[4][152];
  __shared__ float o2[4][72];
  int tid = threadIdx.x;
  int w = tid >> 6, lane = tid & 63;
  int n = blockIdx.x * 4 + w;          // NN % 4 == 0
  xs[w][lane]      = h[(size_t)n*HD + lane];
  xs[w][64 + lane] = h[(size_t)n*HD + 64 + lane];
  __syncthreads();
  for (int o = lane; o < 152; o += 64) {
    int oc = o / 38, t = o % 38;
    float s = c1b[oc];
#pragma unroll
    for (int k = 0; k < 16; ++k) s = fmaf(xs[w][t*3 + k], c1W[oc*16 + k], s);
    o1[w][oc*38 + t] = fmaxf(s, 0.f);
  }
  __syncthreads();
  for (int o = lane; o < 72; o += 64) {
    int oc = o / 9, t = o % 9;
    float s = c2b[oc];
    for (int ic = 0; ic < 4; ++ic) {
#pragma unroll
      for (int k = 0; k < 12; ++k) s = fmaf(o1[w][ic*38 + t*3 + k], c2W[oc*48 + ic*12 + k], s);
    }
    o2[w][oc*9 + t] = fmaxf(s, 0.f);
  }
  __syncthreads();
  int ic = lane >> 3, k = lane & 7;
  float t3 = o2[w][ic*9 + k] * c3W[ic*8 + k];
  for (int off = 32; off; off >>= 1) t3 += __shfl_down(t3, off);
  if (lane == 0) out[n] = 0.001f * (t3 + c3b[0]);   // dt = cumsum(DT*0.1), TW=1
}

// ---------------- launcher ----------------

extern "C" void kernel_launch(void* const* d_in, const int* in_sizes, int n_in,
                              void* d_out, int out_size, void* d_ws, size_t ws_size,
                              hipStream_t stream) {
  (void)out_size;
  float* out = (float*)d_out;

  static const int expect[27] = {
    50000, 150000, 1200000,
    512, 128, 128, 128,
    16384, 128, 128, 128,
    199680, 768, 98304, 768, 197376, 768, 98304, 768,
    768, 768,
    64, 4, 384, 8, 64, 1
  };
  if (n_in != 27) { k_code<<<1, 64, 0, stream>>>(out, 5000099.f); return; }
  for (int i = 0; i < 27; ++i)
    if (in_sizes[i] != expect[i]) { k_code<<<1, 64, 0, stream>>>(out, 5000100.f + (float)i); return; }

  const float* u    = (const float*)d_in[0];
  const float* pos  = (const float*)d_in[1];
  const int*   ei   = (const int*)d_in[2];
  const float* eW1  = (const float*)d_in[3];
  const float* eb1  = (const float*)d_in[4];
  const float* eg1  = (const float*)d_in[5];
  const float* ebe1 = (const float*)d_in[6];
  const float* eW2  = (const float*)d_in[7];
  const float* eb2  = (const float*)d_in[8];
  const float* eg2  = (const float*)d_in[9];
  const float* ebe2 = (const float*)d_in[10];
  const float* m1W  = (const float*)d_in[11];
  const float* m1b  = (const float*)d_in[12];
  const float* m2W  = (const float*)d_in[13];
  const float* m2b  = (const float*)d_in[14];
  const float* u1W  = (const float*)d_in[15];
  const float* u1b  = (const float*)d_in[16];
  const float* u2W  = (const float*)d_in[17];
  const float* u2b  = (const float*)d_in[18];
  const float* bng  = (const float*)d_in[19];
  const float* bnb  = (const float*)d_in[20];
  const float* c1W  = (const float*)d_in[21];
  const float* c1b  = (const float*)d_in[22];
  const float* c2W  = (const float*)d_in[23];
  const float* c2b  = (const float*)d_in[24];
  const float* c3W  = (const float*)d_in[25];
  const float* c3b  = (const float*)d_in[26];

  // ---- workspace ----
  char* wsp = (char*)d_ws;
  size_t off = 0;
  auto alloc = [&](size_t bytes) -> void* {
    void* p = wsp + off;
    off = (off + bytes + 255) & ~(size_t)255;
    return p;
  };
  double* stats  = (double*)alloc(256 * 8);
  float*  musig  = (float*)alloc(256 * 4);
  int*    deg    = (int*)alloc((size_t)NN * 4);
  int*    cursor = (int*)alloc((size_t)NN * 4);
  int*    blk    = (int*)alloc(256 * 4);
  float*  invd   = (float*)alloc((size_t)NN * 4);
  float*  h      = (float*)alloc((size_t)NN * HD * 4);
  float*  agg    = (float*)alloc((size_t)NN * HD * 4);
  size_t needed_direct = off;
  float*  A      = (float*)alloc((size_t)NN * HD * 4);
  float*  B      = (float*)alloc((size_t)NN * HD * 4);
  float*  sfeat  = (float*)alloc((size_t)NE * 4 * 4);
  int*    ssrc   = (int*)alloc((size_t)NE * 4);
  int*    sdst   = (int*)alloc((size_t)NE * 4);
  unsigned short* w2t = (unsigned short*)alloc((size_t)NL * HD * HD * 2);
  size_t needed_fast = off;

  if (ws_size < needed_direct) {
    k_code<<<1, 64, 0, stream>>>(out, (float)(9000000u + (unsigned)(ws_size >> 20)));
    return;
  }
  const bool fast = (ws_size >= needed_fast);

  const int nbN  = (NN + 255) / 256;   // 196
  const int nbE  = (NE + 255) / 256;   // 2344
  const int nt32 = (NN + 31) / 32;     // 1563
  const int nbBN = NN * HD / 256;      // 25000

  // ---- degree / inverse degree (+ sort + W2 bf16 transpose if fast) ----
  hipMemsetAsync(deg, 0, (size_t)NN * 4, stream);
  k_deg<<<nbE, 256, 0, stream>>>(ei, deg);
  k_scan1<<<nbN, 256, 0, stream>>>(deg, cursor, blk, invd);
  if (fast) {
    k_scan2<<<1, 256, 0, stream>>>(blk, nbN);
    k_scan3<<<nbN, 256, 0, stream>>>(cursor, blk);
    k_scatter<<<nbE, 256, 0, stream>>>(ei, u, pos, cursor, ssrc, sdst, sfeat);
    k_w2t<<<(NL*HD*HD + 255) / 256, 256, 0, stream>>>(m2W, w2t);
  }

  // ---- embedding ----
  hipMemsetAsync(stats, 0, 256 * 8, stream);
  k_emb1<<<nt32, 256, 0, stream>>>(u, pos, eW1, eb1, h, stats);
  k_redA<<<1, 128, 0, stream>>>(stats, musig);
  k_bn<<<nbBN, 256, 0, stream>>>(h, musig, eg1, ebe1, 1);
  hipMemsetAsync(stats, 0, 256 * 8, stream);
  k_emb2<<<nt32, 256, 0, stream>>>(h, eW2, eb2, stats);
  k_redA<<<1, 128, 0, stream>>>(stats, musig);
  k_bn<<<nbBN, 256, 0, stream>>>(h, musig, eg2, ebe2, 0);

  // ---- message-passing layers ----
  for (int i = 0; i < NL; ++i) {
    hipMemsetAsync(agg, 0, (size_t)NN * HD * 4, stream);
    if (fast) {
      k_ab<<<nt32, 256, 0, stream>>>(h, m1W + (size_t)i * 260 * HD, A, B);
      k_msg_mfma<<<NE / 32, 256, 0, stream>>>(A, B, ssrc, sdst, sfeat, invd,
                                              m1W + (size_t)i * 260 * HD, m1b + (size_t)i * HD,
                                              w2t + (size_t)i * HD * HD, m2b + (size_t)i * HD, agg);
    } else {
      k_msg_direct<<<NE / 32, 256, 0, stream>>>(h, ei, u, pos, invd,
                                                m1W + (size_t)i * 260 * HD, m1b + (size_t)i * HD,
                                                m2W + (size_t)i * HD * HD, m2b + (size_t)i * HD, agg);
    }
    hipMemsetAsync(stats, 0, 256 * 8, stream);
    k_upd<<<nt32, 256, 0, stream>>>(h, agg, pos,
                                    u1W + (size_t)i * 257 * HD, u1b + (size_t)i * HD,
                                    u2W + (size_t)i * HD * HD, u2b + (size_t)i * HD, stats);
    k_redA<<<1, 128, 0, stream>>>(stats, musig);
    k_bn<<<nbBN, 256, 0, stream>>>(h, musig, bng + (size_t)i * HD, bnb + (size_t)i * HD, 0);
  }

  // ---- CNN head ----
  k_conv<<<NN / 4, 256, 0, stream>>>(h, c1W, c1b, c2W, c2b, c3W, c3b, out);
}

// Round 16
// 2774.025 us; speedup vs baseline: 7.7812x; 1.8754x over previous
//
#include <hip/hip_runtime.h>

#define NN 50000
#define NE 600000
#define HD 128
#define NL 6

typedef __attribute__((ext_vector_type(8))) short bf16x8;
typedef __attribute__((ext_vector_type(4))) float f32x4;

__device__ inline unsigned short f2bf(float x) {
  unsigned u = __float_as_uint(x);
  u += 0x7FFF + ((u >> 16) & 1);           // RNE on raw bits
  return (unsigned short)(u >> 16);
}

__global__ void k_code(float* __restrict__ out, float code) {
  if (threadIdx.x == 0 && blockIdx.x == 0) out[0] = code;
}

// ---------------- weight transposes -> bf16 [layer][n][k] ----------------

// (L,128,128) weights: W[l][k][n] -> T[l][n][k]   (works for m2W and u2W)
__global__ __launch_bounds__(256) void k_w2t(const float* __restrict__ W, unsigned short* __restrict__ T) {
  int idx = blockIdx.x * 256 + threadIdx.x;
  if (idx >= NL * HD * HD) return;
  int l = idx >> 14, r = idx & 16383;
  int n = r >> 7, k = r & 127;
  T[idx] = f2bf(W[(l << 14) + (k << 7) + n]);
}

// u1W (L,257,128): rows 0..255 -> u1t[l][n][k], n<128, k<256
__global__ __launch_bounds__(256) void k_u1t(const float* __restrict__ W, unsigned short* __restrict__ T) {
  int idx = blockIdx.x * 256 + threadIdx.x;
  if (idx >= NL * 128 * 256) return;
  int l = idx >> 15, r = idx & 32767;
  int n = r >> 8, k = r & 255;
  T[idx] = f2bf(W[l * 32896 + k * 128 + n]);
}

// m1W (L,260,128): rows 0..255 -> abt[l][n][k], n<256, k<128
// n<128: W1[k][n] (A-part);  n>=128: W1[128+k][n-128] (B-part)
__global__ __launch_bounds__(256) void k_abt(const float* __restrict__ W, unsigned short* __restrict__ T) {
  int idx = blockIdx.x * 256 + threadIdx.x;
  if (idx >= NL * 256 * 128) return;
  int l = idx >> 15, r = idx & 32767;
  int n = r >> 7, k = r & 127;
  int row = (n < 128) ? k : 128 + k;
  int col = n & 127;
  T[idx] = f2bf(W[l * 33280 + row * 128 + col]);
}

// ---------------- degree histogram, scan, counting sort (by dst) ----------------

__global__ __launch_bounds__(256) void k_deg(const int* __restrict__ ei, int* __restrict__ deg) {
  int e = blockIdx.x * 256 + threadIdx.x;
  if (e < NE) {
    int d = ei[NE + e];
    if (d >= 0 && d < NN) atomicAdd(&deg[d], 1);
  }
}

__global__ __launch_bounds__(256) void k_scan1(const int* __restrict__ deg, int* __restrict__ cursor,
                                               int* __restrict__ blk, float* __restrict__ invd) {
  __shared__ int sd[256];
  int t = threadIdx.x;
  int i = blockIdx.x * 256 + t;
  int v = (i < NN) ? deg[i] : 0;
  sd[t] = v;
  __syncthreads();
  for (int off = 1; off < 256; off <<= 1) {
    int x = (t >= off) ? sd[t - off] : 0;
    __syncthreads();
    if (t >= off) sd[t] += x;
    __syncthreads();
  }
  int incl = sd[t];
  if (i < NN) {
    cursor[i] = incl - v;
    invd[i] = 1.0f / fmaxf((float)v, 1.0f);
  }
  if (t == 255) blk[blockIdx.x] = incl;
}

__global__ __launch_bounds__(256) void k_scan2(int* __restrict__ blk, int nb) {
  __shared__ int sd[256];
  int t = threadIdx.x;
  int v = (t < nb) ? blk[t] : 0;
  sd[t] = v;
  __syncthreads();
  for (int off = 1; off < 256; off <<= 1) {
    int x = (t >= off) ? sd[t - off] : 0;
    __syncthreads();
    if (t >= off) sd[t] += x;
    __syncthreads();
  }
  if (t < nb) blk[t] = sd[t] - v;
}

__global__ __launch_bounds__(256) void k_scan3(int* __restrict__ cursor, const int* __restrict__ blk) {
  int i = blockIdx.x * 256 + threadIdx.x;
  if (i < NN) cursor[i] += blk[blockIdx.x];
}

__global__ __launch_bounds__(256) void k_scatter(const int* __restrict__ ei, const float* __restrict__ u,
                                                 const float* __restrict__ pos, int* __restrict__ cursor,
                                                 int* __restrict__ ssrc, int* __restrict__ sdst,
                                                 float* __restrict__ sfeat) {
  int e = blockIdx.x * 256 + threadIdx.x;
  if (e >= NE) return;
  int s = ei[e], d = ei[NE + e];
  s = s < 0 ? 0 : (s >= NN ? NN - 1 : s);
  d = d < 0 ? 0 : (d >= NN ? NN - 1 : d);
  int p = atomicAdd(&cursor[d], 1);
  ssrc[p] = s;
  sdst[p] = d;
  float du  = u[d] - u[s];
  float dpx = pos[d*3+1] - pos[s*3+1];
  float dpy = pos[d*3+2] - pos[s*3+2];
  float vi  = pos[d*3+0];
  ((float4*)sfeat)[p] = make_float4(du, dpx, dpy, vi);
}

// ---------------- embedding ----------------

__global__ __launch_bounds__(256) void k_emb1(const float* __restrict__ u, const float* __restrict__ pos,
                                              const float* __restrict__ W, const float* __restrict__ b,
                                              float* __restrict__ h, double* __restrict__ stats) {
  __shared__ float xs[32 * 129];
  int tid = threadIdx.x;
  int nl = tid & 31, jg = tid >> 5;
  int gn = blockIdx.x * 32 + nl;
  float f0 = 0.f, f1 = 0.f, f2 = 0.f, f3 = 0.f;
  if (gn < NN) { f0 = u[gn]; f1 = pos[gn*3+1]; f2 = pos[gn*3+2]; f3 = pos[gn*3+0]; }
  float x[16];
#pragma unroll
  for (int q = 0; q < 4; ++q) {
    int j = (jg << 4) + (q << 2);
    float4 w0 = *(const float4*)(W + 0*HD + j);
    float4 w1 = *(const float4*)(W + 1*HD + j);
    float4 w2 = *(const float4*)(W + 2*HD + j);
    float4 w3 = *(const float4*)(W + 3*HD + j);
    float4 bb = *(const float4*)(b + j);
    x[q*4+0] = f0*w0.x + f1*w1.x + f2*w2.x + f3*w3.x + bb.x;
    x[q*4+1] = f0*w0.y + f1*w1.y + f2*w2.y + f3*w3.y + bb.y;
    x[q*4+2] = f0*w0.z + f1*w1.z + f2*w2.z + f3*w3.z + bb.z;
    x[q*4+3] = f0*w0.w + f1*w1.w + f2*w2.w + f3*w3.w + bb.w;
  }
  if (gn < NN) {
#pragma unroll
    for (int q = 0; q < 4; ++q)
      *(float4*)(h + (size_t)gn*HD + (jg<<4) + (q<<2)) = make_float4(x[q*4+0], x[q*4+1], x[q*4+2], x[q*4+3]);
  }
#pragma unroll
  for (int i = 0; i < 16; ++i) xs[nl*129 + (jg<<4) + i] = (gn < NN) ? x[i] : 0.f;
  __syncthreads();
  if (tid < HD) {
    double s = 0.0, sq = 0.0;
    for (int e = 0; e < 32; ++e) { double v = (double)xs[e*129 + tid]; s += v; sq += v*v; }
    atomicAdd(&stats[tid], s);
    atomicAdd(&stats[HD + tid], sq);
  }
}

__global__ __launch_bounds__(256) void k_emb2(float* __restrict__ h, const float* __restrict__ W,
                                              const float* __restrict__ b, double* __restrict__ stats) {
  __shared__ float hs[32 * 129];
  int tid = threadIdx.x;
  int base = blockIdx.x * 32;
#pragma unroll
  for (int r = 0; r < 16; ++r) {
    int lin = r*256 + tid;
    int n = lin >> 7, j = lin & 127;
    int gn = base + n;
    hs[n*129 + j] = (gn < NN) ? h[(size_t)gn*HD + j] : 0.f;
  }
  __syncthreads();
  int nl = tid & 31, jg = tid >> 5;
  int gn = base + nl;
  float acc[16];
#pragma unroll
  for (int q = 0; q < 4; ++q) {
    float4 bb = *(const float4*)(b + (jg<<4) + (q<<2));
    acc[q*4+0] = bb.x; acc[q*4+1] = bb.y; acc[q*4+2] = bb.z; acc[q*4+3] = bb.w;
  }
  for (int k = 0; k < HD; ++k) {
    float a = hs[nl*129 + k];
    const float4* wp = (const float4*)(W + (size_t)k*HD + (jg<<4));
#pragma unroll
    for (int q = 0; q < 4; ++q) {
      float4 wv = wp[q];
      acc[q*4+0] = fmaf(a, wv.x, acc[q*4+0]);
      acc[q*4+1] = fmaf(a, wv.y, acc[q*4+1]);
      acc[q*4+2] = fmaf(a, wv.z, acc[q*4+2]);
      acc[q*4+3] = fmaf(a, wv.w, acc[q*4+3]);
    }
  }
  if (gn < NN) {
#pragma unroll
    for (int q = 0; q < 4; ++q)
      *(float4*)(h + (size_t)gn*HD + (jg<<4) + (q<<2)) = make_float4(acc[q*4+0], acc[q*4+1], acc[q*4+2], acc[q*4+3]);
  }
  __syncthreads();
#pragma unroll
  for (int i = 0; i < 16; ++i) hs[nl*129 + (jg<<4) + i] = (gn < NN) ? acc[i] : 0.f;
  __syncthreads();
  if (tid < HD) {
    double s = 0.0, sq = 0.0;
    for (int e = 0; e < 32; ++e) { double v = (double)hs[e*129 + tid]; s += v; sq += v*v; }
    atomicAdd(&stats[tid], s);
    atomicAdd(&stats[HD + tid], sq);
  }
}

__global__ void k_redA(const double* __restrict__ stats, float* __restrict__ musig) {
  int c = threadIdx.x;   // 128
  double mu  = stats[c] / (double)NN;
  double var = stats[128 + c] / (double)NN - mu * mu;
  musig[c]      = (float)mu;
  musig[HD + c] = (float)(1.0 / sqrt(var + 1e-5));
}

__global__ __launch_bounds__(256) void k_bn(float* __restrict__ h, const float* __restrict__ musig,
                                            const float* __restrict__ g, const float* __restrict__ be,
                                            int relu) {
  int idx = blockIdx.x * 256 + threadIdx.x;
  if (idx >= NN * HD) return;
  int j = idx & 127;
  float x = h[idx];
  x = g[j] * (x - musig[j]) * musig[HD + j] + be[j];
  if (relu) x = fmaxf(x, 0.f);
  h[idx] = x;
}

// ---------------- k_ab via MFMA: [A|B](32x256) = h(32x128,bf16) @ abt ----------------

__global__ __launch_bounds__(256) void k_ab_mfma(const float* __restrict__ h,
                                                 const unsigned short* __restrict__ abt,
                                                 float* __restrict__ A, float* __restrict__ B) {
  __shared__ unsigned short hbf[32 * 136];
  int tid = threadIdx.x;
  int base = blockIdx.x * 32;
#pragma unroll
  for (int r = 0; r < 16; ++r) {
    int lin = r*256 + tid;
    int n = lin >> 7, j = lin & 127;
    int gn = base + n;
    hbf[n*136 + j] = f2bf((gn < NN) ? h[(size_t)gn*HD + j] : 0.f);
  }
  __syncthreads();
  int wv = tid >> 6, lane = tid & 63;
  int quad = lane >> 4, mrow = lane & 15;
  int mt = wv & 1, ntg = wv >> 1;        // ntg in {0,1}; tiles ntg*8..+8 over N=256
  f32x4 acc[8];
#pragma unroll
  for (int t = 0; t < 8; ++t) acc[t] = (f32x4){0.f,0.f,0.f,0.f};
#pragma unroll
  for (int ks = 0; ks < 4; ++ks) {
    bf16x8 a = *(const bf16x8*)(hbf + (mt*16 + mrow)*136 + ks*32 + quad*8);
#pragma unroll
    for (int t = 0; t < 8; ++t) {
      bf16x8 b = *(const bf16x8*)(abt + (size_t)((ntg*8 + t)*16 + mrow)*128 + ks*32 + quad*8);
      acc[t] = __builtin_amdgcn_mfma_f32_16x16x32_bf16(a, b, acc[t], 0, 0, 0);
    }
  }
#pragma unroll
  for (int t = 0; t < 8; ++t) {
    int c = (ntg*8 + t)*16 + mrow;      // 0..255
#pragma unroll
    for (int r = 0; r < 4; ++r) {
      int gn = base + mt*16 + quad*4 + r;
      if (gn < NN) {
        if (c < 128) A[(size_t)gn*HD + c]       = acc[t][r];
        else         B[(size_t)gn*HD + c - 128] = acc[t][r];
      }
    }
  }
}

// ---------------- edge message MLP: fp32 part-1 + bf16-MFMA m2 + segmented flush ----------------

__global__ __launch_bounds__(256) void k_msg_mfma(const float* __restrict__ A, const float* __restrict__ B,
                                                  const int* __restrict__ ssrc, const int* __restrict__ sdst,
                                                  const float* __restrict__ sfeat, const float* __restrict__ invd,
                                                  const float* __restrict__ W1, const float* __restrict__ b1,
                                                  const unsigned short* __restrict__ w2t, const float* __restrict__ b2,
                                                  float* __restrict__ agg) {
  __shared__ unsigned short m1bf[32 * 136];
  __shared__ float m2s[32 * 129];
  __shared__ int lsrc[32];
  __shared__ int ldst[32];
  __shared__ float lfeat[32][4];
  int tid = threadIdx.x;
  int base = blockIdx.x * 32;
  if (tid < 32) { lsrc[tid] = ssrc[base + tid]; ldst[tid] = sdst[base + tid]; }
  if (tid < 128) ((float*)lfeat)[tid] = sfeat[(size_t)base*4 + tid];
  __syncthreads();
  {
    int el = tid & 31, jg = tid >> 5;
    int s = lsrc[el], d = ldst[el];
    float f0 = lfeat[el][0], f1 = lfeat[el][1], f2 = lfeat[el][2], f3 = lfeat[el][3];
    const float* Arow = A + (size_t)d*HD + (jg<<4);
    const float* Brow = B + (size_t)s*HD + (jg<<4);
    const float* We = W1 + 256*HD + (jg<<4);
    float m1[16];
#pragma unroll
    for (int q = 0; q < 4; ++q) {
      float4 av = *(const float4*)(Arow + (q<<2));
      float4 bv = *(const float4*)(Brow + (q<<2));
      float4 w0 = *(const float4*)(We + 0*HD + (q<<2));
      float4 w1 = *(const float4*)(We + 1*HD + (q<<2));
      float4 w2 = *(const float4*)(We + 2*HD + (q<<2));
      float4 w3 = *(const float4*)(We + 3*HD + (q<<2));
      float4 bb = *(const float4*)(b1 + (jg<<4) + (q<<2));
      m1[q*4+0] = fmaxf(av.x + bv.x + f0*w0.x + f1*w1.x + f2*w2.x + f3*w3.x + bb.x, 0.f);
      m1[q*4+1] = fmaxf(av.y + bv.y + f0*w0.y + f1*w1.y + f2*w2.y + f3*w3.y + bb.y, 0.f);
      m1[q*4+2] = fmaxf(av.z + bv.z + f0*w0.z + f1*w1.z + f2*w2.z + f3*w3.z + bb.z, 0.f);
      m1[q*4+3] = fmaxf(av.w + bv.w + f0*w0.w + f1*w1.w + f2*w2.w + f3*w3.w + bb.w, 0.f);
    }
    unsigned* p = (unsigned*)(m1bf + el*136 + (jg<<4));
#pragma unroll
    for (int i = 0; i < 8; ++i)
      p[i] = (unsigned)f2bf(m1[2*i]) | ((unsigned)f2bf(m1[2*i+1]) << 16);
  }
  __syncthreads();
  {
    int wv = tid >> 6, lane = tid & 63;
    int quad = lane >> 4, mrow = lane & 15;
    int mt = wv & 1, ntg = wv >> 1;
    f32x4 acc0 = {0.f,0.f,0.f,0.f}, acc1 = acc0, acc2 = acc0, acc3 = acc0;
#pragma unroll
    for (int ks = 0; ks < 4; ++ks) {
      bf16x8 a = *(const bf16x8*)(m1bf + (mt*16 + mrow)*136 + ks*32 + quad*8);
      bf16x8 bf0 = *(const bf16x8*)(w2t + ((ntg*4+0)*16 + mrow)*128 + ks*32 + quad*8);
      bf16x8 bf1 = *(const bf16x8*)(w2t + ((ntg*4+1)*16 + mrow)*128 + ks*32 + quad*8);
      bf16x8 bf2 = *(const bf16x8*)(w2t + ((ntg*4+2)*16 + mrow)*128 + ks*32 + quad*8);
      bf16x8 bf3 = *(const bf16x8*)(w2t + ((ntg*4+3)*16 + mrow)*128 + ks*32 + quad*8);
      acc0 = __builtin_amdgcn_mfma_f32_16x16x32_bf16(a, bf0, acc0, 0, 0, 0);
      acc1 = __builtin_amdgcn_mfma_f32_16x16x32_bf16(a, bf1, acc1, 0, 0, 0);
      acc2 = __builtin_amdgcn_mfma_f32_16x16x32_bf16(a, bf2, acc2, 0, 0, 0);
      acc3 = __builtin_amdgcn_mfma_f32_16x16x32_bf16(a, bf3, acc3, 0, 0, 0);
    }
    f32x4 av[4] = {acc0, acc1, acc2, acc3};
#pragma unroll
    for (int t = 0; t < 4; ++t) {
      int c = (ntg*4 + t)*16 + mrow;
      float bb = b2[c];
#pragma unroll
      for (int r = 0; r < 4; ++r) {
        int erow = mt*16 + quad*4 + r;
        m2s[erow*129 + c] = fmaxf(av[t][r] + bb, 0.f);
      }
    }
  }
  __syncthreads();
  if (tid < HD) {
    int j = tid;
    float a2 = 0.f;
    int cur = ldst[0];
    for (int e = 0; e < 32; ++e) {
      int de = ldst[e];
      if (de != cur) {
        atomicAdd(&agg[(size_t)cur*HD + j], a2 * invd[cur]);
        a2 = 0.f;
        cur = de;
      }
      a2 += m2s[e*129 + j];
    }
    atomicAdd(&agg[(size_t)cur*HD + j], a2 * invd[cur]);
  }
}

// ---------------- fallback: direct edge MLP + naive atomics (unsorted) ----------------

__global__ __launch_bounds__(256) void k_msg_direct(const float* __restrict__ h,
                                                    const int* __restrict__ ei, const float* __restrict__ u,
                                                    const float* __restrict__ pos, const float* __restrict__ invd,
                                                    const float* __restrict__ W1, const float* __restrict__ b1,
                                                    const float* __restrict__ W2, const float* __restrict__ b2,
                                                    float* __restrict__ agg) {
  __shared__ float hd[32 * 129];
  __shared__ float hsr[32 * 129];
  __shared__ float m1s[32 * 129];
  __shared__ int lsrc[32];
  __shared__ int ldst[32];
  __shared__ float lf[32][4];
  int tid = threadIdx.x;
  int base = blockIdx.x * 32;
  if (tid < 32) {
    int e = base + tid;
    int s = ei[e], d = ei[NE + e];
    s = s < 0 ? 0 : (s >= NN ? NN - 1 : s);
    d = d < 0 ? 0 : (d >= NN ? NN - 1 : d);
    lsrc[tid] = s; ldst[tid] = d;
    lf[tid][0] = u[d] - u[s];
    lf[tid][1] = pos[d*3+1] - pos[s*3+1];
    lf[tid][2] = pos[d*3+2] - pos[s*3+2];
    lf[tid][3] = pos[d*3+0];
  }
  __syncthreads();
#pragma unroll
  for (int r = 0; r < 16; ++r) {
    int lin = r*256 + tid;
    int n = lin >> 7, j = lin & 127;
    hd[n*129 + j]  = h[(size_t)ldst[n]*HD + j];
    hsr[n*129 + j] = h[(size_t)lsrc[n]*HD + j];
  }
  __syncthreads();
  int el = tid & 31, jg = tid >> 5;
  float f0 = lf[el][0], f1 = lf[el][1], f2 = lf[el][2], f3 = lf[el][3];
  const float* We = W1 + 256*HD + (jg<<4);
  float acc[16];
#pragma unroll
  for (int q = 0; q < 4; ++q) {
    float4 w0 = *(const float4*)(We + 0*HD + (q<<2));
    float4 w1 = *(const float4*)(We + 1*HD + (q<<2));
    float4 w2 = *(const float4*)(We + 2*HD + (q<<2));
    float4 w3 = *(const float4*)(We + 3*HD + (q<<2));
    float4 bb = *(const float4*)(b1 + (jg<<4) + (q<<2));
    acc[q*4+0] = f0*w0.x + f1*w1.x + f2*w2.x + f3*w3.x + bb.x;
    acc[q*4+1] = f0*w0.y + f1*w1.y + f2*w2.y + f3*w3.y + bb.y;
    acc[q*4+2] = f0*w0.z + f1*w1.z + f2*w2.z + f3*w3.z + bb.z;
    acc[q*4+3] = f0*w0.w + f1*w1.w + f2*w2.w + f3*w3.w + bb.w;
  }
  for (int k = 0; k < HD; ++k) {
    float a  = hd[el*129 + k];
    float bs = hsr[el*129 + k];
    const float4* wa = (const float4*)(W1 + (size_t)k*HD + (jg<<4));
    const float4* wb = (const float4*)(W1 + (size_t)(128 + k)*HD + (jg<<4));
#pragma unroll
    for (int q = 0; q < 4; ++q) {
      float4 w1v = wa[q];
      float4 w2v = wb[q];
      acc[q*4+0] = fmaf(a, w1v.x, fmaf(bs, w2v.x, acc[q*4+0]));
      acc[q*4+1] = fmaf(a, w1v.y, fmaf(bs, w2v.y, acc[q*4+1]));
      acc[q*4+2] = fmaf(a, w1v.z, fmaf(bs, w2v.z, acc[q*4+2]));
      acc[q*4+3] = fmaf(a, w1v.w, fmaf(bs, w2v.w, acc[q*4+3]));
    }
  }
#pragma unroll
  for (int i = 0; i < 16; ++i) m1s[el*129 + (jg<<4) + i] = fmaxf(acc[i], 0.f);
  __syncthreads();
  float acc2[16];
#pragma unroll
  for (int q = 0; q < 4; ++q) {
    float4 bb = *(const float4*)(b2 + (jg<<4) + (q<<2));
    acc2[q*4+0] = bb.x; acc2[q*4+1] = bb.y; acc2[q*4+2] = bb.z; acc2[q*4+3] = bb.w;
  }
  for (int k = 0; k < HD; ++k) {
    float a = m1s[el*129 + k];
    const float4* wp = (const float4*)(W2 + (size_t)k*HD + (jg<<4));
#pragma unroll
    for (int q = 0; q < 4; ++q) {
      float4 wv = wp[q];
      acc2[q*4+0] = fmaf(a, wv.x, acc2[q*4+0]);
      acc2[q*4+1] = fmaf(a, wv.y, acc2[q*4+1]);
      acc2[q*4+2] = fmaf(a, wv.z, acc2[q*4+2]);
      acc2[q*4+3] = fmaf(a, wv.w, acc2[q*4+3]);
    }
  }
#pragma unroll
  for (int i = 0; i < 16; ++i) hd[el*129 + (jg<<4) + i] = fmaxf(acc2[i], 0.f);
  __syncthreads();
  if (tid < HD) {
    int j = tid;
    for (int e = 0; e < 32; ++e) {
      int de = ldst[e];
      atomicAdd(&agg[(size_t)de*HD + j], hd[e*129 + j] * invd[de]);
    }
  }
}

// ---------------- node update MLP via MFMA ----------------
// GEMM1: up1 = relu([h|agg](32x256,bf16) @ u1t + b1 + var*U1var)
// GEMM2: x = h + relu(up1(bf16) @ u2t + b2); write h; fp64 stats partials.

__global__ __launch_bounds__(256) void k_upd_mfma(float* __restrict__ h, const float* __restrict__ agg,
                                                  const float* __restrict__ pos,
                                                  const unsigned short* __restrict__ u1t,
                                                  const float* __restrict__ U1var, const float* __restrict__ b1,
                                                  const unsigned short* __restrict__ u2t, const float* __restrict__ b2,
                                                  double* __restrict__ stats) {
  __shared__ float hs[32 * 129];              // fp32 h rows; later holds x
  __shared__ unsigned short abf[32 * 264];    // bf16 [h|agg] rows, K=256
  __shared__ unsigned short u1bf[32 * 136];   // bf16 up1 rows, K=128
  __shared__ float lvar[32];
  int tid = threadIdx.x;
  int base = blockIdx.x * 32;
#pragma unroll
  for (int r = 0; r < 16; ++r) {
    int lin = r*256 + tid;
    int n = lin >> 7, j = lin & 127;
    int gn = base + n;
    float hv = (gn < NN) ? h[(size_t)gn*HD + j]   : 0.f;
    float av = (gn < NN) ? agg[(size_t)gn*HD + j] : 0.f;
    hs[n*129 + j] = hv;
    abf[n*264 + j]       = f2bf(hv);
    abf[n*264 + 128 + j] = f2bf(av);
  }
  if (tid < 32) lvar[tid] = (base + tid < NN) ? pos[(base + tid)*3 + 0] : 0.f;
  __syncthreads();
  int wv = tid >> 6, lane = tid & 63;
  int quad = lane >> 4, mrow = lane & 15;
  int mt = wv & 1, ntg = wv >> 1;
  // ---- GEMM1: K=256 ----
  {
    f32x4 acc[4];
#pragma unroll
    for (int t = 0; t < 4; ++t) acc[t] = (f32x4){0.f,0.f,0.f,0.f};
#pragma unroll
    for (int ks = 0; ks < 8; ++ks) {
      bf16x8 a = *(const bf16x8*)(abf + (mt*16 + mrow)*264 + ks*32 + quad*8);
#pragma unroll
      for (int t = 0; t < 4; ++t) {
        bf16x8 b = *(const bf16x8*)(u1t + (size_t)((ntg*4 + t)*16 + mrow)*256 + ks*32 + quad*8);
        acc[t] = __builtin_amdgcn_mfma_f32_16x16x32_bf16(a, b, acc[t], 0, 0, 0);
      }
    }
#pragma unroll
    for (int t = 0; t < 4; ++t) {
      int c = (ntg*4 + t)*16 + mrow;
      float bb = b1[c];
      float wvv = U1var[c];
#pragma unroll
      for (int r = 0; r < 4; ++r) {
        int m = mt*16 + quad*4 + r;
        float v = fmaxf(acc[t][r] + bb + lvar[m]*wvv, 0.f);
        u1bf[m*136 + c] = f2bf(v);
      }
    }
  }
  __syncthreads();
  // ---- GEMM2: K=128, residual epilogue into hs ----
  {
    f32x4 acc[4];
#pragma unroll
    for (int t = 0; t < 4; ++t) acc[t] = (f32x4){0.f,0.f,0.f,0.f};
#pragma unroll
    for (int ks = 0; ks < 4; ++ks) {
      bf16x8 a = *(const bf16x8*)(u1bf + (mt*16 + mrow)*136 + ks*32 + quad*8);
#pragma unroll
      for (int t = 0; t < 4; ++t) {
        bf16x8 b = *(const bf16x8*)(u2t + (size_t)((ntg*4 + t)*16 + mrow)*128 + ks*32 + quad*8);
        acc[t] = __builtin_amdgcn_mfma_f32_16x16x32_bf16(a, b, acc[t], 0, 0, 0);
      }
    }
#pragma unroll
    for (int t = 0; t < 4; ++t) {
      int c = (ntg*4 + t)*16 + mrow;
      float bb = b2[c];
#pragma unroll
      for (int r = 0; r < 4; ++r) {
        int m = mt*16 + quad*4 + r;
        if (base + m < NN)
          hs[m*129 + c] = hs[m*129 + c] + fmaxf(acc[t][r] + bb, 0.f);
        // invalid rows keep their 0 -> stats stay correct
      }
    }
  }
  __syncthreads();
  // ---- global write + fp64 stats ----
#pragma unroll
  for (int r = 0; r < 16; ++r) {
    int lin = r*256 + tid;
    int n = lin >> 7, j = lin & 127;
    int gn = base + n;
    if (gn < NN) h[(size_t)gn*HD + j] = hs[n*129 + j];
  }
  __syncthreads();
  if (tid < HD) {
    double s = 0.0, sq = 0.0;
    for (int e = 0; e < 32; ++e) { double v = (double)hs[e*129 + tid]; s += v; sq += v*v; }
    atomicAdd(&stats[tid], s);
    atomicAdd(&stats[HD + tid], sq);
  }
}

// ---------------- fallback node update MLP (fp32) ----------------

__global__ __launch_bounds__(256) void k_upd(float* __restrict__ h, const float* __restrict__ agg,
                                             const float* __restrict__ pos,
                                             const float* __restrict__ W1, const float* __restrict__ b1,
                                             const float* __restrict__ W2, const float* __restrict__ b2,
                                             double* __restrict__ stats) {
  __shared__ float hs[32 * 129];
  __shared__ float as_[32 * 129];
  int tid = threadIdx.x;
  int base = blockIdx.x * 32;
#pragma unroll
  for (int r = 0; r < 16; ++r) {
    int lin = r*256 + tid;
    int n = lin >> 7, j = lin & 127;
    int gn = base + n;
    hs[n*129 + j]  = (gn < NN) ? h[(size_t)gn*HD + j]   : 0.f;
    as_[n*129 + j] = (gn < NN) ? agg[(size_t)gn*HD + j] : 0.f;
  }
  __syncthreads();
  int nl = tid & 31, jg = tid >> 5;
  int gn = base + nl;
  float var = (gn < NN) ? pos[gn*3+0] : 0.f;
  float acc[16];
#pragma unroll
  for (int q = 0; q < 4; ++q) {
    int j = (jg<<4) + (q<<2);
    float4 bb = *(const float4*)(b1 + j);
    float4 wv = *(const float4*)(W1 + 256*HD + j);
    acc[q*4+0] = fmaf(var, wv.x, bb.x);
    acc[q*4+1] = fmaf(var, wv.y, bb.y);
    acc[q*4+2] = fmaf(var, wv.z, bb.z);
    acc[q*4+3] = fmaf(var, wv.w, bb.w);
  }
  for (int k = 0; k < HD; ++k) {
    float a = hs[nl*129 + k];
    float g = as_[nl*129 + k];
    const float4* w1p = (const float4*)(W1 + (size_t)k*HD + (jg<<4));
    const float4* w2p = (const float4*)(W1 + (size_t)(128 + k)*HD + (jg<<4));
#pragma unroll
    for (int q = 0; q < 4; ++q) {
      float4 wa = w1p[q];
      float4 wb = w2p[q];
      acc[q*4+0] = fmaf(a, wa.x, fmaf(g, wb.x, acc[q*4+0]));
      acc[q*4+1] = fmaf(a, wa.y, fmaf(g, wb.y, acc[q*4+1]));
      acc[q*4+2] = fmaf(a, wa.z, fmaf(g, wb.z, acc[q*4+2]));
      acc[q*4+3] = fmaf(a, wa.w, fmaf(g, wb.w, acc[q*4+3]));
    }
  }
  float up1[16];
#pragma unroll
  for (int i = 0; i < 16; ++i) up1[i] = fmaxf(acc[i], 0.f);
  __syncthreads();
#pragma unroll
  for (int i = 0; i < 16; ++i) as_[nl*129 + (jg<<4) + i] = up1[i];
  __syncthreads();
  float acc2[16];
#pragma unroll
  for (int q = 0; q < 4; ++q) {
    float4 bb = *(const float4*)(b2 + (jg<<4) + (q<<2));
    acc2[q*4+0] = bb.x; acc2[q*4+1] = bb.y; acc2[q*4+2] = bb.z; acc2[q*4+3] = bb.w;
  }
  for (int k = 0; k < HD; ++k) {
    float a = as_[nl*129 + k];
    const float4* wp = (const float4*)(W2 + (size_t)k*HD + (jg<<4));
#pragma unroll
    for (int q = 0; q < 4; ++q) {
      float4 wv = wp[q];
      acc2[q*4+0] = fmaf(a, wv.x, acc2[q*4+0]);
      acc2[q*4+1] = fmaf(a, wv.y, acc2[q*4+1]);
      acc2[q*4+2] = fmaf(a, wv.z, acc2[q*4+2]);
      acc2[q*4+3] = fmaf(a, wv.w, acc2[q*4+3]);
    }
  }
  float x[16];
#pragma unroll
  for (int i = 0; i < 16; ++i)
    x[i] = hs[nl*129 + (jg<<4) + i] + fmaxf(acc2[i], 0.f);
  if (gn < NN) {
#pragma unroll
    for (int q = 0; q < 4; ++q)
      *(float4*)(h + (size_t)gn*HD + (jg<<4) + (q<<2)) = make_float4(x[q*4+0], x[q*4+1], x[q*4+2], x[q*4+3]);
  }
  __syncthreads();
#pragma unroll
  for (int i = 0; i < 16; ++i) hs[nl*129 + (jg<<4) + i] = (gn < NN) ? x[i] : 0.f;
  __syncthreads();
  if (tid < HD) {
    double s = 0.0, sq = 0.0;
    for (int e = 0; e < 32; ++e) { double v = (double)hs[e*129 + tid]; s += v; sq += v*v; }
    atomicAdd(&stats[tid], s);
    atomicAdd(&stats[HD + tid], sq);
  }
}

// ---------------- CNN head (full 72-slot o2 coverage) ----------------

__global__ __launch_bounds__(256) void k_conv(const float* __restrict__ h,
                                              const float* __restrict__ c1W, const float* __restrict__ c1b,
                                              const float* __restrict__ c2W, const float* __restrict__ c2b,
                                              const float* __restrict__ c3W, const float* __restrict__ c3b,
                                              float* __restrict__ out) {
  __shared__ float xs[4][128];
  __shared__ float o1[4][152];
  __shared__ float o2[4][72];
  int tid = threadIdx.x;
  int w = tid >> 6, lane = tid & 63;
  int n = blockIdx.x * 4 + w;
  xs[w][lane]      = h[(size_t)n*HD + lane];
  xs[w][64 + lane] = h[(size_t)n*HD + 64 + lane];
  __syncthreads();
  for (int o = lane; o < 152; o += 64) {
    int oc = o / 38, t = o % 38;
    float s = c1b[oc];
#pragma unroll
    for (int k = 0; k < 16; ++k) s = fmaf(xs[w][t*3 + k], c1W[oc*16 + k], s);
    o1[w][oc*38 + t] = fmaxf(s, 0.f);
  }
  __syncthreads();
  for (int o = lane; o < 72; o += 64) {
    int oc = o / 9, t = o % 9;
    float s = c2b[oc];
    for (int ic = 0; ic < 4; ++ic) {
#pragma unroll
      for (int k = 0; k < 12; ++k) s = fmaf(o1[w][ic*38 + t*3 + k], c2W[oc*48 + ic*12 + k], s);
    }
    o2[w][oc*9 + t] = fmaxf(s, 0.f);
  }
  __syncthreads();
  int ic = lane >> 3, k = lane & 7;
  float t3 = o2[w][ic*9 + k] * c3W[ic*8 + k];
  for (int off = 32; off; off >>= 1) t3 += __shfl_down(t3, off);
  if (lane == 0) out[n] = 0.001f * (t3 + c3b[0]);
}

// ---------------- launcher ----------------

extern "C" void kernel_launch(void* const* d_in, const int* in_sizes, int n_in,
                              void* d_out, int out_size, void* d_ws, size_t ws_size,
                              hipStream_t stream) {
  (void)out_size;
  float* out = (float*)d_out;

  static const int expect[27] = {
    50000, 150000, 1200000,
    512, 128, 128, 128,
    16384, 128, 128, 128,
    199680, 768, 98304, 768, 197376, 768, 98304, 768,
    768, 768,
    64, 4, 384, 8, 64, 1
  };
  if (n_in != 27) { k_code<<<1, 64, 0, stream>>>(out, 5000099.f); return; }
  for (int i = 0; i < 27; ++i)
    if (in_sizes[i] != expect[i]) { k_code<<<1, 64, 0, stream>>>(out, 5000100.f + (float)i); return; }

  const float* u    = (const float*)d_in[0];
  const float* pos  = (const float*)d_in[1];
  const int*   ei   = (const int*)d_in[2];
  const float* eW1  = (const float*)d_in[3];
  const float* eb1  = (const float*)d_in[4];
  const float* eg1  = (const float*)d_in[5];
  const float* ebe1 = (const float*)d_in[6];
  const float* eW2  = (const float*)d_in[7];
  const float* eb2  = (const float*)d_in[8];
  const float* eg2  = (const float*)d_in[9];
  const float* ebe2 = (const float*)d_in[10];
  const float* m1W  = (const float*)d_in[11];
  const float* m1b  = (const float*)d_in[12];
  const float* m2W  = (const float*)d_in[13];
  const float* m2b  = (const float*)d_in[14];
  const float* u1W  = (const float*)d_in[15];
  const float* u1b  = (const float*)d_in[16];
  const float* u2W  = (const float*)d_in[17];
  const float* u2b  = (const float*)d_in[18];
  const float* bng  = (const float*)d_in[19];
  const float* bnb  = (const float*)d_in[20];
  const float* c1W  = (const float*)d_in[21];
  const float* c1b  = (const float*)d_in[22];
  const float* c2W  = (const float*)d_in[23];
  const float* c2b  = (const float*)d_in[24];
  const float* c3W  = (const float*)d_in[25];
  const float* c3b  = (const float*)d_in[26];

  // ---- workspace ----
  char* wsp = (char*)d_ws;
  size_t off = 0;
  auto alloc = [&](size_t bytes) -> void* {
    void* p = wsp + off;
    off = (off + bytes + 255) & ~(size_t)255;
    return p;
  };
  double* stats  = (double*)alloc(256 * 8);
  float*  musig  = (float*)alloc(256 * 4);
  int*    deg    = (int*)alloc((size_t)NN * 4);
  int*    cursor = (int*)alloc((size_t)NN * 4);
  int*    blk    = (int*)alloc(256 * 4);
  float*  invd   = (float*)alloc((size_t)NN * 4);
  float*  h      = (float*)alloc((size_t)NN * HD * 4);
  float*  agg    = (float*)alloc((size_t)NN * HD * 4);
  size_t needed_direct = off;
  float*  A      = (float*)alloc((size_t)NN * HD * 4);
  float*  B      = (float*)alloc((size_t)NN * HD * 4);
  float*  sfeat  = (float*)alloc((size_t)NE * 4 * 4);
  int*    ssrc   = (int*)alloc((size_t)NE * 4);
  int*    sdst   = (int*)alloc((size_t)NE * 4);
  unsigned short* w2t = (unsigned short*)alloc((size_t)NL * HD * HD * 2);
  unsigned short* u2t = (unsigned short*)alloc((size_t)NL * HD * HD * 2);
  unsigned short* u1t = (unsigned short*)alloc((size_t)NL * HD * 256 * 2);
  unsigned short* abt = (unsigned short*)alloc((size_t)NL * 256 * HD * 2);
  size_t needed_fast = off;

  if (ws_size < needed_direct) {
    k_code<<<1, 64, 0, stream>>>(out, (float)(9000000u + (unsigned)(ws_size >> 20)));
    return;
  }
  const bool fast = (ws_size >= needed_fast);

  const int nbN  = (NN + 255) / 256;   // 196
  const int nbE  = (NE + 255) / 256;   // 2344
  const int nt32 = (NN + 31) / 32;     // 1563
  const int nbBN = NN * HD / 256;      // 25000

  // ---- degree / inverse degree (+ sort + bf16 weight transposes if fast) ----
  hipMemsetAsync(deg, 0, (size_t)NN * 4, stream);
  k_deg<<<nbE, 256, 0, stream>>>(ei, deg);
  k_scan1<<<nbN, 256, 0, stream>>>(deg, cursor, blk, invd);
  if (fast) {
    k_scan2<<<1, 256, 0, stream>>>(blk, nbN);
    k_scan3<<<nbN, 256, 0, stream>>>(cursor, blk);
    k_scatter<<<nbE, 256, 0, stream>>>(ei, u, pos, cursor, ssrc, sdst, sfeat);
    k_w2t<<<(NL*HD*HD + 255) / 256, 256, 0, stream>>>(m2W, w2t);
    k_w2t<<<(NL*HD*HD + 255) / 256, 256, 0, stream>>>(u2W, u2t);
    k_u1t<<<(NL*HD*256 + 255) / 256, 256, 0, stream>>>(u1W, u1t);
    k_abt<<<(NL*256*HD + 255) / 256, 256, 0, stream>>>(m1W, abt);
  }

  // ---- embedding ----
  hipMemsetAsync(stats, 0, 256 * 8, stream);
  k_emb1<<<nt32, 256, 0, stream>>>(u, pos, eW1, eb1, h, stats);
  k_redA<<<1, 128, 0, stream>>>(stats, musig);
  k_bn<<<nbBN, 256, 0, stream>>>(h, musig, eg1, ebe1, 1);
  hipMemsetAsync(stats, 0, 256 * 8, stream);
  k_emb2<<<nt32, 256, 0, stream>>>(h, eW2, eb2, stats);
  k_redA<<<1, 128, 0, stream>>>(stats, musig);
  k_bn<<<nbBN, 256, 0, stream>>>(h, musig, eg2, ebe2, 0);

  // ---- message-passing layers ----
  for (int i = 0; i < NL; ++i) {
    hipMemsetAsync(agg, 0, (size_t)NN * HD * 4, stream);
    if (fast) {
      k_ab_mfma<<<nt32, 256, 0, stream>>>(h, abt + (size_t)i * 256 * HD, A, B);
      k_msg_mfma<<<NE / 32, 256, 0, stream>>>(A, B, ssrc, sdst, sfeat, invd,
                                              m1W + (size_t)i * 260 * HD, m1b + (size_t)i * HD,
                                              w2t + (size_t)i * HD * HD, m2b + (size_t)i * HD, agg);
    } else {
      k_msg_direct<<<NE / 32, 256, 0, stream>>>(h, ei, u, pos, invd,
                                                m1W + (size_t)i * 260 * HD, m1b + (size_t)i * HD,
                                                m2W + (size_t)i * HD * HD, m2b + (size_t)i * HD, agg);
    }
    hipMemsetAsync(stats, 0, 256 * 8, stream);
    if (fast) {
      k_upd_mfma<<<nt32, 256, 0, stream>>>(h, agg, pos,
                                           u1t + (size_t)i * HD * 256,
                                           u1W + (size_t)i * 32896 + 256 * HD,
                                           u1b + (size_t)i * HD,
                                           u2t + (size_t)i * HD * HD,
                                           u2b + (size_t)i * HD, stats);
    } else {
      k_upd<<<nt32, 256, 0, stream>>>(h, agg, pos,
                                      u1W + (size_t)i * 257 * HD, u1b + (size_t)i * HD,
                                      u2W + (size_t)i * HD * HD, u2b + (size_t)i * HD, stats);
    }
    k_redA<<<1, 128, 0, stream>>>(stats, musig);
    k_bn<<<nbBN, 256, 0, stream>>>(h, musig, bng + (size_t)i * HD, bnb + (size_t)i * HD, 0);
  }

  // ---- CNN head ----
  k_conv<<<NN / 4, 256, 0, stream>>>(h, c1W, c1b, c2W, c2b, c3W, c3b, out);
}

// Round 18
// 2636.007 us; speedup vs baseline: 8.1887x; 1.0524x over previous
//
#include <hip/hip_runtime.h>

#define NN 50000
#define NE 600000
#define HD 128
#define NL 6

typedef __attribute__((ext_vector_type(8))) short bf16x8;
typedef __attribute__((ext_vector_type(4))) float f32x4;

__device__ inline unsigned short f2bf(float x) {
  unsigned u = __float_as_uint(x);
  u += 0x7FFF + ((u >> 16) & 1);           // RNE on raw bits
  return (unsigned short)(u >> 16);
}
__device__ inline float bf2f(unsigned short s) {
  return __uint_as_float((unsigned)s << 16);
}

__global__ void k_code(float* __restrict__ out, float code) {
  if (threadIdx.x == 0 && blockIdx.x == 0) out[0] = code;
}

// ---------------- weight transposes -> bf16 [layer][n][k] ----------------

__global__ __launch_bounds__(256) void k_w2t(const float* __restrict__ W, unsigned short* __restrict__ T) {
  int idx = blockIdx.x * 256 + threadIdx.x;
  if (idx >= NL * HD * HD) return;
  int l = idx >> 14, r = idx & 16383;
  int n = r >> 7, k = r & 127;
  T[idx] = f2bf(W[(l << 14) + (k << 7) + n]);
}

__global__ __launch_bounds__(256) void k_u1t(const float* __restrict__ W, unsigned short* __restrict__ T) {
  int idx = blockIdx.x * 256 + threadIdx.x;
  if (idx >= NL * 128 * 256) return;
  int l = idx >> 15, r = idx & 32767;
  int n = r >> 8, k = r & 255;
  T[idx] = f2bf(W[l * 32896 + k * 128 + n]);
}

__global__ __launch_bounds__(256) void k_abt(const float* __restrict__ W, unsigned short* __restrict__ T) {
  int idx = blockIdx.x * 256 + threadIdx.x;
  if (idx >= NL * 256 * 128) return;
  int l = idx >> 15, r = idx & 32767;
  int n = r >> 7, k = r & 127;
  int row = (n < 128) ? k : 128 + k;
  int col = n & 127;
  T[idx] = f2bf(W[l * 33280 + row * 128 + col]);
}

// ---------------- degree histogram, scan, counting sort (by dst) ----------------

__global__ __launch_bounds__(256) void k_deg(const int* __restrict__ ei, int* __restrict__ deg) {
  int e = blockIdx.x * 256 + threadIdx.x;
  if (e < NE) {
    int d = ei[NE + e];
    if (d >= 0 && d < NN) atomicAdd(&deg[d], 1);
  }
}

__global__ __launch_bounds__(256) void k_scan1(const int* __restrict__ deg, int* __restrict__ cursor,
                                               int* __restrict__ blk, float* __restrict__ invd) {
  __shared__ int sd[256];
  int t = threadIdx.x;
  int i = blockIdx.x * 256 + t;
  int v = (i < NN) ? deg[i] : 0;
  sd[t] = v;
  __syncthreads();
  for (int off = 1; off < 256; off <<= 1) {
    int x = (t >= off) ? sd[t - off] : 0;
    __syncthreads();
    if (t >= off) sd[t] += x;
    __syncthreads();
  }
  int incl = sd[t];
  if (i < NN) {
    cursor[i] = incl - v;
    invd[i] = 1.0f / fmaxf((float)v, 1.0f);
  }
  if (t == 255) blk[blockIdx.x] = incl;
}

__global__ __launch_bounds__(256) void k_scan2(int* __restrict__ blk, int nb) {
  __shared__ int sd[256];
  int t = threadIdx.x;
  int v = (t < nb) ? blk[t] : 0;
  sd[t] = v;
  __syncthreads();
  for (int off = 1; off < 256; off <<= 1) {
    int x = (t >= off) ? sd[t - off] : 0;
    __syncthreads();
    if (t >= off) sd[t] += x;
    __syncthreads();
  }
  if (t < nb) blk[t] = sd[t] - v;
}

__global__ __launch_bounds__(256) void k_scan3(int* __restrict__ cursor, const int* __restrict__ blk) {
  int i = blockIdx.x * 256 + threadIdx.x;
  if (i < NN) cursor[i] += blk[blockIdx.x];
}

__global__ __launch_bounds__(256) void k_scatter(const int* __restrict__ ei, const float* __restrict__ u,
                                                 const float* __restrict__ pos, int* __restrict__ cursor,
                                                 int* __restrict__ ssrc, int* __restrict__ sdst,
                                                 float* __restrict__ sfeat) {
  int e = blockIdx.x * 256 + threadIdx.x;
  if (e >= NE) return;
  int s = ei[e], d = ei[NE + e];
  s = s < 0 ? 0 : (s >= NN ? NN - 1 : s);
  d = d < 0 ? 0 : (d >= NN ? NN - 1 : d);
  int p = atomicAdd(&cursor[d], 1);
  ssrc[p] = s;
  sdst[p] = d;
  float du  = u[d] - u[s];
  float dpx = pos[d*3+1] - pos[s*3+1];
  float dpy = pos[d*3+2] - pos[s*3+2];
  float vi  = pos[d*3+0];
  ((float4*)sfeat)[p] = make_float4(du, dpx, dpy, vi);
}

// ---------------- embedding ----------------

__global__ __launch_bounds__(256) void k_emb1(const float* __restrict__ u, const float* __restrict__ pos,
                                              const float* __restrict__ W, const float* __restrict__ b,
                                              float* __restrict__ h, double* __restrict__ stats) {
  __shared__ float xs[32 * 129];
  int tid = threadIdx.x;
  int nl = tid & 31, jg = tid >> 5;
  int gn = blockIdx.x * 32 + nl;
  float f0 = 0.f, f1 = 0.f, f2 = 0.f, f3 = 0.f;
  if (gn < NN) { f0 = u[gn]; f1 = pos[gn*3+1]; f2 = pos[gn*3+2]; f3 = pos[gn*3+0]; }
  float x[16];
#pragma unroll
  for (int q = 0; q < 4; ++q) {
    int j = (jg << 4) + (q << 2);
    float4 w0 = *(const float4*)(W + 0*HD + j);
    float4 w1 = *(const float4*)(W + 1*HD + j);
    float4 w2 = *(const float4*)(W + 2*HD + j);
    float4 w3 = *(const float4*)(W + 3*HD + j);
    float4 bb = *(const float4*)(b + j);
    x[q*4+0] = f0*w0.x + f1*w1.x + f2*w2.x + f3*w3.x + bb.x;
    x[q*4+1] = f0*w0.y + f1*w1.y + f2*w2.y + f3*w3.y + bb.y;
    x[q*4+2] = f0*w0.z + f1*w1.z + f2*w2.z + f3*w3.z + bb.z;
    x[q*4+3] = f0*w0.w + f1*w1.w + f2*w2.w + f3*w3.w + bb.w;
  }
  if (gn < NN) {
#pragma unroll
    for (int q = 0; q < 4; ++q)
      *(float4*)(h + (size_t)gn*HD + (jg<<4) + (q<<2)) = make_float4(x[q*4+0], x[q*4+1], x[q*4+2], x[q*4+3]);
  }
#pragma unroll
  for (int i = 0; i < 16; ++i) xs[nl*129 + (jg<<4) + i] = (gn < NN) ? x[i] : 0.f;
  __syncthreads();
  if (tid < HD) {
    double s = 0.0, sq = 0.0;
    for (int e = 0; e < 32; ++e) { double v = (double)xs[e*129 + tid]; s += v; sq += v*v; }
    atomicAdd(&stats[tid], s);
    atomicAdd(&stats[HD + tid], sq);
  }
}

__global__ __launch_bounds__(256) void k_emb2(float* __restrict__ h, const float* __restrict__ W,
                                              const float* __restrict__ b, double* __restrict__ stats) {
  __shared__ float hs[32 * 129];
  int tid = threadIdx.x;
  int base = blockIdx.x * 32;
#pragma unroll
  for (int r = 0; r < 16; ++r) {
    int lin = r*256 + tid;
    int n = lin >> 7, j = lin & 127;
    int gn = base + n;
    hs[n*129 + j] = (gn < NN) ? h[(size_t)gn*HD + j] : 0.f;
  }
  __syncthreads();
  int nl = tid & 31, jg = tid >> 5;
  int gn = base + nl;
  float acc[16];
#pragma unroll
  for (int q = 0; q < 4; ++q) {
    float4 bb = *(const float4*)(b + (jg<<4) + (q<<2));
    acc[q*4+0] = bb.x; acc[q*4+1] = bb.y; acc[q*4+2] = bb.z; acc[q*4+3] = bb.w;
  }
  for (int k = 0; k < HD; ++k) {
    float a = hs[nl*129 + k];
    const float4* wp = (const float4*)(W + (size_t)k*HD + (jg<<4));
#pragma unroll
    for (int q = 0; q < 4; ++q) {
      float4 wv = wp[q];
      acc[q*4+0] = fmaf(a, wv.x, acc[q*4+0]);
      acc[q*4+1] = fmaf(a, wv.y, acc[q*4+1]);
      acc[q*4+2] = fmaf(a, wv.z, acc[q*4+2]);
      acc[q*4+3] = fmaf(a, wv.w, acc[q*4+3]);
    }
  }
  if (gn < NN) {
#pragma unroll
    for (int q = 0; q < 4; ++q)
      *(float4*)(h + (size_t)gn*HD + (jg<<4) + (q<<2)) = make_float4(acc[q*4+0], acc[q*4+1], acc[q*4+2], acc[q*4+3]);
  }
  __syncthreads();
#pragma unroll
  for (int i = 0; i < 16; ++i) hs[nl*129 + (jg<<4) + i] = (gn < NN) ? acc[i] : 0.f;
  __syncthreads();
  if (tid < HD) {
    double s = 0.0, sq = 0.0;
    for (int e = 0; e < 32; ++e) { double v = (double)hs[e*129 + tid]; s += v; sq += v*v; }
    atomicAdd(&stats[tid], s);
    atomicAdd(&stats[HD + tid], sq);
  }
}

__global__ void k_redA(const double* __restrict__ stats, float* __restrict__ musig) {
  int c = threadIdx.x;   // 128
  double mu  = stats[c] / (double)NN;
  double var = stats[128 + c] / (double)NN - mu * mu;
  musig[c]      = (float)mu;
  musig[HD + c] = (float)(1.0 / sqrt(var + 1e-5));
}

__global__ __launch_bounds__(256) void k_bn(float* __restrict__ h, const float* __restrict__ musig,
                                            const float* __restrict__ g, const float* __restrict__ be,
                                            int relu) {
  int idx = blockIdx.x * 256 + threadIdx.x;
  if (idx >= NN * HD) return;
  int j = idx & 127;
  float x = h[idx];
  x = g[j] * (x - musig[j]) * musig[HD + j] + be[j];
  if (relu) x = fmaxf(x, 0.f);
  h[idx] = x;
}

// ---------------- k_ab via MFMA, fused BN of previous layer, bf16 A/B output ----------------

__global__ __launch_bounds__(256) void k_ab_mfma(float* __restrict__ h,
                                                 const unsigned short* __restrict__ abt,
                                                 const float* __restrict__ musig,
                                                 const float* __restrict__ g, const float* __restrict__ be,
                                                 int applyBN,
                                                 unsigned short* __restrict__ A, unsigned short* __restrict__ B) {
  __shared__ unsigned short hbf[32 * 136];
  int tid = threadIdx.x;
  int base = blockIdx.x * 32;
#pragma unroll
  for (int r = 0; r < 16; ++r) {
    int lin = r*256 + tid;
    int n = lin >> 7, j = lin & 127;
    int gn = base + n;
    float hv = (gn < NN) ? h[(size_t)gn*HD + j] : 0.f;
    if (applyBN) {
      hv = g[j] * (hv - musig[j]) * musig[HD + j] + be[j];
      if (gn < NN) h[(size_t)gn*HD + j] = hv;
    }
    hbf[n*136 + j] = f2bf((gn < NN) ? hv : 0.f);
  }
  __syncthreads();
  int wv = tid >> 6, lane = tid & 63;
  int quad = lane >> 4, mrow = lane & 15;
  int mt = wv & 1, ntg = wv >> 1;
  f32x4 acc[8];
#pragma unroll
  for (int t = 0; t < 8; ++t) acc[t] = (f32x4){0.f,0.f,0.f,0.f};
#pragma unroll
  for (int ks = 0; ks < 4; ++ks) {
    bf16x8 a = *(const bf16x8*)(hbf + (mt*16 + mrow)*136 + ks*32 + quad*8);
#pragma unroll
    for (int t = 0; t < 8; ++t) {
      bf16x8 b = *(const bf16x8*)(abt + (size_t)((ntg*8 + t)*16 + mrow)*128 + ks*32 + quad*8);
      acc[t] = __builtin_amdgcn_mfma_f32_16x16x32_bf16(a, b, acc[t], 0, 0, 0);
    }
  }
#pragma unroll
  for (int t = 0; t < 8; ++t) {
    int c = (ntg*8 + t)*16 + mrow;
#pragma unroll
    for (int r = 0; r < 4; ++r) {
      int gn = base + mt*16 + quad*4 + r;
      if (gn < NN) {
        if (c < 128) A[(size_t)gn*HD + c]       = f2bf(acc[t][r]);
        else         B[(size_t)gn*HD + c - 128] = f2bf(acc[t][r]);
      }
    }
  }
}

// ---------------- edge message MLP: bf16 A/B gather + fp32 m1 + bf16-MFMA m2 + segmented flush ----------------

__global__ __launch_bounds__(256) void k_msg_mfma(const unsigned short* __restrict__ A,
                                                  const unsigned short* __restrict__ B,
                                                  const int* __restrict__ ssrc, const int* __restrict__ sdst,
                                                  const float* __restrict__ sfeat, const float* __restrict__ invd,
                                                  const float* __restrict__ W1, const float* __restrict__ b1,
                                                  const unsigned short* __restrict__ w2t, const float* __restrict__ b2,
                                                  float* __restrict__ agg) {
  __shared__ unsigned short m1bf[32 * 136];
  __shared__ float m2s[32 * 129];
  __shared__ int lsrc[32];
  __shared__ int ldst[32];
  __shared__ float lfeat[32][4];
  int tid = threadIdx.x;
  int base = blockIdx.x * 32;
  if (tid < 32) { lsrc[tid] = ssrc[base + tid]; ldst[tid] = sdst[base + tid]; }
  if (tid < 128) ((float*)lfeat)[tid] = sfeat[(size_t)base*4 + tid];
  __syncthreads();
  {
    int el = tid & 31, jg = tid >> 5;
    int s = lsrc[el], d = ldst[el];
    float f0 = lfeat[el][0], f1 = lfeat[el][1], f2 = lfeat[el][2], f3 = lfeat[el][3];
    const unsigned short* Ar = A + (size_t)d*HD + (jg<<4);
    const unsigned short* Br = B + (size_t)s*HD + (jg<<4);
    bf16x8 a0 = *(const bf16x8*)(Ar);
    bf16x8 a1 = *(const bf16x8*)(Ar + 8);
    bf16x8 b0 = *(const bf16x8*)(Br);
    bf16x8 b1v = *(const bf16x8*)(Br + 8);
    const float* We = W1 + 256*HD + (jg<<4);
    float m1[16];
#pragma unroll
    for (int q = 0; q < 4; ++q) {
      float4 w0 = *(const float4*)(We + 0*HD + (q<<2));
      float4 w1 = *(const float4*)(We + 1*HD + (q<<2));
      float4 w2 = *(const float4*)(We + 2*HD + (q<<2));
      float4 w3 = *(const float4*)(We + 3*HD + (q<<2));
      float4 bb = *(const float4*)(b1 + (jg<<4) + (q<<2));
#pragma unroll
      for (int z = 0; z < 4; ++z) {
        int i = q*4 + z;
        unsigned short av = (i < 8) ? (unsigned short)a0[i] : (unsigned short)a1[i-8];
        unsigned short bv = (i < 8) ? (unsigned short)b0[i] : (unsigned short)b1v[i-8];
        float we  = (z==0?w0.x:(z==1?w0.y:(z==2?w0.z:w0.w)));
        float w1e = (z==0?w1.x:(z==1?w1.y:(z==2?w1.z:w1.w)));
        float w2e = (z==0?w2.x:(z==1?w2.y:(z==2?w2.z:w2.w)));
        float w3e = (z==0?w3.x:(z==1?w3.y:(z==2?w3.z:w3.w)));
        float bbe = (z==0?bb.x:(z==1?bb.y:(z==2?bb.z:bb.w)));
        m1[i] = fmaxf(bf2f(av) + bf2f(bv) + f0*we + f1*w1e + f2*w2e + f3*w3e + bbe, 0.f);
      }
    }
    unsigned* p = (unsigned*)(m1bf + el*136 + (jg<<4));
#pragma unroll
    for (int i = 0; i < 8; ++i)
      p[i] = (unsigned)f2bf(m1[2*i]) | ((unsigned)f2bf(m1[2*i+1]) << 16);
  }
  __syncthreads();
  {
    int wv = tid >> 6, lane = tid & 63;
    int quad = lane >> 4, mrow = lane & 15;
    int mt = wv & 1, ntg = wv >> 1;
    f32x4 acc0 = {0.f,0.f,0.f,0.f}, acc1 = acc0, acc2 = acc0, acc3 = acc0;
#pragma unroll
    for (int ks = 0; ks < 4; ++ks) {
      bf16x8 a = *(const bf16x8*)(m1bf + (mt*16 + mrow)*136 + ks*32 + quad*8);
      bf16x8 bf0 = *(const bf16x8*)(w2t + ((ntg*4+0)*16 + mrow)*128 + ks*32 + quad*8);
      bf16x8 bf1 = *(const bf16x8*)(w2t + ((ntg*4+1)*16 + mrow)*128 + ks*32 + quad*8);
      bf16x8 bf2 = *(const bf16x8*)(w2t + ((ntg*4+2)*16 + mrow)*128 + ks*32 + quad*8);
      bf16x8 bf3 = *(const bf16x8*)(w2t + ((ntg*4+3)*16 + mrow)*128 + ks*32 + quad*8);
      acc0 = __builtin_amdgcn_mfma_f32_16x16x32_bf16(a, bf0, acc0, 0, 0, 0);
      acc1 = __builtin_amdgcn_mfma_f32_16x16x32_bf16(a, bf1, acc1, 0, 0, 0);
      acc2 = __builtin_amdgcn_mfma_f32_16x16x32_bf16(a, bf2, acc2, 0, 0, 0);
      acc3 = __builtin_amdgcn_mfma_f32_16x16x32_bf16(a, bf3, acc3, 0, 0, 0);
    }
    f32x4 av[4] = {acc0, acc1, acc2, acc3};
#pragma unroll
    for (int t = 0; t < 4; ++t) {
      int c = (ntg*4 + t)*16 + mrow;
      float bb = b2[c];
#pragma unroll
      for (int r = 0; r < 4; ++r) {
        int erow = mt*16 + quad*4 + r;
        m2s[erow*129 + c] = fmaxf(av[t][r] + bb, 0.f);
      }
    }
  }
  __syncthreads();
  if (tid < HD) {
    int j = tid;
    float a2 = 0.f;
    int cur = ldst[0];
    for (int e = 0; e < 32; ++e) {
      int de = ldst[e];
      if (de != cur) {
        atomicAdd(&agg[(size_t)cur*HD + j], a2 * invd[cur]);
        a2 = 0.f;
        cur = de;
      }
      a2 += m2s[e*129 + j];
    }
    atomicAdd(&agg[(size_t)cur*HD + j], a2 * invd[cur]);
  }
}

// ---------------- fallback: direct edge MLP + naive atomics (unsorted) ----------------

__global__ __launch_bounds__(256) void k_msg_direct(const float* __restrict__ h,
                                                    const int* __restrict__ ei, const float* __restrict__ u,
                                                    const float* __restrict__ pos, const float* __restrict__ invd,
                                                    const float* __restrict__ W1, const float* __restrict__ b1,
                                                    const float* __restrict__ W2, const float* __restrict__ b2,
                                                    float* __restrict__ agg) {
  __shared__ float hd[32 * 129];
  __shared__ float hsr[32 * 129];
  __shared__ float m1s[32 * 129];
  __shared__ int lsrc[32];
  __shared__ int ldst[32];
  __shared__ float lf[32][4];
  int tid = threadIdx.x;
  int base = blockIdx.x * 32;
  if (tid < 32) {
    int e = base + tid;
    int s = ei[e], d = ei[NE + e];
    s = s < 0 ? 0 : (s >= NN ? NN - 1 : s);
    d = d < 0 ? 0 : (d >= NN ? NN - 1 : d);
    lsrc[tid] = s; ldst[tid] = d;
    lf[tid][0] = u[d] - u[s];
    lf[tid][1] = pos[d*3+1] - pos[s*3+1];
    lf[tid][2] = pos[d*3+2] - pos[s*3+2];
    lf[tid][3] = pos[d*3+0];
  }
  __syncthreads();
#pragma unroll
  for (int r = 0; r < 16; ++r) {
    int lin = r*256 + tid;
    int n = lin >> 7, j = lin & 127;
    hd[n*129 + j]  = h[(size_t)ldst[n]*HD + j];
    hsr[n*129 + j] = h[(size_t)lsrc[n]*HD + j];
  }
  __syncthreads();
  int el = tid & 31, jg = tid >> 5;
  float f0 = lf[el][0], f1 = lf[el][1], f2 = lf[el][2], f3 = lf[el][3];
  const float* We = W1 + 256*HD + (jg<<4);
  float acc[16];
#pragma unroll
  for (int q = 0; q < 4; ++q) {
    float4 w0 = *(const float4*)(We + 0*HD + (q<<2));
    float4 w1 = *(const float4*)(We + 1*HD + (q<<2));
    float4 w2 = *(const float4*)(We + 2*HD + (q<<2));
    float4 w3 = *(const float4*)(We + 3*HD + (q<<2));
    float4 bb = *(const float4*)(b1 + (jg<<4) + (q<<2));
    acc[q*4+0] = f0*w0.x + f1*w1.x + f2*w2.x + f3*w3.x + bb.x;
    acc[q*4+1] = f0*w0.y + f1*w1.y + f2*w2.y + f3*w3.y + bb.y;
    acc[q*4+2] = f0*w0.z + f1*w1.z + f2*w2.z + f3*w3.z + bb.z;
    acc[q*4+3] = f0*w0.w + f1*w1.w + f2*w2.w + f3*w3.w + bb.w;
  }
  for (int k = 0; k < HD; ++k) {
    float a  = hd[el*129 + k];
    float bs = hsr[el*129 + k];
    const float4* wa = (const float4*)(W1 + (size_t)k*HD + (jg<<4));
    const float4* wb = (const float4*)(W1 + (size_t)(128 + k)*HD + (jg<<4));
#pragma unroll
    for (int q = 0; q < 4; ++q) {
      float4 w1v = wa[q];
      float4 w2v = wb[q];
      acc[q*4+0] = fmaf(a, w1v.x, fmaf(bs, w2v.x, acc[q*4+0]));
      acc[q*4+1] = fmaf(a, w1v.y, fmaf(bs, w2v.y, acc[q*4+1]));
      acc[q*4+2] = fmaf(a, w1v.z, fmaf(bs, w2v.z, acc[q*4+2]));
      acc[q*4+3] = fmaf(a, w1v.w, fmaf(bs, w2v.w, acc[q*4+3]));
    }
  }
#pragma unroll
  for (int i = 0; i < 16; ++i) m1s[el*129 + (jg<<4) + i] = fmaxf(acc[i], 0.f);
  __syncthreads();
  float acc2[16];
#pragma unroll
  for (int q = 0; q < 4; ++q) {
    float4 bb = *(const float4*)(b2 + (jg<<4) + (q<<2));
    acc2[q*4+0] = bb.x; acc2[q*4+1] = bb.y; acc2[q*4+2] = bb.z; acc2[q*4+3] = bb.w;
  }
  for (int k = 0; k < HD; ++k) {
    float a = m1s[el*129 + k];
    const float4* wp = (const float4*)(W2 + (size_t)k*HD + (jg<<4));
#pragma unroll
    for (int q = 0; q < 4; ++q) {
      float4 wv = wp[q];
      acc2[q*4+0] = fmaf(a, wv.x, acc2[q*4+0]);
      acc2[q*4+1] = fmaf(a, wv.y, acc2[q*4+1]);
      acc2[q*4+2] = fmaf(a, wv.z, acc2[q*4+2]);
      acc2[q*4+3] = fmaf(a, wv.w, acc2[q*4+3]);
    }
  }
#pragma unroll
  for (int i = 0; i < 16; ++i) hd[el*129 + (jg<<4) + i] = fmaxf(acc2[i], 0.f);
  __syncthreads();
  if (tid < HD) {
    int j = tid;
    for (int e = 0; e < 32; ++e) {
      int de = ldst[e];
      atomicAdd(&agg[(size_t)de*HD + j], hd[e*129 + j] * invd[de]);
    }
  }
}

// ---------------- node update MLP via MFMA ----------------

__global__ __launch_bounds__(256) void k_upd_mfma(float* __restrict__ h, const float* __restrict__ agg,
                                                  const float* __restrict__ pos,
                                                  const unsigned short* __restrict__ u1t,
                                                  const float* __restrict__ U1var, const float* __restrict__ b1,
                                                  const unsigned short* __restrict__ u2t, const float* __restrict__ b2,
                                                  double* __restrict__ stats) {
  __shared__ float hs[32 * 129];
  __shared__ unsigned short abf[32 * 264];
  __shared__ unsigned short u1bf[32 * 136];
  __shared__ float lvar[32];
  int tid = threadIdx.x;
  int base = blockIdx.x * 32;
#pragma unroll
  for (int r = 0; r < 16; ++r) {
    int lin = r*256 + tid;
    int n = lin >> 7, j = lin & 127;
    int gn = base + n;
    float hv = (gn < NN) ? h[(size_t)gn*HD + j]   : 0.f;
    float av = (gn < NN) ? agg[(size_t)gn*HD + j] : 0.f;
    hs[n*129 + j] = hv;
    abf[n*264 + j]       = f2bf(hv);
    abf[n*264 + 128 + j] = f2bf(av);
  }
  if (tid < 32) lvar[tid] = (base + tid < NN) ? pos[(base + tid)*3 + 0] : 0.f;
  __syncthreads();
  int wv = tid >> 6, lane = tid & 63;
  int quad = lane >> 4, mrow = lane & 15;
  int mt = wv & 1, ntg = wv >> 1;
  {
    f32x4 acc[4];
#pragma unroll
    for (int t = 0; t < 4; ++t) acc[t] = (f32x4){0.f,0.f,0.f,0.f};
#pragma unroll
    for (int ks = 0; ks < 8; ++ks) {
      bf16x8 a = *(const bf16x8*)(abf + (mt*16 + mrow)*264 + ks*32 + quad*8);
#pragma unroll
      for (int t = 0; t < 4; ++t) {
        bf16x8 b = *(const bf16x8*)(u1t + (size_t)((ntg*4 + t)*16 + mrow)*256 + ks*32 + quad*8);
        acc[t] = __builtin_amdgcn_mfma_f32_16x16x32_bf16(a, b, acc[t], 0, 0, 0);
      }
    }
#pragma unroll
    for (int t = 0; t < 4; ++t) {
      int c = (ntg*4 + t)*16 + mrow;
      float bb = b1[c];
      float wvv = U1var[c];
#pragma unroll
      for (int r = 0; r < 4; ++r) {
        int m = mt*16 + quad*4 + r;
        float v = fmaxf(acc[t][r] + bb + lvar[m]*wvv, 0.f);
        u1bf[m*136 + c] = f2bf(v);
      }
    }
  }
  __syncthreads();
  {
    f32x4 acc[4];
#pragma unroll
    for (int t = 0; t < 4; ++t) acc[t] = (f32x4){0.f,0.f,0.f,0.f};
#pragma unroll
    for (int ks = 0; ks < 4; ++ks) {
      bf16x8 a = *(const bf16x8*)(u1bf + (mt*16 + mrow)*136 + ks*32 + quad*8);
#pragma unroll
      for (int t = 0; t < 4; ++t) {
        bf16x8 b = *(const bf16x8*)(u2t + (size_t)((ntg*4 + t)*16 + mrow)*128 + ks*32 + quad*8);
        acc[t] = __builtin_amdgcn_mfma_f32_16x16x32_bf16(a, b, acc[t], 0, 0, 0);
      }
    }
#pragma unroll
    for (int t = 0; t < 4; ++t) {
      int c = (ntg*4 + t)*16 + mrow;
      float bb = b2[c];
#pragma unroll
      for (int r = 0; r < 4; ++r) {
        int m = mt*16 + quad*4 + r;
        if (base + m < NN)
          hs[m*129 + c] = hs[m*129 + c] + fmaxf(acc[t][r] + bb, 0.f);
      }
    }
  }
  __syncthreads();
#pragma unroll
  for (int r = 0; r < 16; ++r) {
    int lin = r*256 + tid;
    int n = lin >> 7, j = lin & 127;
    int gn = base + n;
    if (gn < NN) h[(size_t)gn*HD + j] = hs[n*129 + j];
  }
  __syncthreads();
  if (tid < HD) {
    double s = 0.0, sq = 0.0;
    for (int e = 0; e < 32; ++e) { double v = (double)hs[e*129 + tid]; s += v; sq += v*v; }
    atomicAdd(&stats[tid], s);
    atomicAdd(&stats[HD + tid], sq);
  }
}

// ---------------- fallback node update MLP (fp32) ----------------

__global__ __launch_bounds__(256) void k_upd(float* __restrict__ h, const float* __restrict__ agg,
                                             const float* __restrict__ pos,
                                             const float* __restrict__ W1, const float* __restrict__ b1,
                                             const float* __restrict__ W2, const float* __restrict__ b2,
                                             double* __restrict__ stats) {
  __shared__ float hs[32 * 129];
  __shared__ float as_[32 * 129];
  int tid = threadIdx.x;
  int base = blockIdx.x * 32;
#pragma unroll
  for (int r = 0; r < 16; ++r) {
    int lin = r*256 + tid;
    int n = lin >> 7, j = lin & 127;
    int gn = base + n;
    hs[n*129 + j]  = (gn < NN) ? h[(size_t)gn*HD + j]   : 0.f;
    as_[n*129 + j] = (gn < NN) ? agg[(size_t)gn*HD + j] : 0.f;
  }
  __syncthreads();
  int nl = tid & 31, jg = tid >> 5;
  int gn = base + nl;
  float var = (gn < NN) ? pos[gn*3+0] : 0.f;
  float acc[16];
#pragma unroll
  for (int q = 0; q < 4; ++q) {
    int j = (jg<<4) + (q<<2);
    float4 bb = *(const float4*)(b1 + j);
    float4 wv = *(const float4*)(W1 + 256*HD + j);
    acc[q*4+0] = fmaf(var, wv.x, bb.x);
    acc[q*4+1] = fmaf(var, wv.y, bb.y);
    acc[q*4+2] = fmaf(var, wv.z, bb.z);
    acc[q*4+3] = fmaf(var, wv.w, bb.w);
  }
  for (int k = 0; k < HD; ++k) {
    float a = hs[nl*129 + k];
    float g = as_[nl*129 + k];
    const float4* w1p = (const float4*)(W1 + (size_t)k*HD + (jg<<4));
    const float4* w2p = (const float4*)(W1 + (size_t)(128 + k)*HD + (jg<<4));
#pragma unroll
    for (int q = 0; q < 4; ++q) {
      float4 wa = w1p[q];
      float4 wb = w2p[q];
      acc[q*4+0] = fmaf(a, wa.x, fmaf(g, wb.x, acc[q*4+0]));
      acc[q*4+1] = fmaf(a, wa.y, fmaf(g, wb.y, acc[q*4+1]));
      acc[q*4+2] = fmaf(a, wa.z, fmaf(g, wb.z, acc[q*4+2]));
      acc[q*4+3] = fmaf(a, wa.w, fmaf(g, wb.w, acc[q*4+3]));
    }
  }
  float up1[16];
#pragma unroll
  for (int i = 0; i < 16; ++i) up1[i] = fmaxf(acc[i], 0.f);
  __syncthreads();
#pragma unroll
  for (int i = 0; i < 16; ++i) as_[nl*129 + (jg<<4) + i] = up1[i];
  __syncthreads();
  float acc2[16];
#pragma unroll
  for (int q = 0; q < 4; ++q) {
    float4 bb = *(const float4*)(b2 + (jg<<4) + (q<<2));
    acc2[q*4+0] = bb.x; acc2[q*4+1] = bb.y; acc2[q*4+2] = bb.z; acc2[q*4+3] = bb.w;
  }
  for (int k = 0; k < HD; ++k) {
    float a = as_[nl*129 + k];
    const float4* wp = (const float4*)(W2 + (size_t)k*HD + (jg<<4));
#pragma unroll
    for (int q = 0; q < 4; ++q) {
      float4 wv = wp[q];
      acc2[q*4+0] = fmaf(a, wv.x, acc2[q*4+0]);
      acc2[q*4+1] = fmaf(a, wv.y, acc2[q*4+1]);
      acc2[q*4+2] = fmaf(a, wv.z, acc2[q*4+2]);
      acc2[q*4+3] = fmaf(a, wv.w, acc2[q*4+3]);
    }
  }
  float x[16];
#pragma unroll
  for (int i = 0; i < 16; ++i)
    x[i] = hs[nl*129 + (jg<<4) + i] + fmaxf(acc2[i], 0.f);
  if (gn < NN) {
#pragma unroll
    for (int q = 0; q < 4; ++q)
      *(float4*)(h + (size_t)gn*HD + (jg<<4) + (q<<2)) = make_float4(x[q*4+0], x[q*4+1], x[q*4+2], x[q*4+3]);
  }
  __syncthreads();
#pragma unroll
  for (int i = 0; i < 16; ++i) hs[nl*129 + (jg<<4) + i] = (gn < NN) ? x[i] : 0.f;
  __syncthreads();
  if (tid < HD) {
    double s = 0.0, sq = 0.0;
    for (int e = 0; e < 32; ++e) { double v = (double)hs[e*129 + tid]; s += v; sq += v*v; }
    atomicAdd(&stats[tid], s);
    atomicAdd(&stats[HD + tid], sq);
  }
}

// ---------------- CNN head (optional fused BN of last layer) ----------------

__global__ __launch_bounds__(256) void k_conv(const float* __restrict__ h,
                                              const float* __restrict__ musig,
                                              const float* __restrict__ g, const float* __restrict__ be,
                                              int applyBN,
                                              const float* __restrict__ c1W, const float* __restrict__ c1b,
                                              const float* __restrict__ c2W, const float* __restrict__ c2b,
                                              const float* __restrict__ c3W, const float* __restrict__ c3b,
                                              float* __restrict__ out) {
  __shared__ float xs[4][128];
  __shared__ float o1[4][152];
  __shared__ float o2[4][72];
  int tid = threadIdx.x;
  int w = tid >> 6, lane = tid & 63;
  int n = blockIdx.x * 4 + w;
#pragma unroll
  for (int half = 0; half < 2; ++half) {
    int j = half * 64 + lane;
    float v = h[(size_t)n*HD + j];
    if (applyBN) v = g[j] * (v - musig[j]) * musig[HD + j] + be[j];
    xs[w][j] = v;
  }
  __syncthreads();
  for (int o = lane; o < 152; o += 64) {
    int oc = o / 38, t = o % 38;
    float s = c1b[oc];
#pragma unroll
    for (int k = 0; k < 16; ++k) s = fmaf(xs[w][t*3 + k], c1W[oc*16 + k], s);
    o1[w][oc*38 + t] = fmaxf(s, 0.f);
  }
  __syncthreads();
  for (int o = lane; o < 72; o += 64) {
    int oc = o / 9, t = o % 9;
    float s = c2b[oc];
    for (int ic = 0; ic < 4; ++ic) {
#pragma unroll
      for (int k = 0; k < 12; ++k) s = fmaf(o1[w][ic*38 + t*3 + k], c2W[oc*48 + ic*12 + k], s);
    }
    o2[w][oc*9 + t] = fmaxf(s, 0.f);
  }
  __syncthreads();
  int ic = lane >> 3, k = lane & 7;
  float t3 = o2[w][ic*9 + k] * c3W[ic*8 + k];
  for (int off = 32; off; off >>= 1) t3 += __shfl_down(t3, off);
  if (lane == 0) out[n] = 0.001f * (t3 + c3b[0]);
}

// ---------------- launcher ----------------

extern "C" void kernel_launch(void* const* d_in, const int* in_sizes, int n_in,
                              void* d_out, int out_size, void* d_ws, size_t ws_size,
                              hipStream_t stream) {
  (void)out_size;
  float* out = (float*)d_out;

  static const int expect[27] = {
    50000, 150000, 1200000,
    512, 128, 128, 128,
    16384, 128, 128, 128,
    199680, 768, 98304, 768, 197376, 768, 98304, 768,
    768, 768,
    64, 4, 384, 8, 64, 1
  };
  if (n_in != 27) { k_code<<<1, 64, 0, stream>>>(out, 5000099.f); return; }
  for (int i = 0; i < 27; ++i)
    if (in_sizes[i] != expect[i]) { k_code<<<1, 64, 0, stream>>>(out, 5000100.f + (float)i); return; }

  const float* u    = (const float*)d_in[0];
  const float* pos  = (const float*)d_in[1];
  const int*   ei   = (const int*)d_in[2];
  const float* eW1  = (const float*)d_in[3];
  const float* eb1  = (const float*)d_in[4];
  const float* eg1  = (const float*)d_in[5];
  const float* ebe1 = (const float*)d_in[6];
  const float* eW2  = (const float*)d_in[7];
  const float* eb2  = (const float*)d_in[8];
  const float* eg2  = (const float*)d_in[9];
  const float* ebe2 = (const float*)d_in[10];
  const float* m1W  = (const float*)d_in[11];
  const float* m1b  = (const float*)d_in[12];
  const float* m2W  = (const float*)d_in[13];
  const float* m2b  = (const float*)d_in[14];
  const float* u1W  = (const float*)d_in[15];
  const float* u1b  = (const float*)d_in[16];
  const float* u2W  = (const float*)d_in[17];
  const float* u2b  = (const float*)d_in[18];
  const float* bng  = (const float*)d_in[19];
  const float* bnb  = (const float*)d_in[20];
  const float* c1W  = (const float*)d_in[21];
  const float* c1b  = (const float*)d_in[22];
  const float* c2W  = (const float*)d_in[23];
  const float* c2b  = (const float*)d_in[24];
  const float* c3W  = (const float*)d_in[25];
  const float* c3b  = (const float*)d_in[26];

  // ---- workspace ----
  char* wsp = (char*)d_ws;
  size_t off = 0;
  auto alloc = [&](size_t bytes) -> void* {
    void* p = wsp + off;
    off = (off + bytes + 255) & ~(size_t)255;
    return p;
  };
  double* stats  = (double*)alloc(256 * 8);
  float*  musig  = (float*)alloc(256 * 4);
  int*    deg    = (int*)alloc((size_t)NN * 4);
  int*    cursor = (int*)alloc((size_t)NN * 4);
  int*    blk    = (int*)alloc(256 * 4);
  float*  invd   = (float*)alloc((size_t)NN * 4);
  float*  h      = (float*)alloc((size_t)NN * HD * 4);
  float*  agg    = (float*)alloc((size_t)NN * HD * 4);
  size_t needed_direct = off;
  unsigned short* A = (unsigned short*)alloc((size_t)NN * HD * 2);
  unsigned short* B = (unsigned short*)alloc((size_t)NN * HD * 2);
  float*  sfeat  = (float*)alloc((size_t)NE * 4 * 4);
  int*    ssrc   = (int*)alloc((size_t)NE * 4);
  int*    sdst   = (int*)alloc((size_t)NE * 4);
  unsigned short* w2t = (unsigned short*)alloc((size_t)NL * HD * HD * 2);
  unsigned short* u2t = (unsigned short*)alloc((size_t)NL * HD * HD * 2);
  unsigned short* u1t = (unsigned short*)alloc((size_t)NL * HD * 256 * 2);
  unsigned short* abt = (unsigned short*)alloc((size_t)NL * 256 * HD * 2);
  size_t needed_fast = off;

  if (ws_size < needed_direct) {
    k_code<<<1, 64, 0, stream>>>(out, (float)(9000000u + (unsigned)(ws_size >> 20)));
    return;
  }
  const bool fast = (ws_size >= needed_fast);

  const int nbN  = (NN + 255) / 256;
  const int nbE  = (NE + 255) / 256;
  const int nt32 = (NN + 31) / 32;
  const int nbBN = NN * HD / 256;

  // ---- degree / inverse degree (+ sort + bf16 weight transposes if fast) ----
  hipMemsetAsync(deg, 0, (size_t)NN * 4, stream);
  k_deg<<<nbE, 256, 0, stream>>>(ei, deg);
  k_scan1<<<nbN, 256, 0, stream>>>(deg, cursor, blk, invd);
  if (fast) {
    k_scan2<<<1, 256, 0, stream>>>(blk, nbN);
    k_scan3<<<nbN, 256, 0, stream>>>(cursor, blk);
    k_scatter<<<nbE, 256, 0, stream>>>(ei, u, pos, cursor, ssrc, sdst, sfeat);
    k_w2t<<<(NL*HD*HD + 255) / 256, 256, 0, stream>>>(m2W, w2t);
    k_w2t<<<(NL*HD*HD + 255) / 256, 256, 0, stream>>>(u2W, u2t);
    k_u1t<<<(NL*HD*256 + 255) / 256, 256, 0, stream>>>(u1W, u1t);
    k_abt<<<(NL*256*HD + 255) / 256, 256, 0, stream>>>(m1W, abt);
  }

  // ---- embedding ----
  hipMemsetAsync(stats, 0, 256 * 8, stream);
  k_emb1<<<nt32, 256, 0, stream>>>(u, pos, eW1, eb1, h, stats);
  k_redA<<<1, 128, 0, stream>>>(stats, musig);
  k_bn<<<nbBN, 256, 0, stream>>>(h, musig, eg1, ebe1, 1);
  hipMemsetAsync(stats, 0, 256 * 8, stream);
  k_emb2<<<nt32, 256, 0, stream>>>(h, eW2, eb2, stats);
  k_redA<<<1, 128, 0, stream>>>(stats, musig);
  k_bn<<<nbBN, 256, 0, stream>>>(h, musig, eg2, ebe2, 0);

  // ---- message-passing layers ----
  for (int i = 0; i < NL; ++i) {
    hipMemsetAsync(agg, 0, (size_t)NN * HD * 4, stream);
    if (fast) {
      k_ab_mfma<<<nt32, 256, 0, stream>>>(h, abt + (size_t)i * 256 * HD,
                                          musig, bng + (size_t)(i > 0 ? i - 1 : 0) * HD,
                                          bnb + (size_t)(i > 0 ? i - 1 : 0) * HD,
                                          (i > 0) ? 1 : 0, A, B);
      k_msg_mfma<<<NE / 32, 256, 0, stream>>>(A, B, ssrc, sdst, sfeat, invd,
                                              m1W + (size_t)i * 260 * HD, m1b + (size_t)i * HD,
                                              w2t + (size_t)i * HD * HD, m2b + (size_t)i * HD, agg);
    } else {
      k_msg_direct<<<NE / 32, 256, 0, stream>>>(h, ei, u, pos, invd,
                                                m1W + (size_t)i * 260 * HD, m1b + (size_t)i * HD,
                                                m2W + (size_t)i * HD * HD, m2b + (size_t)i * HD, agg);
    }
    hipMemsetAsync(stats, 0, 256 * 8, stream);
    if (fast) {
      k_upd_mfma<<<nt32, 256, 0, stream>>>(h, agg, pos,
                                           u1t + (size_t)i * HD * 256,
                                           u1W + (size_t)i * 32896 + 256 * HD,
                                           u1b + (size_t)i * HD,
                                           u2t + (size_t)i * HD * HD,
                                           u2b + (size_t)i * HD, stats);
    } else {
      k_upd<<<nt32, 256, 0, stream>>>(h, agg, pos,
                                      u1W + (size_t)i * 257 * HD, u1b + (size_t)i * HD,
                                      u2W + (size_t)i * HD * HD, u2b + (size_t)i * HD, stats);
    }
    k_redA<<<1, 128, 0, stream>>>(stats, musig);
    if (!fast) {
      k_bn<<<nbBN, 256, 0, stream>>>(h, musig, bng + (size_t)i * HD, bnb + (size_t)i * HD, 0);
    }
  }

  // ---- CNN head (fused BN of layer 5 in fast path) ----
  k_conv<<<NN / 4, 256, 0, stream>>>(h, musig, bng + (size_t)(NL - 1) * HD, bnb + (size_t)(NL - 1) * HD,
                                     fast ? 1 : 0,
                                     c1W, c1b, c2W, c2b, c3W, c3b, out);
}

// Round 19
// 2526.656 us; speedup vs baseline: 8.5431x; 1.0433x over previous
//
#include <hip/hip_runtime.h>

#define NN 50000
#define NE 600000
#define HD 128
#define NL 6

typedef __attribute__((ext_vector_type(8))) short bf16x8;
typedef __attribute__((ext_vector_type(4))) float f32x4;

__device__ inline unsigned short f2bf(float x) {
  unsigned u = __float_as_uint(x);
  u += 0x7FFF + ((u >> 16) & 1);           // RNE on raw bits
  return (unsigned short)(u >> 16);
}
__device__ inline float bf2f(unsigned short s) {
  return __uint_as_float((unsigned)s << 16);
}

__global__ void k_code(float* __restrict__ out, float code) {
  if (threadIdx.x == 0 && blockIdx.x == 0) out[0] = code;
}

// ---------------- weight transposes -> bf16 [layer][n][k] ----------------

__global__ __launch_bounds__(256) void k_w2t(const float* __restrict__ W, unsigned short* __restrict__ T) {
  int idx = blockIdx.x * 256 + threadIdx.x;
  if (idx >= NL * HD * HD) return;
  int l = idx >> 14, r = idx & 16383;
  int n = r >> 7, k = r & 127;
  T[idx] = f2bf(W[(l << 14) + (k << 7) + n]);
}

__global__ __launch_bounds__(256) void k_u1t(const float* __restrict__ W, unsigned short* __restrict__ T) {
  int idx = blockIdx.x * 256 + threadIdx.x;
  if (idx >= NL * 128 * 256) return;
  int l = idx >> 15, r = idx & 32767;
  int n = r >> 8, k = r & 255;
  T[idx] = f2bf(W[l * 32896 + k * 128 + n]);
}

__global__ __launch_bounds__(256) void k_abt(const float* __restrict__ W, unsigned short* __restrict__ T) {
  int idx = blockIdx.x * 256 + threadIdx.x;
  if (idx >= NL * 256 * 128) return;
  int l = idx >> 15, r = idx & 32767;
  int n = r >> 7, k = r & 127;
  int row = (n < 128) ? k : 128 + k;
  int col = n & 127;
  T[idx] = f2bf(W[l * 33280 + row * 128 + col]);
}

// ---------------- degree histogram, scan, counting sort (by dst) ----------------

__global__ __launch_bounds__(256) void k_deg(const int* __restrict__ ei, int* __restrict__ deg) {
  int e = blockIdx.x * 256 + threadIdx.x;
  if (e < NE) {
    int d = ei[NE + e];
    if (d >= 0 && d < NN) atomicAdd(&deg[d], 1);
  }
}

__global__ __launch_bounds__(256) void k_scan1(const int* __restrict__ deg, int* __restrict__ cursor,
                                               int* __restrict__ blk, float* __restrict__ invd) {
  __shared__ int sd[256];
  int t = threadIdx.x;
  int i = blockIdx.x * 256 + t;
  int v = (i < NN) ? deg[i] : 0;
  sd[t] = v;
  __syncthreads();
  for (int off = 1; off < 256; off <<= 1) {
    int x = (t >= off) ? sd[t - off] : 0;
    __syncthreads();
    if (t >= off) sd[t] += x;
    __syncthreads();
  }
  int incl = sd[t];
  if (i < NN) {
    cursor[i] = incl - v;
    invd[i] = 1.0f / fmaxf((float)v, 1.0f);
  }
  if (t == 255) blk[blockIdx.x] = incl;
}

__global__ __launch_bounds__(256) void k_scan2(int* __restrict__ blk, int nb) {
  __shared__ int sd[256];
  int t = threadIdx.x;
  int v = (t < nb) ? blk[t] : 0;
  sd[t] = v;
  __syncthreads();
  for (int off = 1; off < 256; off <<= 1) {
    int x = (t >= off) ? sd[t - off] : 0;
    __syncthreads();
    if (t >= off) sd[t] += x;
    __syncthreads();
  }
  if (t < nb) blk[t] = sd[t] - v;
}

__global__ __launch_bounds__(256) void k_scan3(int* __restrict__ cursor, const int* __restrict__ blk) {
  int i = blockIdx.x * 256 + threadIdx.x;
  if (i < NN) cursor[i] += blk[blockIdx.x];
}

__global__ __launch_bounds__(256) void k_scatter(const int* __restrict__ ei, const float* __restrict__ u,
                                                 const float* __restrict__ pos, int* __restrict__ cursor,
                                                 int* __restrict__ ssrc, int* __restrict__ sdst,
                                                 float* __restrict__ sfeat) {
  int e = blockIdx.x * 256 + threadIdx.x;
  if (e >= NE) return;
  int s = ei[e], d = ei[NE + e];
  s = s < 0 ? 0 : (s >= NN ? NN - 1 : s);
  d = d < 0 ? 0 : (d >= NN ? NN - 1 : d);
  int p = atomicAdd(&cursor[d], 1);
  ssrc[p] = s;
  sdst[p] = d;
  float du  = u[d] - u[s];
  float dpx = pos[d*3+1] - pos[s*3+1];
  float dpy = pos[d*3+2] - pos[s*3+2];
  float vi  = pos[d*3+0];
  ((float4*)sfeat)[p] = make_float4(du, dpx, dpy, vi);
}

// ---------------- embedding ----------------

__global__ __launch_bounds__(256) void k_emb1(const float* __restrict__ u, const float* __restrict__ pos,
                                              const float* __restrict__ W, const float* __restrict__ b,
                                              float* __restrict__ h, double* __restrict__ stats) {
  __shared__ float xs[32 * 129];
  int tid = threadIdx.x;
  int nl = tid & 31, jg = tid >> 5;
  int gn = blockIdx.x * 32 + nl;
  float f0 = 0.f, f1 = 0.f, f2 = 0.f, f3 = 0.f;
  if (gn < NN) { f0 = u[gn]; f1 = pos[gn*3+1]; f2 = pos[gn*3+2]; f3 = pos[gn*3+0]; }
  float x[16];
#pragma unroll
  for (int q = 0; q < 4; ++q) {
    int j = (jg << 4) + (q << 2);
    float4 w0 = *(const float4*)(W + 0*HD + j);
    float4 w1 = *(const float4*)(W + 1*HD + j);
    float4 w2 = *(const float4*)(W + 2*HD + j);
    float4 w3 = *(const float4*)(W + 3*HD + j);
    float4 bb = *(const float4*)(b + j);
    x[q*4+0] = f0*w0.x + f1*w1.x + f2*w2.x + f3*w3.x + bb.x;
    x[q*4+1] = f0*w0.y + f1*w1.y + f2*w2.y + f3*w3.y + bb.y;
    x[q*4+2] = f0*w0.z + f1*w1.z + f2*w2.z + f3*w3.z + bb.z;
    x[q*4+3] = f0*w0.w + f1*w1.w + f2*w2.w + f3*w3.w + bb.w;
  }
  if (gn < NN) {
#pragma unroll
    for (int q = 0; q < 4; ++q)
      *(float4*)(h + (size_t)gn*HD + (jg<<4) + (q<<2)) = make_float4(x[q*4+0], x[q*4+1], x[q*4+2], x[q*4+3]);
  }
#pragma unroll
  for (int i = 0; i < 16; ++i) xs[nl*129 + (jg<<4) + i] = (gn < NN) ? x[i] : 0.f;
  __syncthreads();
  if (tid < HD) {
    double s = 0.0, sq = 0.0;
    for (int e = 0; e < 32; ++e) { double v = (double)xs[e*129 + tid]; s += v; sq += v*v; }
    atomicAdd(&stats[tid], s);
    atomicAdd(&stats[HD + tid], sq);
  }
}

__global__ __launch_bounds__(256) void k_emb2(float* __restrict__ h, const float* __restrict__ W,
                                              const float* __restrict__ b, double* __restrict__ stats) {
  __shared__ float hs[32 * 129];
  int tid = threadIdx.x;
  int base = blockIdx.x * 32;
#pragma unroll
  for (int r = 0; r < 16; ++r) {
    int lin = r*256 + tid;
    int n = lin >> 7, j = lin & 127;
    int gn = base + n;
    hs[n*129 + j] = (gn < NN) ? h[(size_t)gn*HD + j] : 0.f;
  }
  __syncthreads();
  int nl = tid & 31, jg = tid >> 5;
  int gn = base + nl;
  float acc[16];
#pragma unroll
  for (int q = 0; q < 4; ++q) {
    float4 bb = *(const float4*)(b + (jg<<4) + (q<<2));
    acc[q*4+0] = bb.x; acc[q*4+1] = bb.y; acc[q*4+2] = bb.z; acc[q*4+3] = bb.w;
  }
  for (int k = 0; k < HD; ++k) {
    float a = hs[nl*129 + k];
    const float4* wp = (const float4*)(W + (size_t)k*HD + (jg<<4));
#pragma unroll
    for (int q = 0; q < 4; ++q) {
      float4 wv = wp[q];
      acc[q*4+0] = fmaf(a, wv.x, acc[q*4+0]);
      acc[q*4+1] = fmaf(a, wv.y, acc[q*4+1]);
      acc[q*4+2] = fmaf(a, wv.z, acc[q*4+2]);
      acc[q*4+3] = fmaf(a, wv.w, acc[q*4+3]);
    }
  }
  if (gn < NN) {
#pragma unroll
    for (int q = 0; q < 4; ++q)
      *(float4*)(h + (size_t)gn*HD + (jg<<4) + (q<<2)) = make_float4(acc[q*4+0], acc[q*4+1], acc[q*4+2], acc[q*4+3]);
  }
  __syncthreads();
#pragma unroll
  for (int i = 0; i < 16; ++i) hs[nl*129 + (jg<<4) + i] = (gn < NN) ? acc[i] : 0.f;
  __syncthreads();
  if (tid < HD) {
    double s = 0.0, sq = 0.0;
    for (int e = 0; e < 32; ++e) { double v = (double)hs[e*129 + tid]; s += v; sq += v*v; }
    atomicAdd(&stats[tid], s);
    atomicAdd(&stats[HD + tid], sq);
  }
}

__global__ void k_redA(const double* __restrict__ stats, float* __restrict__ musig) {
  int c = threadIdx.x;   // 128
  double mu  = stats[c] / (double)NN;
  double var = stats[128 + c] / (double)NN - mu * mu;
  musig[c]      = (float)mu;
  musig[HD + c] = (float)(1.0 / sqrt(var + 1e-5));
}

__global__ __launch_bounds__(256) void k_bn(float* __restrict__ h, const float* __restrict__ musig,
                                            const float* __restrict__ g, const float* __restrict__ be,
                                            int relu) {
  int idx = blockIdx.x * 256 + threadIdx.x;
  if (idx >= NN * HD) return;
  int j = idx & 127;
  float x = h[idx];
  x = g[j] * (x - musig[j]) * musig[HD + j] + be[j];
  if (relu) x = fmaxf(x, 0.f);
  h[idx] = x;
}

// ---------------- k_ab via MFMA, fused BN of previous layer, bf16 A/B output ----------------

__global__ __launch_bounds__(256) void k_ab_mfma(float* __restrict__ h,
                                                 const unsigned short* __restrict__ abt,
                                                 const float* __restrict__ musig,
                                                 const float* __restrict__ g, const float* __restrict__ be,
                                                 int applyBN,
                                                 unsigned short* __restrict__ A, unsigned short* __restrict__ B) {
  __shared__ unsigned short hbf[32 * 136];
  int tid = threadIdx.x;
  int base = blockIdx.x * 32;
#pragma unroll
  for (int r = 0; r < 16; ++r) {
    int lin = r*256 + tid;
    int n = lin >> 7, j = lin & 127;
    int gn = base + n;
    float hv = (gn < NN) ? h[(size_t)gn*HD + j] : 0.f;
    if (applyBN) {
      hv = g[j] * (hv - musig[j]) * musig[HD + j] + be[j];
      if (gn < NN) h[(size_t)gn*HD + j] = hv;
    }
    hbf[n*136 + j] = f2bf((gn < NN) ? hv : 0.f);
  }
  __syncthreads();
  int wv = tid >> 6, lane = tid & 63;
  int quad = lane >> 4, mrow = lane & 15;
  int mt = wv & 1, ntg = wv >> 1;
  f32x4 acc[8];
#pragma unroll
  for (int t = 0; t < 8; ++t) acc[t] = (f32x4){0.f,0.f,0.f,0.f};
#pragma unroll
  for (int ks = 0; ks < 4; ++ks) {
    bf16x8 a = *(const bf16x8*)(hbf + (mt*16 + mrow)*136 + ks*32 + quad*8);
#pragma unroll
    for (int t = 0; t < 8; ++t) {
      bf16x8 b = *(const bf16x8*)(abt + (size_t)((ntg*8 + t)*16 + mrow)*128 + ks*32 + quad*8);
      acc[t] = __builtin_amdgcn_mfma_f32_16x16x32_bf16(a, b, acc[t], 0, 0, 0);
    }
  }
#pragma unroll
  for (int t = 0; t < 8; ++t) {
    int c = (ntg*8 + t)*16 + mrow;
#pragma unroll
    for (int r = 0; r < 4; ++r) {
      int gn = base + mt*16 + quad*4 + r;
      if (gn < NN) {
        if (c < 128) A[(size_t)gn*HD + c]       = f2bf(acc[t][r]);
        else         B[(size_t)gn*HD + c - 128] = f2bf(acc[t][r]);
      }
    }
  }
}

// ---------------- edge message MLP: bf16 gather + fp32 m1 + bf16-MFMA m2 (LDS-slim) + flush ----------------
// LDS: m1bf (8.7 KB) is reused to hold bf16 m2 after the MFMA phase -> ~9.7 KB total.

__global__ __launch_bounds__(256) void k_msg_mfma(const unsigned short* __restrict__ A,
                                                  const unsigned short* __restrict__ B,
                                                  const int* __restrict__ ssrc, const int* __restrict__ sdst,
                                                  const float* __restrict__ sfeat, const float* __restrict__ invd,
                                                  const float* __restrict__ W1, const float* __restrict__ b1,
                                                  const unsigned short* __restrict__ w2t, const float* __restrict__ b2,
                                                  float* __restrict__ agg) {
  __shared__ unsigned short m1bf[32 * 136];   // m1 (bf16) then m2 (bf16)
  __shared__ int lsrc[32];
  __shared__ int ldst[32];
  __shared__ float lfeat[32][4];
  int tid = threadIdx.x;
  int base = blockIdx.x * 32;
  if (tid < 32) { lsrc[tid] = ssrc[base + tid]; ldst[tid] = sdst[base + tid]; }
  if (tid < 128) ((float*)lfeat)[tid] = sfeat[(size_t)base*4 + tid];
  __syncthreads();
  {
    int el = tid & 31, jg = tid >> 5;
    int s = lsrc[el], d = ldst[el];
    float f0 = lfeat[el][0], f1 = lfeat[el][1], f2 = lfeat[el][2], f3 = lfeat[el][3];
    const unsigned short* Ar = A + (size_t)d*HD + (jg<<4);
    const unsigned short* Br = B + (size_t)s*HD + (jg<<4);
    bf16x8 a0 = *(const bf16x8*)(Ar);
    bf16x8 a1 = *(const bf16x8*)(Ar + 8);
    bf16x8 b0 = *(const bf16x8*)(Br);
    bf16x8 b1v = *(const bf16x8*)(Br + 8);
    const float* We = W1 + 256*HD + (jg<<4);
    float m1[16];
#pragma unroll
    for (int q = 0; q < 4; ++q) {
      float4 w0 = *(const float4*)(We + 0*HD + (q<<2));
      float4 w1 = *(const float4*)(We + 1*HD + (q<<2));
      float4 w2 = *(const float4*)(We + 2*HD + (q<<2));
      float4 w3 = *(const float4*)(We + 3*HD + (q<<2));
      float4 bb = *(const float4*)(b1 + (jg<<4) + (q<<2));
#pragma unroll
      for (int z = 0; z < 4; ++z) {
        int i = q*4 + z;
        unsigned short av = (i < 8) ? (unsigned short)a0[i] : (unsigned short)a1[i-8];
        unsigned short bv = (i < 8) ? (unsigned short)b0[i] : (unsigned short)b1v[i-8];
        float we  = (z==0?w0.x:(z==1?w0.y:(z==2?w0.z:w0.w)));
        float w1e = (z==0?w1.x:(z==1?w1.y:(z==2?w1.z:w1.w)));
        float w2e = (z==0?w2.x:(z==1?w2.y:(z==2?w2.z:w2.w)));
        float w3e = (z==0?w3.x:(z==1?w3.y:(z==2?w3.z:w3.w)));
        float bbe = (z==0?bb.x:(z==1?bb.y:(z==2?bb.z:bb.w)));
        m1[i] = fmaxf(bf2f(av) + bf2f(bv) + f0*we + f1*w1e + f2*w2e + f3*w3e + bbe, 0.f);
      }
    }
    unsigned* p = (unsigned*)(m1bf + el*136 + (jg<<4));
#pragma unroll
    for (int i = 0; i < 8; ++i)
      p[i] = (unsigned)f2bf(m1[2*i]) | ((unsigned)f2bf(m1[2*i+1]) << 16);
  }
  __syncthreads();
  {
    int wv = tid >> 6, lane = tid & 63;
    int quad = lane >> 4, mrow = lane & 15;
    int mt = wv & 1, ntg = wv >> 1;
    f32x4 acc0 = {0.f,0.f,0.f,0.f}, acc1 = acc0, acc2 = acc0, acc3 = acc0;
#pragma unroll
    for (int ks = 0; ks < 4; ++ks) {
      bf16x8 a = *(const bf16x8*)(m1bf + (mt*16 + mrow)*136 + ks*32 + quad*8);
      bf16x8 bf0 = *(const bf16x8*)(w2t + ((ntg*4+0)*16 + mrow)*128 + ks*32 + quad*8);
      bf16x8 bf1 = *(const bf16x8*)(w2t + ((ntg*4+1)*16 + mrow)*128 + ks*32 + quad*8);
      bf16x8 bf2 = *(const bf16x8*)(w2t + ((ntg*4+2)*16 + mrow)*128 + ks*32 + quad*8);
      bf16x8 bf3 = *(const bf16x8*)(w2t + ((ntg*4+3)*16 + mrow)*128 + ks*32 + quad*8);
      acc0 = __builtin_amdgcn_mfma_f32_16x16x32_bf16(a, bf0, acc0, 0, 0, 0);
      acc1 = __builtin_amdgcn_mfma_f32_16x16x32_bf16(a, bf1, acc1, 0, 0, 0);
      acc2 = __builtin_amdgcn_mfma_f32_16x16x32_bf16(a, bf2, acc2, 0, 0, 0);
      acc3 = __builtin_amdgcn_mfma_f32_16x16x32_bf16(a, bf3, acc3, 0, 0, 0);
    }
    __syncthreads();   // all m1bf reads done -> safe to overwrite with m2
    f32x4 av[4] = {acc0, acc1, acc2, acc3};
#pragma unroll
    for (int t = 0; t < 4; ++t) {
      int c = (ntg*4 + t)*16 + mrow;
      float bb = b2[c];
#pragma unroll
      for (int r = 0; r < 4; ++r) {
        int erow = mt*16 + quad*4 + r;
        m1bf[erow*136 + c] = f2bf(fmaxf(av[t][r] + bb, 0.f));
      }
    }
  }
  __syncthreads();
  if (tid < HD) {
    int j = tid;
    float a2 = 0.f;
    int cur = ldst[0];
    for (int e = 0; e < 32; ++e) {
      int de = ldst[e];
      if (de != cur) {
        atomicAdd(&agg[(size_t)cur*HD + j], a2 * invd[cur]);
        a2 = 0.f;
        cur = de;
      }
      a2 += bf2f(m1bf[e*136 + j]);
    }
    atomicAdd(&agg[(size_t)cur*HD + j], a2 * invd[cur]);
  }
}

// ---------------- fallback: direct edge MLP + naive atomics (unsorted) ----------------

__global__ __launch_bounds__(256) void k_msg_direct(const float* __restrict__ h,
                                                    const int* __restrict__ ei, const float* __restrict__ u,
                                                    const float* __restrict__ pos, const float* __restrict__ invd,
                                                    const float* __restrict__ W1, const float* __restrict__ b1,
                                                    const float* __restrict__ W2, const float* __restrict__ b2,
                                                    float* __restrict__ agg) {
  __shared__ float hd[32 * 129];
  __shared__ float hsr[32 * 129];
  __shared__ float m1s[32 * 129];
  __shared__ int lsrc[32];
  __shared__ int ldst[32];
  __shared__ float lf[32][4];
  int tid = threadIdx.x;
  int base = blockIdx.x * 32;
  if (tid < 32) {
    int e = base + tid;
    int s = ei[e], d = ei[NE + e];
    s = s < 0 ? 0 : (s >= NN ? NN - 1 : s);
    d = d < 0 ? 0 : (d >= NN ? NN - 1 : d);
    lsrc[tid] = s; ldst[tid] = d;
    lf[tid][0] = u[d] - u[s];
    lf[tid][1] = pos[d*3+1] - pos[s*3+1];
    lf[tid][2] = pos[d*3+2] - pos[s*3+2];
    lf[tid][3] = pos[d*3+0];
  }
  __syncthreads();
#pragma unroll
  for (int r = 0; r < 16; ++r) {
    int lin = r*256 + tid;
    int n = lin >> 7, j = lin & 127;
    hd[n*129 + j]  = h[(size_t)ldst[n]*HD + j];
    hsr[n*129 + j] = h[(size_t)lsrc[n]*HD + j];
  }
  __syncthreads();
  int el = tid & 31, jg = tid >> 5;
  float f0 = lf[el][0], f1 = lf[el][1], f2 = lf[el][2], f3 = lf[el][3];
  const float* We = W1 + 256*HD + (jg<<4);
  float acc[16];
#pragma unroll
  for (int q = 0; q < 4; ++q) {
    float4 w0 = *(const float4*)(We + 0*HD + (q<<2));
    float4 w1 = *(const float4*)(We + 1*HD + (q<<2));
    float4 w2 = *(const float4*)(We + 2*HD + (q<<2));
    float4 w3 = *(const float4*)(We + 3*HD + (q<<2));
    float4 bb = *(const float4*)(b1 + (jg<<4) + (q<<2));
    acc[q*4+0] = f0*w0.x + f1*w1.x + f2*w2.x + f3*w3.x + bb.x;
    acc[q*4+1] = f0*w0.y + f1*w1.y + f2*w2.y + f3*w3.y + bb.y;
    acc[q*4+2] = f0*w0.z + f1*w1.z + f2*w2.z + f3*w3.z + bb.z;
    acc[q*4+3] = f0*w0.w + f1*w1.w + f2*w2.w + f3*w3.w + bb.w;
  }
  for (int k = 0; k < HD; ++k) {
    float a  = hd[el*129 + k];
    float bs = hsr[el*129 + k];
    const float4* wa = (const float4*)(W1 + (size_t)k*HD + (jg<<4));
    const float4* wb = (const float4*)(W1 + (size_t)(128 + k)*HD + (jg<<4));
#pragma unroll
    for (int q = 0; q < 4; ++q) {
      float4 w1v = wa[q];
      float4 w2v = wb[q];
      acc[q*4+0] = fmaf(a, w1v.x, fmaf(bs, w2v.x, acc[q*4+0]));
      acc[q*4+1] = fmaf(a, w1v.y, fmaf(bs, w2v.y, acc[q*4+1]));
      acc[q*4+2] = fmaf(a, w1v.z, fmaf(bs, w2v.z, acc[q*4+2]));
      acc[q*4+3] = fmaf(a, w1v.w, fmaf(bs, w2v.w, acc[q*4+3]));
    }
  }
#pragma unroll
  for (int i = 0; i < 16; ++i) m1s[el*129 + (jg<<4) + i] = fmaxf(acc[i], 0.f);
  __syncthreads();
  float acc2[16];
#pragma unroll
  for (int q = 0; q < 4; ++q) {
    float4 bb = *(const float4*)(b2 + (jg<<4) + (q<<2));
    acc2[q*4+0] = bb.x; acc2[q*4+1] = bb.y; acc2[q*4+2] = bb.z; acc2[q*4+3] = bb.w;
  }
  for (int k = 0; k < HD; ++k) {
    float a = m1s[el*129 + k];
    const float4* wp = (const float4*)(W2 + (size_t)k*HD + (jg<<4));
#pragma unroll
    for (int q = 0; q < 4; ++q) {
      float4 wv = wp[q];
      acc2[q*4+0] = fmaf(a, wv.x, acc2[q*4+0]);
      acc2[q*4+1] = fmaf(a, wv.y, acc2[q*4+1]);
      acc2[q*4+2] = fmaf(a, wv.z, acc2[q*4+2]);
      acc2[q*4+3] = fmaf(a, wv.w, acc2[q*4+3]);
    }
  }
#pragma unroll
  for (int i = 0; i < 16; ++i) hd[el*129 + (jg<<4) + i] = fmaxf(acc2[i], 0.f);
  __syncthreads();
  if (tid < HD) {
    int j = tid;
    for (int e = 0; e < 32; ++e) {
      int de = ldst[e];
      atomicAdd(&agg[(size_t)de*HD + j], hd[e*129 + j] * invd[de]);
    }
  }
}

// ---------------- node update MLP via MFMA ----------------

__global__ __launch_bounds__(256) void k_upd_mfma(float* __restrict__ h, const float* __restrict__ agg,
                                                  const float* __restrict__ pos,
                                                  const unsigned short* __restrict__ u1t,
                                                  const float* __restrict__ U1var, const float* __restrict__ b1,
                                                  const unsigned short* __restrict__ u2t, const float* __restrict__ b2,
                                                  double* __restrict__ stats) {
  __shared__ float hs[32 * 129];
  __shared__ unsigned short abf[32 * 264];
  __shared__ unsigned short u1bf[32 * 136];
  __shared__ float lvar[32];
  int tid = threadIdx.x;
  int base = blockIdx.x * 32;
#pragma unroll
  for (int r = 0; r < 16; ++r) {
    int lin = r*256 + tid;
    int n = lin >> 7, j = lin & 127;
    int gn = base + n;
    float hv = (gn < NN) ? h[(size_t)gn*HD + j]   : 0.f;
    float av = (gn < NN) ? agg[(size_t)gn*HD + j] : 0.f;
    hs[n*129 + j] = hv;
    abf[n*264 + j]       = f2bf(hv);
    abf[n*264 + 128 + j] = f2bf(av);
  }
  if (tid < 32) lvar[tid] = (base + tid < NN) ? pos[(base + tid)*3 + 0] : 0.f;
  __syncthreads();
  int wv = tid >> 6, lane = tid & 63;
  int quad = lane >> 4, mrow = lane & 15;
  int mt = wv & 1, ntg = wv >> 1;
  {
    f32x4 acc[4];
#pragma unroll
    for (int t = 0; t < 4; ++t) acc[t] = (f32x4){0.f,0.f,0.f,0.f};
#pragma unroll
    for (int ks = 0; ks < 8; ++ks) {
      bf16x8 a = *(const bf16x8*)(abf + (mt*16 + mrow)*264 + ks*32 + quad*8);
#pragma unroll
      for (int t = 0; t < 4; ++t) {
        bf16x8 b = *(const bf16x8*)(u1t + (size_t)((ntg*4 + t)*16 + mrow)*256 + ks*32 + quad*8);
        acc[t] = __builtin_amdgcn_mfma_f32_16x16x32_bf16(a, b, acc[t], 0, 0, 0);
      }
    }
#pragma unroll
    for (int t = 0; t < 4; ++t) {
      int c = (ntg*4 + t)*16 + mrow;
      float bb = b1[c];
      float wvv = U1var[c];
#pragma unroll
      for (int r = 0; r < 4; ++r) {
        int m = mt*16 + quad*4 + r;
        float v = fmaxf(acc[t][r] + bb + lvar[m]*wvv, 0.f);
        u1bf[m*136 + c] = f2bf(v);
      }
    }
  }
  __syncthreads();
  {
    f32x4 acc[4];
#pragma unroll
    for (int t = 0; t < 4; ++t) acc[t] = (f32x4){0.f,0.f,0.f,0.f};
#pragma unroll
    for (int ks = 0; ks < 4; ++ks) {
      bf16x8 a = *(const bf16x8*)(u1bf + (mt*16 + mrow)*136 + ks*32 + quad*8);
#pragma unroll
      for (int t = 0; t < 4; ++t) {
        bf16x8 b = *(const bf16x8*)(u2t + (size_t)((ntg*4 + t)*16 + mrow)*128 + ks*32 + quad*8);
        acc[t] = __builtin_amdgcn_mfma_f32_16x16x32_bf16(a, b, acc[t], 0, 0, 0);
      }
    }
#pragma unroll
    for (int t = 0; t < 4; ++t) {
      int c = (ntg*4 + t)*16 + mrow;
      float bb = b2[c];
#pragma unroll
      for (int r = 0; r < 4; ++r) {
        int m = mt*16 + quad*4 + r;
        if (base + m < NN)
          hs[m*129 + c] = hs[m*129 + c] + fmaxf(acc[t][r] + bb, 0.f);
      }
    }
  }
  __syncthreads();
#pragma unroll
  for (int r = 0; r < 16; ++r) {
    int lin = r*256 + tid;
    int n = lin >> 7, j = lin & 127;
    int gn = base + n;
    if (gn < NN) h[(size_t)gn*HD + j] = hs[n*129 + j];
  }
  __syncthreads();
  if (tid < HD) {
    double s = 0.0, sq = 0.0;
    for (int e = 0; e < 32; ++e) { double v = (double)hs[e*129 + tid]; s += v; sq += v*v; }
    atomicAdd(&stats[tid], s);
    atomicAdd(&stats[HD + tid], sq);
  }
}

// ---------------- fallback node update MLP (fp32) ----------------

__global__ __launch_bounds__(256) void k_upd(float* __restrict__ h, const float* __restrict__ agg,
                                             const float* __restrict__ pos,
                                             const float* __restrict__ W1, const float* __restrict__ b1,
                                             const float* __restrict__ W2, const float* __restrict__ b2,
                                             double* __restrict__ stats) {
  __shared__ float hs[32 * 129];
  __shared__ float as_[32 * 129];
  int tid = threadIdx.x;
  int base = blockIdx.x * 32;
#pragma unroll
  for (int r = 0; r < 16; ++r) {
    int lin = r*256 + tid;
    int n = lin >> 7, j = lin & 127;
    int gn = base + n;
    hs[n*129 + j]  = (gn < NN) ? h[(size_t)gn*HD + j]   : 0.f;
    as_[n*129 + j] = (gn < NN) ? agg[(size_t)gn*HD + j] : 0.f;
  }
  __syncthreads();
  int nl = tid & 31, jg = tid >> 5;
  int gn = base + nl;
  float var = (gn < NN) ? pos[gn*3+0] : 0.f;
  float acc[16];
#pragma unroll
  for (int q = 0; q < 4; ++q) {
    int j = (jg<<4) + (q<<2);
    float4 bb = *(const float4*)(b1 + j);
    float4 wv = *(const float4*)(W1 + 256*HD + j);
    acc[q*4+0] = fmaf(var, wv.x, bb.x);
    acc[q*4+1] = fmaf(var, wv.y, bb.y);
    acc[q*4+2] = fmaf(var, wv.z, bb.z);
    acc[q*4+3] = fmaf(var, wv.w, bb.w);
  }
  for (int k = 0; k < HD; ++k) {
    float a = hs[nl*129 + k];
    float g = as_[nl*129 + k];
    const float4* w1p = (const float4*)(W1 + (size_t)k*HD + (jg<<4));
    const float4* w2p = (const float4*)(W1 + (size_t)(128 + k)*HD + (jg<<4));
#pragma unroll
    for (int q = 0; q < 4; ++q) {
      float4 wa = w1p[q];
      float4 wb = w2p[q];
      acc[q*4+0] = fmaf(a, wa.x, fmaf(g, wb.x, acc[q*4+0]));
      acc[q*4+1] = fmaf(a, wa.y, fmaf(g, wb.y, acc[q*4+1]));
      acc[q*4+2] = fmaf(a, wa.z, fmaf(g, wb.z, acc[q*4+2]));
      acc[q*4+3] = fmaf(a, wa.w, fmaf(g, wb.w, acc[q*4+3]));
    }
  }
  float up1[16];
#pragma unroll
  for (int i = 0; i < 16; ++i) up1[i] = fmaxf(acc[i], 0.f);
  __syncthreads();
#pragma unroll
  for (int i = 0; i < 16; ++i) as_[nl*129 + (jg<<4) + i] = up1[i];
  __syncthreads();
  float acc2[16];
#pragma unroll
  for (int q = 0; q < 4; ++q) {
    float4 bb = *(const float4*)(b2 + (jg<<4) + (q<<2));
    acc2[q*4+0] = bb.x; acc2[q*4+1] = bb.y; acc2[q*4+2] = bb.z; acc2[q*4+3] = bb.w;
  }
  for (int k = 0; k < HD; ++k) {
    float a = as_[nl*129 + k];
    const float4* wp = (const float4*)(W2 + (size_t)k*HD + (jg<<4));
#pragma unroll
    for (int q = 0; q < 4; ++q) {
      float4 wv = wp[q];
      acc2[q*4+0] = fmaf(a, wv.x, acc2[q*4+0]);
      acc2[q*4+1] = fmaf(a, wv.y, acc2[q*4+1]);
      acc2[q*4+2] = fmaf(a, wv.z, acc2[q*4+2]);
      acc2[q*4+3] = fmaf(a, wv.w, acc2[q*4+3]);
    }
  }
  float x[16];
#pragma unroll
  for (int i = 0; i < 16; ++i)
    x[i] = hs[nl*129 + (jg<<4) + i] + fmaxf(acc2[i], 0.f);
  if (gn < NN) {
#pragma unroll
    for (int q = 0; q < 4; ++q)
      *(float4*)(h + (size_t)gn*HD + (jg<<4) + (q<<2)) = make_float4(x[q*4+0], x[q*4+1], x[q*4+2], x[q*4+3]);
  }
  __syncthreads();
#pragma unroll
  for (int i = 0; i < 16; ++i) hs[nl*129 + (jg<<4) + i] = (gn < NN) ? x[i] : 0.f;
  __syncthreads();
  if (tid < HD) {
    double s = 0.0, sq = 0.0;
    for (int e = 0; e < 32; ++e) { double v = (double)hs[e*129 + tid]; s += v; sq += v*v; }
    atomicAdd(&stats[tid], s);
    atomicAdd(&stats[HD + tid], sq);
  }
}

// ---------------- CNN head (optional fused BN of last layer) ----------------

__global__ __launch_bounds__(256) void k_conv(const float* __restrict__ h,
                                              const float* __restrict__ musig,
                                              const float* __restrict__ g, const float* __restrict__ be,
                                              int applyBN,
                                              const float* __restrict__ c1W, const float* __restrict__ c1b,
                                              const float* __restrict__ c2W, const float* __restrict__ c2b,
                                              const float* __restrict__ c3W, const float* __restrict__ c3b,
                                              float* __restrict__ out) {
  __shared__ float xs[4][128];
  __shared__ float o1[4][152];
  __shared__ float o2[4][72];
  int tid = threadIdx.x;
  int w = tid >> 6, lane = tid & 63;
  int n = blockIdx.x * 4 + w;
#pragma unroll
  for (int half = 0; half < 2; ++half) {
    int j = half * 64 + lane;
    float v = h[(size_t)n*HD + j];
    if (applyBN) v = g[j] * (v - musig[j]) * musig[HD + j] + be[j];
    xs[w][j] = v;
  }
  __syncthreads();
  for (int o = lane; o < 152; o += 64) {
    int oc = o / 38, t = o % 38;
    float s = c1b[oc];
#pragma unroll
    for (int k = 0; k < 16; ++k) s = fmaf(xs[w][t*3 + k], c1W[oc*16 + k], s);
    o1[w][oc*38 + t] = fmaxf(s, 0.f);
  }
  __syncthreads();
  for (int o = lane; o < 72; o += 64) {
    int oc = o / 9, t = o % 9;
    float s = c2b[oc];
    for (int ic = 0; ic < 4; ++ic) {
#pragma unroll
      for (int k = 0; k < 12; ++k) s = fmaf(o1[w][ic*38 + t*3 + k], c2W[oc*48 + ic*12 + k], s);
    }
    o2[w][oc*9 + t] = fmaxf(s, 0.f);
  }
  __syncthreads();
  int ic = lane >> 3, k = lane & 7;
  float t3 = o2[w][ic*9 + k] * c3W[ic*8 + k];
  for (int off = 32; off; off >>= 1) t3 += __shfl_down(t3, off);
  if (lane == 0) out[n] = 0.001f * (t3 + c3b[0]);
}

// ---------------- launcher ----------------

extern "C" void kernel_launch(void* const* d_in, const int* in_sizes, int n_in,
                              void* d_out, int out_size, void* d_ws, size_t ws_size,
                              hipStream_t stream) {
  (void)out_size;
  float* out = (float*)d_out;

  static const int expect[27] = {
    50000, 150000, 1200000,
    512, 128, 128, 128,
    16384, 128, 128, 128,
    199680, 768, 98304, 768, 197376, 768, 98304, 768,
    768, 768,
    64, 4, 384, 8, 64, 1
  };
  if (n_in != 27) { k_code<<<1, 64, 0, stream>>>(out, 5000099.f); return; }
  for (int i = 0; i < 27; ++i)
    if (in_sizes[i] != expect[i]) { k_code<<<1, 64, 0, stream>>>(out, 5000100.f + (float)i); return; }

  const float* u    = (const float*)d_in[0];
  const float* pos  = (const float*)d_in[1];
  const int*   ei   = (const int*)d_in[2];
  const float* eW1  = (const float*)d_in[3];
  const float* eb1  = (const float*)d_in[4];
  const float* eg1  = (const float*)d_in[5];
  const float* ebe1 = (const float*)d_in[6];
  const float* eW2  = (const float*)d_in[7];
  const float* eb2  = (const float*)d_in[8];
  const float* eg2  = (const float*)d_in[9];
  const float* ebe2 = (const float*)d_in[10];
  const float* m1W  = (const float*)d_in[11];
  const float* m1b  = (const float*)d_in[12];
  const float* m2W  = (const float*)d_in[13];
  const float* m2b  = (const float*)d_in[14];
  const float* u1W  = (const float*)d_in[15];
  const float* u1b  = (const float*)d_in[16];
  const float* u2W  = (const float*)d_in[17];
  const float* u2b  = (const float*)d_in[18];
  const float* bng  = (const float*)d_in[19];
  const float* bnb  = (const float*)d_in[20];
  const float* c1W  = (const float*)d_in[21];
  const float* c1b  = (const float*)d_in[22];
  const float* c2W  = (const float*)d_in[23];
  const float* c2b  = (const float*)d_in[24];
  const float* c3W  = (const float*)d_in[25];
  const float* c3b  = (const float*)d_in[26];

  // ---- workspace ----
  char* wsp = (char*)d_ws;
  size_t off = 0;
  auto alloc = [&](size_t bytes) -> void* {
    void* p = wsp + off;
    off = (off + bytes + 255) & ~(size_t)255;
    return p;
  };
  double* stats  = (double*)alloc(256 * 8);
  float*  musig  = (float*)alloc(256 * 4);
  int*    deg    = (int*)alloc((size_t)NN * 4);
  int*    cursor = (int*)alloc((size_t)NN * 4);
  int*    blk    = (int*)alloc(256 * 4);
  float*  invd   = (float*)alloc((size_t)NN * 4);
  float*  h      = (float*)alloc((size_t)NN * HD * 4);
  float*  agg    = (float*)alloc((size_t)NN * HD * 4);
  size_t needed_direct = off;
  unsigned short* A = (unsigned short*)alloc((size_t)NN * HD * 2);
  unsigned short* B = (unsigned short*)alloc((size_t)NN * HD * 2);
  float*  sfeat  = (float*)alloc((size_t)NE * 4 * 4);
  int*    ssrc   = (int*)alloc((size_t)NE * 4);
  int*    sdst   = (int*)alloc((size_t)NE * 4);
  unsigned short* w2t = (unsigned short*)alloc((size_t)NL * HD * HD * 2);
  unsigned short* u2t = (unsigned short*)alloc((size_t)NL * HD * HD * 2);
  unsigned short* u1t = (unsigned short*)alloc((size_t)NL * HD * 256 * 2);
  unsigned short* abt = (unsigned short*)alloc((size_t)NL * 256 * HD * 2);
  size_t needed_fast = off;

  if (ws_size < needed_direct) {
    k_code<<<1, 64, 0, stream>>>(out, (float)(9000000u + (unsigned)(ws_size >> 20)));
    return;
  }
  const bool fast = (ws_size >= needed_fast);

  const int nbN  = (NN + 255) / 256;
  const int nbE  = (NE + 255) / 256;
  const int nt32 = (NN + 31) / 32;
  const int nbBN = NN * HD / 256;

  // ---- degree / inverse degree (+ sort + bf16 weight transposes if fast) ----
  hipMemsetAsync(deg, 0, (size_t)NN * 4, stream);
  k_deg<<<nbE, 256, 0, stream>>>(ei, deg);
  k_scan1<<<nbN, 256, 0, stream>>>(deg, cursor, blk, invd);
  if (fast) {
    k_scan2<<<1, 256, 0, stream>>>(blk, nbN);
    k_scan3<<<nbN, 256, 0, stream>>>(cursor, blk);
    k_scatter<<<nbE, 256, 0, stream>>>(ei, u, pos, cursor, ssrc, sdst, sfeat);
    k_w2t<<<(NL*HD*HD + 255) / 256, 256, 0, stream>>>(m2W, w2t);
    k_w2t<<<(NL*HD*HD + 255) / 256, 256, 0, stream>>>(u2W, u2t);
    k_u1t<<<(NL*HD*256 + 255) / 256, 256, 0, stream>>>(u1W, u1t);
    k_abt<<<(NL*256*HD + 255) / 256, 256, 0, stream>>>(m1W, abt);
  }

  // ---- embedding ----
  hipMemsetAsync(stats, 0, 256 * 8, stream);
  k_emb1<<<nt32, 256, 0, stream>>>(u, pos, eW1, eb1, h, stats);
  k_redA<<<1, 128, 0, stream>>>(stats, musig);
  k_bn<<<nbBN, 256, 0, stream>>>(h, musig, eg1, ebe1, 1);
  hipMemsetAsync(stats, 0, 256 * 8, stream);
  k_emb2<<<nt32, 256, 0, stream>>>(h, eW2, eb2, stats);
  k_redA<<<1, 128, 0, stream>>>(stats, musig);
  k_bn<<<nbBN, 256, 0, stream>>>(h, musig, eg2, ebe2, 0);

  // ---- message-passing layers ----
  for (int i = 0; i < NL; ++i) {
    hipMemsetAsync(agg, 0, (size_t)NN * HD * 4, stream);
    if (fast) {
      k_ab_mfma<<<nt32, 256, 0, stream>>>(h, abt + (size_t)i * 256 * HD,
                                          musig, bng + (size_t)(i > 0 ? i - 1 : 0) * HD,
                                          bnb + (size_t)(i > 0 ? i - 1 : 0) * HD,
                                          (i > 0) ? 1 : 0, A, B);
      k_msg_mfma<<<NE / 32, 256, 0, stream>>>(A, B, ssrc, sdst, sfeat, invd,
                                              m1W + (size_t)i * 260 * HD, m1b + (size_t)i * HD,
                                              w2t + (size_t)i * HD * HD, m2b + (size_t)i * HD, agg);
    } else {
      k_msg_direct<<<NE / 32, 256, 0, stream>>>(h, ei, u, pos, invd,
                                                m1W + (size_t)i * 260 * HD, m1b + (size_t)i * HD,
                                                m2W + (size_t)i * HD * HD, m2b + (size_t)i * HD, agg);
    }
    hipMemsetAsync(stats, 0, 256 * 8, stream);
    if (fast) {
      k_upd_mfma<<<nt32, 256, 0, stream>>>(h, agg, pos,
                                           u1t + (size_t)i * HD * 256,
                                           u1W + (size_t)i * 32896 + 256 * HD,
                                           u1b + (size_t)i * HD,
                                           u2t + (size_t)i * HD * HD,
                                           u2b + (size_t)i * HD, stats);
    } else {
      k_upd<<<nt32, 256, 0, stream>>>(h, agg, pos,
                                      u1W + (size_t)i * 257 * HD, u1b + (size_t)i * HD,
                                      u2W + (size_t)i * HD * HD, u2b + (size_t)i * HD, stats);
    }
    k_redA<<<1, 128, 0, stream>>>(stats, musig);
    if (!fast) {
      k_bn<<<nbBN, 256, 0, stream>>>(h, musig, bng + (size_t)i * HD, bnb + (size_t)i * HD, 0);
    }
  }

  // ---- CNN head (fused BN of layer 5 in fast path) ----
  k_conv<<<NN / 4, 256, 0, stream>>>(h, musig, bng + (size_t)(NL - 1) * HD, bnb + (size_t)(NL - 1) * HD,
                                     fast ? 1 : 0,
                                     c1W, c1b, c2W, c2b, c3W, c3b, out);
}